// Round 9
// baseline (2257.676 us; speedup 1.0000x reference)
//
#include <hip/hip_runtime.h>
#include <math.h>

#define HP     270
#define PLANE  72900      // 270*270
#define PW     272
#define PPLANE 73984      // 272*272

typedef unsigned int uint32;
typedef __attribute__((ext_vector_type(8))) short bf16x8;
typedef __attribute__((ext_vector_type(4))) float f32x4;

// ---------------- reduction helper ----------------
__device__ __forceinline__ float blockReduceSum(float val) {
  __shared__ float sh[16];
  int lane = threadIdx.x & 63, wid = threadIdx.x >> 6;
#pragma unroll
  for (int o = 32; o > 0; o >>= 1) val += __shfl_down(val, o, 64);
  __syncthreads();
  if (lane == 0) sh[wid] = val;
  __syncthreads();
  float tot = 0.f;
  int nw = (blockDim.x + 63) >> 6;
  for (int i = 0; i < nw; ++i) tot += sh[i];
  return tot;
}

// ---------------- twiddle matrix ----------------
__global__ __launch_bounds__(256) void k_twiddle(float2* __restrict__ tw) {
  int idx = blockIdx.x * 256 + threadIdx.x;
  if (idx >= PLANE) return;
  int j = idx / HP, k = idx % HP;
  int m = (j * k) % HP;
  double ang = (2.0 * M_PI * (double)m) / 270.0;
  tw[idx] = make_float2((float)cos(ang), (float)sin(ang));
}

// ---------------- symmetric pad x (2,256,256) -> xp (2,270,270), pad 7 ----------------
__global__ __launch_bounds__(256) void k_sympad(const float* __restrict__ x, float* __restrict__ xp) {
  int idx = blockIdx.x * 256 + threadIdx.x;
  if (idx >= 2 * PLANE) return;
  int b = idx / PLANE, p = idx % PLANE;
  int i = p / HP, j = p % HP;
  int si = i - 7; si = si < 0 ? -1 - si : (si > 255 ? 511 - si : si);
  int sj = j - 7; sj = sj < 0 ? -1 - sj : (sj > 255 ? 511 - sj : sj);
  xp[idx] = x[(b * 256 + si) * 256 + sj];
}

// ---------------- edgetaper 1D weights ----------------
__global__ __launch_bounds__(512) void k_edget(const float* __restrict__ bk, float* __restrict__ ahw) {
  __shared__ float pr[15], pc[15], acr[15], accl[15];
  int t = threadIdx.x;
  if (t < 15) {
    float sr = 0.f, scv = 0.f;
    for (int k = 0; k < 15; ++k) { sr += bk[t * 15 + k]; scv += bk[k * 15 + t]; }
    pr[t] = sr; pc[t] = scv;
  }
  __syncthreads();
  if (t < 30) {
    int l = t % 15; bool isr = (t < 15);
    const float* p = isr ? pr : pc;
    float s = 0.f;
    for (int j = 0; j + l < 15; ++j) s += p[j] * p[j + l];
    if (isr) acr[l] = s; else accl[l] = s;
  }
  __syncthreads();
  for (int i = t; i < 540; i += blockDim.x) {
    bool isr = (i < 270);
    int ii = isr ? i : i - 270;
    const float* ac = isr ? acr : accl;
    int m = (ii == 269) ? 0 : ii;
    float zv;
    if (m < 15) zv = ac[m];
    else if (m >= 255) zv = ac[269 - m];
    else zv = 0.f;
    ahw[i] = 1.f - zv / ac[0];
  }
}

// ---------------- Hf = psf2otf(blur 15x15) ----------------
__global__ __launch_bounds__(256) void k_Hf(const float* __restrict__ bk, float2* __restrict__ Hf) {
  int p = blockIdx.x * 256 + threadIdx.x;
  if (p >= PLANE) return;
  int u = p / HP, v = p % HP;
  float2 er[15], es[15];
#pragma unroll
  for (int r = 0; r < 15; ++r) {
    int m = ((u * (r - 7)) % HP + HP) % HP;
    float sn, cs;
    sincosf(2.f * (float)M_PI * (float)m / 270.f, &sn, &cs);
    er[r] = make_float2(cs, -sn);
    int m2 = ((v * (r - 7)) % HP + HP) % HP;
    sincosf(2.f * (float)M_PI * (float)m2 / 270.f, &sn, &cs);
    es[r] = make_float2(cs, -sn);
  }
  float ar = 0.f, ai = 0.f;
#pragma unroll 1
  for (int r = 0; r < 15; ++r) {
    float rr = 0.f, ri = 0.f;
#pragma unroll
    for (int s = 0; s < 15; ++s) {
      float wv = bk[r * 15 + s];
      rr += wv * es[s].x; ri += wv * es[s].y;
    }
    ar += er[r].x * rr - er[r].y * ri;
    ai += er[r].x * ri + er[r].y * rr;
  }
  Hf[p] = make_float2(ar, ai);
}

// ---------------- weight normalization, plain layout ----------------
__global__ __launch_bounds__(256) void k_wnorm(const float* __restrict__ w, const float* __restrict__ scale,
                                               float* __restrict__ out, int fsize) {
  int f = blockIdx.x;
  const float* wf = w + (size_t)f * fsize;
  float s = 0.f;
  for (int i = threadIdx.x; i < fsize; i += 256) s += wf[i];
  float mean = blockReduceSum(s) / (float)fsize;
  float s2 = 0.f;
  for (int i = threadIdx.x; i < fsize; i += 256) { float d = wf[i] - mean; s2 += d * d; }
  float nrm = sqrtf(blockReduceSum(s2));
  float sc = scale[f] / nrm;
  for (int i = threadIdx.x; i < fsize; i += 256) out[(size_t)f * fsize + i] = (wf[i] - mean) * sc;
}

// ---------------- transpose conv5 weights to tap-major (flipped) ----------------
__global__ void k_wT(const float* __restrict__ cwn, float* __restrict__ wT) {
  int idx = blockIdx.x * 256 + threadIdx.x;
  if (idx >= 800) return;
  int t = idx >> 5, f = idx & 31;
  int dri = t / 5, dci = t % 5;           // input offsets dr = dri-2, dc = dci-2
  wT[t * 32 + f] = cwn[f * 25 + (4 - dri) * 5 + (4 - dci)];
}

// ---------------- weight normalization -> split-bf16 MFMA fragment layout ----------------
template <int CIN, int COUT>
__global__ __launch_bounds__(256) void k_wfrag(const float* __restrict__ w, const float* __restrict__ scale,
                                               unsigned short* __restrict__ outb) {
  constexpr int KC = CIN / 32, MT = COUT / 16, FS = CIN * 9;
  int fg = blockIdx.x;
  int f = fg % COUT, iter = fg / COUT;
  const float* wf = w + (size_t)fg * FS;
  float s = 0.f;
  for (int i = threadIdx.x; i < FS; i += 256) s += wf[i];
  float mean = blockReduceSum(s) / (float)FS;
  float s2 = 0.f;
  for (int i = threadIdx.x; i < FS; i += 256) { float d = wf[i] - mean; s2 += d * d; }
  float nrm = sqrtf(blockReduceSum(s2));
  float scv = scale[fg] / nrm;
  unsigned short* dst0 = outb + (size_t)iter * (9 * KC * MT * 64 * 16);
  for (int i = threadIdx.x; i < FS; i += 256) {
    float val = (wf[i] - mean) * scv;
    int ci = i / 9, rs = i - ci * 9;
    int kc = ci >> 5, cil = ci & 31, q = cil >> 3, j = cil & 7;
    int mt = f >> 4, ocl = f & 15, lane = q * 16 + ocl;
    unsigned short* d2 = dst0 + ((((rs * KC + kc) * MT + mt) * 64 + lane) * 16);
    uint32 u = __float_as_uint(val);
    d2[j] = (unsigned short)(u >> 16);
    float lof = val - __uint_as_float(u & 0xFFFF0000u);
    d2[8 + j] = (unsigned short)(__float_as_uint(lof) >> 16);
  }
}

// ---------------- S = sum_f |FT(ww_f 5x5)|^2 ----------------
__global__ __launch_bounds__(256) void k_S(const float* __restrict__ wwn, float* __restrict__ S) {
  int p = blockIdx.x * 256 + threadIdx.x;
  if (p >= PLANE) return;
  int u = p / HP, v = p % HP;
  float2 er[5], es[5];
#pragma unroll
  for (int r = 0; r < 5; ++r) {
    float sn, cs;
    int m = (u * r) % HP;
    sincosf(2.f * (float)M_PI * (float)m / 270.f, &sn, &cs);
    er[r] = make_float2(cs, -sn);
    int m2 = (v * r) % HP;
    sincosf(2.f * (float)M_PI * (float)m2 / 270.f, &sn, &cs);
    es[r] = make_float2(cs, -sn);
  }
  float prr[25], pii[25];
#pragma unroll
  for (int r = 0; r < 5; ++r)
#pragma unroll
    for (int s = 0; s < 5; ++s) {
      prr[r * 5 + s] = er[r].x * es[s].x - er[r].y * es[s].y;
      pii[r * 5 + s] = er[r].x * es[s].y + er[r].y * es[s].x;
    }
  float acc = 0.f;
#pragma unroll 1
  for (int f = 0; f < 24; ++f) {
    float xr = 0.f, xi = 0.f;
#pragma unroll
    for (int t = 0; t < 25; ++t) {
      float wv = wwn[f * 25 + t];
      xr += wv * prr[t]; xi += wv * pii[t];
    }
    acc += xr * xr + xi * xi;
  }
  S[p] = acc;
}

// ---------------- T = conj(Hf)/(|Hf|^2 + a_d S) ----------------
__global__ __launch_bounds__(256) void k_T(const float2* __restrict__ Hf, const float* __restrict__ S,
                                           const float* __restrict__ alpha, float2* __restrict__ T) {
  int idx = blockIdx.x * 256 + threadIdx.x;
  if (idx >= 4 * PLANE) return;
  int d = idx / PLANE, p = idx % PLANE;
  float a = expf(alpha[d]);
  float2 h = Hf[p];
  float den = h.x * h.x + h.y * h.y + a * S[p];
  T[idx] = make_float2(h.x / den, -h.y / den);
}

__global__ __launch_bounds__(256) void k_amp(const float2* __restrict__ T, float* __restrict__ red) {
  int d = blockIdx.x;
  const float2* Td = T + (size_t)d * PLANE;
  float acc = 0.f;
  for (int i = threadIdx.x; i < PLANE; i += 256) { float2 t = Td[i]; acc += t.x * t.x + t.y * t.y; }
  float tot = blockReduceSum(acc);
  if (threadIdx.x == 0) red[d] = tot / (float)PLANE;
}

__global__ void k_eps(const float* __restrict__ apj, const float* __restrict__ stdn, float* __restrict__ red) {
  int s = threadIdx.x;
  if (s < 8) {
    int b = s >> 2, d = s & 3;
    red[8 + s] = expf(apj[0]) * stdn[b] * sqrtf(red[d]) * sqrtf(72899.f);
  }
}

__global__ void k_inv(const float* __restrict__ p, float* __restrict__ inv) {
  int t = threadIdx.x;
  if (t < 32) inv[t] = 1.f / p[t];
}

// ---------------- register-tiled DFT passes ----------------
template <int NR, bool REALIN>
__global__ __launch_bounds__(64) void k_rowT(const void* __restrict__ inv_, float2* __restrict__ out,
                                             const float2* __restrict__ tw, float sgn) {
  int v = blockIdx.x * 64 + threadIdx.x;
  int r0 = blockIdx.y * NR;
  int m = blockIdx.z;
  bool ok = v < HP;
  int vc = ok ? v : 0;
  float P[NR], R[NR], Q[NR], Sm[NR];
#pragma unroll
  for (int i = 0; i < NR; ++i) { P[i] = R[i] = 0.f; if (!REALIN) { Q[i] = Sm[i] = 0.f; } }
  const float*  inR = (const float*)inv_  + ((size_t)m * HP + r0) * HP;
  const float2* inC = (const float2*)inv_ + ((size_t)m * HP + r0) * HP;
#pragma unroll 3
  for (int w = 0; w < HP; ++w) {
    float2 t = tw[w * HP + vc];
#pragma unroll
    for (int i = 0; i < NR; ++i) {
      if (REALIN) {
        float a = inR[i * HP + w];
        P[i] += a * t.x; R[i] += a * t.y;
      } else {
        float2 g = inC[i * HP + w];
        P[i] += g.x * t.x; Q[i] += g.y * t.y;
        R[i] += g.x * t.y; Sm[i] += g.y * t.x;
      }
    }
  }
  if (ok) {
#pragma unroll
    for (int i = 0; i < NR; ++i) {
      float ar, ai;
      if (REALIN) { ar = P[i]; ai = sgn * R[i]; }
      else        { ar = P[i] - sgn * Q[i]; ai = sgn * R[i] + Sm[i]; }
      out[((size_t)m * HP + r0 + i) * HP + v] = make_float2(ar, ai);
    }
  }
}

template <int NU, bool REALOUT>
__global__ __launch_bounds__(64) void k_colT(const float2* __restrict__ in, void* __restrict__ outv,
                                             const float2* __restrict__ tw, float sgn, float scale) {
  int v = blockIdx.x * 64 + threadIdx.x;
  int u0 = blockIdx.y * NU;
  int m = blockIdx.z;
  bool ok = v < HP;
  int vc = ok ? v : 0;
  float P[NU], Q[NU], R[NU], Sm[NU];
#pragma unroll
  for (int j = 0; j < NU; ++j) { P[j] = Q[j] = 0.f; if (!REALOUT) { R[j] = Sm[j] = 0.f; } }
  const float2* cp = in + (size_t)m * PLANE + vc;
#pragma unroll 3
  for (int h = 0; h < HP; ++h) {
    float2 g = cp[(size_t)h * HP];
    const float2* tr = tw + h * HP + u0;
#pragma unroll
    for (int j = 0; j < NU; ++j) {
      float2 t = tr[j];
      P[j] += g.x * t.x; Q[j] += g.y * t.y;
      if (!REALOUT) { R[j] += g.x * t.y; Sm[j] += g.y * t.x; }
    }
  }
  if (ok) {
#pragma unroll
    for (int j = 0; j < NU; ++j) {
      float ar = (P[j] - sgn * Q[j]) * scale;
      if (REALOUT) ((float*)outv)[((size_t)m * HP + u0 + j) * HP + v] = ar;
      else {
        float ai = (sgn * R[j] + Sm[j]) * scale;
        ((float2*)outv)[((size_t)m * HP + u0 + j) * HP + v] = make_float2(ar, ai);
      }
    }
  }
}

// ---------------- pointwise ----------------
__global__ __launch_bounds__(256) void k_mulHf(const float2* __restrict__ in, const float2* __restrict__ Hf,
                                               float2* __restrict__ out) {
  int idx = blockIdx.x * 256 + threadIdx.x;
  if (idx >= 2 * PLANE) return;
  int p = idx % PLANE;
  float2 a = in[idx], b = Hf[p];
  out[idx] = make_float2(a.x * b.x - a.y * b.y, a.x * b.y + a.y * b.x);
}

__global__ __launch_bounds__(256) void k_taper(float* __restrict__ xp, const float* __restrict__ blr,
                                               const float* __restrict__ ahw) {
  int idx = blockIdx.x * 256 + threadIdx.x;
  if (idx >= 2 * PLANE) return;
  int p = idx % PLANE;
  int i = p / HP, j = p % HP;
  float al = ahw[i] * ahw[270 + j];
  xp[idx] = al * xp[idx] + (1.f - al) * blr[idx];
}

__global__ __launch_bounds__(256) void k_mulTY(const float2* __restrict__ T, const float2* __restrict__ Y,
                                               float2* __restrict__ out) {
  int idx = blockIdx.x * 256 + threadIdx.x;
  if (idx >= 8 * PLANE) return;
  int s = idx / PLANE, p = idx % PLANE;
  int b = s >> 2, d = s & 3;
  float2 a = T[(size_t)d * PLANE + p], y = Y[(size_t)b * PLANE + p];
  out[idx] = make_float2(a.x * y.x - a.y * y.y, a.x * y.y + a.y * y.x);
}

// ---------------- split+pack helper ----------------
__device__ __forceinline__ uint2 split_pack(float t0, float t1) {
  uint32 u0 = __float_as_uint(t0), u1 = __float_as_uint(t1);
  uint32 hiw = (u0 >> 16) | (u1 & 0xFFFF0000u);
  float r0 = t0 - __uint_as_float(u0 & 0xFFFF0000u);
  float r1 = t1 - __uint_as_float(u1 & 0xFFFF0000u);
  uint32 low = (__float_as_uint(r0) >> 16) | (__float_as_uint(r1) & 0xFFFF0000u);
  return make_uint2(hiw, low);
}

template <typename T, int STRIDE>
__device__ __forceinline__ void store_halo_s(T* __restrict__ op, int xx, int yy, int o, T val) {
  op[o] = val;
  bool xl = (xx == 0), xr = (xx == 269), yt = (yy == 0), yb = (yy == 269);
  if (xl) op[o - STRIDE] = val;
  if (xr) op[o + STRIDE] = val;
  if (yt) { op[o - PW * STRIDE] = val; if (xl) op[o - (PW + 1) * STRIDE] = val; if (xr) op[o - (PW - 1) * STRIDE] = val; }
  if (yb) { op[o + PW * STRIDE] = val; if (xl) op[o + (PW - 1) * STRIDE] = val; if (xr) op[o + (PW + 1) * STRIDE] = val; }
}

// ---------------- first conv 5x5 1->32 -> grouped split act records ----------------
__global__ __launch_bounds__(256) void k_conv5(const float* __restrict__ z, const float* __restrict__ cw,
                                               const float* __restrict__ bias, const float* __restrict__ pre,
                                               uint4* __restrict__ actout) {
  int p = blockIdx.x * 256 + threadIdx.x;
  if (p >= PLANE) return;
  int sc = blockIdx.y;
  int i = p / HP, j = p % HP;
  const float* zs = z + (size_t)sc * PLANE;
  float v[25];
#pragma unroll
  for (int r = 0; r < 5; ++r) {
    int ii = i + r - 2; ii = ii < 0 ? -1 - ii : (ii > 269 ? 539 - ii : ii);
#pragma unroll
    for (int s = 0; s < 5; ++s) {
      int jj = j + s - 2; jj = jj < 0 ? -1 - jj : (jj > 269 ? 539 - jj : jj);
      v[r * 5 + s] = zs[ii * HP + jj];
    }
  }
  int o = (i + 1) * PW + (j + 1);
#pragma unroll 1
  for (int g = 0; g < 4; ++g) {
    float tt[8];
#pragma unroll
    for (int r8 = 0; r8 < 8; ++r8) {
      int oc = 8 * g + r8;
      float a = bias[oc];
#pragma unroll
      for (int k = 0; k < 25; ++k) a += cw[oc * 25 + k] * v[k];
      float pa = pre[oc];
      tt[r8] = fmaxf(a, 0.f) + pa * fminf(a, 0.f);
    }
    uint2 sp0 = split_pack(tt[0], tt[1]), sp1 = split_pack(tt[2], tt[3]);
    uint2 sp2 = split_pack(tt[4], tt[5]), sp3 = split_pack(tt[6], tt[7]);
    uint4 hi = make_uint4(sp0.x, sp1.x, sp2.x, sp3.x);
    uint4 lo = make_uint4(sp0.y, sp1.y, sp2.y, sp3.y);
    uint4* opb = actout + (size_t)(sc * 4 + g) * PPLANE * 2;
    store_halo_s<uint4, 2>(opb, j, i, o * 2, hi);
    store_halo_s<uint4, 2>(opb, j, i, o * 2 + 1, lo);
  }
}

// ---------------- MFMA 3x3 conv, 16x16 pixel tiles + XCD band swizzle ----------------
// Wave = 16 cols x 4 rows; block = 16x16 tile. Out-of-range lanes clamp LOADS to
// (269,269) but are masked from all epilogue reads/writes (vld). Per-(o,kc) batch
// B loads into short-lived regs (no long-lived ping-pong: R6's explicit prefetch
// blew the VGPR budget and the compiler de-pipelined it — R8 post-mortem).
template <int CIN, int COUT, bool SC, bool SPLIT>
__global__ __launch_bounds__(256, 3) void k_mconv(
    const uint4* __restrict__ act, const unsigned short* __restrict__ wf,
    const float* __restrict__ bias, const float* __restrict__ pre,
    uint2* __restrict__ actout, float* __restrict__ sout,
    const uint2* __restrict__ scact, const float* __restrict__ scinv,
    const float* __restrict__ wTt) {
  constexpr int KC = CIN / 32, MT = COUT / 16;
  const int lane = threadIdx.x & 63, wv = threadIdx.x >> 6;
  const int quad = lane >> 4, col = lane & 15;
  const int sc = blockIdx.y;
  // XCD band swizzle: 289 tiles -> 8 bands of 36 (+1 tail)
  int bx = blockIdx.x;
  int tile = (bx < 288) ? ((bx & 7) * 36 + (bx >> 3)) : 288;
  const int tx0 = (tile % 17) * 16, ty0 = (tile / 17) * 16;

  uint32 py[4], px[4], boff[4];
  bool vld[4];
#pragma unroll
  for (int nt = 0; nt < 4; ++nt) {
    int xr = tx0 + col, yr = ty0 + wv * 4 + nt;
    vld[nt] = (xr < 270) && (yr < 270);
    int xx = xr > 269 ? 269 : xr;
    int yy = yr > 269 ? 269 : yr;
    px[nt] = xx; py[nt] = yy;
    boff[nt] = (yy + 1) * PW + xx;
  }
  uint32 bo[KC][4];
#pragma unroll
  for (int kc = 0; kc < KC; ++kc)
#pragma unroll
    for (int nt = 0; nt < 4; ++nt)
      bo[kc][nt] = ((uint32)(sc * (CIN / 8) + kc * 4 + quad) * PPLANE + boff[nt]) * 2;

  f32x4 acc[MT][4];
#pragma unroll
  for (int mt = 0; mt < MT; ++mt)
#pragma unroll
    for (int nt = 0; nt < 4; ++nt) { f32x4 z = {0.f, 0.f, 0.f, 0.f}; acc[mt][nt] = z; }

#pragma unroll
  for (int o = 0; o < 9; ++o) {
    const int dy = o / 3, dx = o % 3;
    const int doff2 = ((dy - 1) * PW + dx) * 2;
#pragma unroll
    for (int kc = 0; kc < KC; ++kc) {
      union { uint4 u; bf16x8 v; } Wh[MT], Wl[MT];
#pragma unroll
      for (int mt = 0; mt < MT; ++mt) {
        const uint4* wp = (const uint4*)wf + ((((o * KC + kc) * MT + mt) * 64 + lane) * 2);
        Wh[mt].u = wp[0]; Wl[mt].u = wp[1];
      }
      // batch the 8 B loads for this (o,kc) before any MFMA
      union { uint4 u; bf16x8 v; } Bh[4], Bl[4];
#pragma unroll
      for (int nt = 0; nt < 4; ++nt) {
        Bh[nt].u = act[bo[kc][nt] + doff2];
        Bl[nt].u = act[bo[kc][nt] + doff2 + 1];
      }
#pragma unroll
      for (int nt = 0; nt < 4; ++nt) {
#pragma unroll
        for (int mt = 0; mt < MT; ++mt)
          acc[mt][nt] = __builtin_amdgcn_mfma_f32_16x16x32_bf16(Wh[mt].v, Bh[nt].v, acc[mt][nt], 0, 0, 0);
#pragma unroll
        for (int mt = 0; mt < MT; ++mt)
          acc[mt][nt] = __builtin_amdgcn_mfma_f32_16x16x32_bf16(Wl[mt].v, Bh[nt].v, acc[mt][nt], 0, 0, 0);
#pragma unroll
        for (int mt = 0; mt < MT; ++mt)
          acc[mt][nt] = __builtin_amdgcn_mfma_f32_16x16x32_bf16(Wh[mt].v, Bl[nt].v, acc[mt][nt], 0, 0, 0);
      }
    }
  }

  if (SPLIT) {
#pragma unroll
    for (int mt = 0; mt < MT; ++mt) {
      const int ocb = mt * 16 + quad * 4;
      const int g2 = 2 * mt + (quad >> 1), slot = quad & 1;
      f32x4 bias4 = *(const f32x4*)(bias + ocb);
      f32x4 pr4 = *(const f32x4*)(pre + ocb);
      f32x4 inv4;
      if (SC) inv4 = *(const f32x4*)(scinv + ocb);
#pragma unroll
      for (int nt = 0; nt < 4; ++nt) {
        if (!vld[nt]) continue;        // masked: clamped duplicates must not read/write
        const uint32 ppix = boff[nt] + 1;
        float v[4];
#pragma unroll
        for (int r = 0; r < 4; ++r) v[r] = acc[mt][nt][r] + bias4[r];
        if (SC) {
          const uint2* rec = scact + ((size_t)(sc * (COUT / 8) + g2) * PPLANE + ppix) * 4;
          uint2 hi = rec[slot], lo = rec[2 + slot];
          float s0 = __uint_as_float(hi.x << 16) + __uint_as_float(lo.x << 16);
          float s1 = __uint_as_float(hi.x & 0xFFFF0000u) + __uint_as_float(lo.x & 0xFFFF0000u);
          float s2 = __uint_as_float(hi.y << 16) + __uint_as_float(lo.y << 16);
          float s3 = __uint_as_float(hi.y & 0xFFFF0000u) + __uint_as_float(lo.y & 0xFFFF0000u);
          v[0] += (s0 >= 0.f) ? s0 : s0 * inv4[0];
          v[1] += (s1 >= 0.f) ? s1 : s1 * inv4[1];
          v[2] += (s2 >= 0.f) ? s2 : s2 * inv4[2];
          v[3] += (s3 >= 0.f) ? s3 : s3 * inv4[3];
        }
        float t0 = fmaxf(v[0], 0.f) + pr4[0] * fminf(v[0], 0.f);
        float t1 = fmaxf(v[1], 0.f) + pr4[1] * fminf(v[1], 0.f);
        float t2 = fmaxf(v[2], 0.f) + pr4[2] * fminf(v[2], 0.f);
        float t3 = fmaxf(v[3], 0.f) + pr4[3] * fminf(v[3], 0.f);
        uint2 sp0 = split_pack(t0, t1), sp1 = split_pack(t2, t3);
        uint2* opb = actout + (size_t)(sc * (COUT / 8) + g2) * PPLANE * 4;
        int oidx = (int)ppix * 4;
        store_halo_s<uint2, 4>(opb, (int)px[nt], (int)py[nt], oidx + slot,     make_uint2(sp0.x, sp1.x));
        store_halo_s<uint2, 4>(opb, (int)px[nt], (int)py[nt], oidx + 2 + slot, make_uint2(sp0.y, sp1.y));
      }
    }
  } else {
    // fused convT channel contraction: s_t = sum_ch wT[t][ch]*(acc+bias)
    float4 b4[MT];
#pragma unroll
    for (int mt = 0; mt < MT; ++mt) b4[mt] = *(const float4*)(bias + mt * 16 + quad * 4);
#pragma unroll
    for (int nt = 0; nt < 4; ++nt) {
      float vv[MT][4];
#pragma unroll
      for (int mt = 0; mt < MT; ++mt) {
        vv[mt][0] = acc[mt][nt][0] + b4[mt].x;
        vv[mt][1] = acc[mt][nt][1] + b4[mt].y;
        vv[mt][2] = acc[mt][nt][2] + b4[mt].z;
        vv[mt][3] = acc[mt][nt][3] + b4[mt].w;
      }
      float* sp = sout + (size_t)sc * 25 * PLANE + (int)(py[nt] * 270 + px[nt]);
#pragma unroll
      for (int t = 0; t < 25; ++t) {
        const float* wp = wTt + t * 32 + quad * 4;
        float c = 0.f;
#pragma unroll
        for (int mt = 0; mt < MT; ++mt) {
          float4 w4 = *(const float4*)(wp + mt * 16);
          c += w4.x * vv[mt][0] + w4.y * vv[mt][1] + w4.z * vv[mt][2] + w4.w * vv[mt][3];
        }
        c += __shfl_xor(c, 16, 64);        // vld is quad-uniform: shuffles stay uniform
        c += __shfl_xor(c, 32, 64);
        if (quad == 0 && vld[nt]) sp[(size_t)t * PLANE] = c;
      }
    }
  }
}

// ---------------- convT pass 2: out = bt + sum_t s_t(shifted) ----------------
__global__ __launch_bounds__(256) void k_convT2(const float* __restrict__ s, const float* __restrict__ bt,
                                                float* __restrict__ yo) {
  int p = blockIdx.x * 256 + threadIdx.x;
  if (p >= PLANE) return;
  int sc = blockIdx.y;
  int y = p / 270, x = p - y * 270;
  float acc = bt[0];
  const float* sb = s + (size_t)sc * 25 * PLANE;
#pragma unroll
  for (int a = 0; a < 5; ++a) {
    int yy = y + a - 2;
    if ((unsigned)yy >= 270u) continue;
    const float* row = sb + (size_t)(a * 5) * PLANE + yy * 270;
#pragma unroll
    for (int b = 0; b < 5; ++b) {
      int xx = x + b - 2;
      if ((unsigned)xx < 270u) acc += row[(size_t)b * PLANE + xx];
    }
  }
  yo[(size_t)sc * PLANE + p] = acc;
}

// ---------------- norm projection scale ----------------
__global__ __launch_bounds__(256) void k_nrm(const float* __restrict__ yb, float* __restrict__ red) {
  int s = blockIdx.x;
  const float* ys = yb + (size_t)s * PLANE;
  float acc = 0.f;
  for (int i = threadIdx.x; i < PLANE; i += 256) { float v = ys[i]; acc += v * v; }
  float tot = blockReduceSum(acc);
  if (threadIdx.x == 0) {
    float nrm = sqrtf(tot);
    float eps = red[8 + s];
    red[16 + s] = (nrm > eps) ? eps / fmaxf(nrm, 1e-12f) : 1.0f;
  }
}

// ---------------- final: clip(z - scl*y), crop, mix ----------------
__global__ __launch_bounds__(256) void k_final(const float* __restrict__ z, const float* __restrict__ yb,
                                               const float* __restrict__ red, const float* __restrict__ mw,
                                               float* __restrict__ out) {
  int idx = blockIdx.x * 256 + threadIdx.x;
  if (idx >= 131072) return;
  int b = idx >> 16;
  int rem = idx & 65535;
  int h = rem >> 8, w = rem & 255;
  int p = (h + 7) * HP + (w + 7);
  float acc = 0.f;
#pragma unroll
  for (int d = 0; d < 4; ++d) {
    int s = b * 4 + d;
    float v = z[(size_t)s * PLANE + p] - red[16 + s] * yb[(size_t)s * PLANE + p];
    v = fminf(fmaxf(v, 0.f), 255.f);
    acc += mw[d] * v;
  }
  out[idx] = acc;
}

// =====================================================================
extern "C" void kernel_launch(void* const* d_in, const int* in_sizes, int n_in,
                              void* d_out, int out_size, void* d_ws, size_t ws_size,
                              hipStream_t stream) {
  (void)in_sizes; (void)n_in; (void)out_size; (void)ws_size;
  const float* x    = (const float*)d_in[0];
  const float* bk   = (const float*)d_in[1];
  const float* stdn = (const float*)d_in[2];
  const float* ww   = (const float*)d_in[3];
  const float* wwsc = (const float*)d_in[4];
  const float* alph = (const float*)d_in[5];
  const float* cw   = (const float*)d_in[6];
  const float* sf   = (const float*)d_in[7];
  const float* bf   = (const float*)d_in[8];
  const float* bt   = (const float*)d_in[9];
  const float* p1   = (const float*)d_in[10];
  const float* w1   = (const float*)d_in[11];
  const float* s1   = (const float*)d_in[12];
  const float* b1   = (const float*)d_in[13];
  const float* p2   = (const float*)d_in[14];
  const float* w2   = (const float*)d_in[15];
  const float* s2   = (const float*)d_in[16];
  const float* b2   = (const float*)d_in[17];
  const float* apj  = (const float*)d_in[18];
  const float* mwp  = (const float*)d_in[19];
  float* out = (float*)d_out;

  char* wsbase = (char*)d_ws;
  size_t off = 0;
  auto alloc = [&](size_t nbytes) -> char* {
    char* p = wsbase + off;
    off = (off + nbytes + 255) & ~(size_t)255;
    return p;
  };
  // ---- persistent region ----
  float*  zb  = (float*)alloc(8 * (size_t)PLANE * 4);
  float*  yb  = (float*)alloc(8 * (size_t)PLANE * 4);
  float*  red = (float*)alloc(64 * 4);
  float*  inv = (float*)alloc(32 * 4);
  float*  cwn = (float*)alloc(800 * 4);
  float*  wTt = (float*)alloc(800 * 4);
  unsigned short* w1f = (unsigned short*)alloc(5 * 36864 * (size_t)2);
  unsigned short* w2f = (unsigned short*)alloc(5 * 36864 * (size_t)2);
  // ---- union region ----
  size_t U0 = off;
  // DFT view
  float2* tw  = (float2*)alloc(2 * (size_t)PLANE * 4);
  float*  xp  = (float*)alloc(2 * (size_t)PLANE * 4);
  float*  rtm = (float*)alloc(2 * (size_t)PLANE * 4);
  float2* cb0 = (float2*)alloc(2 * 8 * (size_t)PLANE * 8);
  float2* cb1 = (float2*)alloc(2 * 8 * (size_t)PLANE * 8);
  float2* Yb  = (float2*)alloc(2 * 2 * (size_t)PLANE * 8);
  float2* Hf  = (float2*)alloc(2 * (size_t)PLANE * 4);
  float*  Sb  = (float*)alloc((size_t)PLANE * 4);
  float2* Tb  = (float2*)alloc(2 * 4 * (size_t)PLANE * 4);
  float*  ahw = (float*)alloc(540 * 4);
  float*  wwn = (float*)alloc(600 * 4);
  // conv view (aliases the DFT view)
  off = U0;
  uint4* act1 = (uint4*)alloc(4 * 4 * (size_t)PPLANE * 32);   // 32ch split acts; also aliases sOb (4*25*PLANE f32)
  uint4* act2 = (uint4*)alloc(4 * 8 * (size_t)PPLANE * 32);   // 64ch split acts
  float* sOb = (float*)act1;

  // setup
  k_twiddle<<<285, 256, 0, stream>>>(tw);
  k_sympad<<<(2 * PLANE + 255) / 256, 256, 0, stream>>>(x, xp);
  k_edget<<<1, 512, 0, stream>>>(bk, ahw);
  k_Hf<<<285, 256, 0, stream>>>(bk, Hf);
  k_wnorm<<<24, 256, 0, stream>>>(ww, wwsc, wwn, 25);
  k_wnorm<<<32, 256, 0, stream>>>(cw, sf, cwn, 25);
  k_wT<<<4, 256, 0, stream>>>(cwn, wTt);
  k_wfrag<32, 64><<<320, 256, 0, stream>>>(w1, s1, w1f);
  k_wfrag<64, 32><<<160, 256, 0, stream>>>(w2, s2, w2f);
  k_inv<<<1, 32, 0, stream>>>(p1, inv);
  k_S<<<285, 256, 0, stream>>>(wwn, Sb);
  k_T<<<(4 * PLANE + 255) / 256, 256, 0, stream>>>(Hf, Sb, alph, Tb);
  k_amp<<<4, 256, 0, stream>>>(Tb, red);
  k_eps<<<1, 64, 0, stream>>>(apj, stdn, red);

  dim3 g2(5, 45, 2), g8(5, 45, 8);

  // edgetaper
  k_rowT<6, true ><<<g2, 64, 0, stream>>>(xp, cb1, tw, -1.f);
  k_colT<6, false><<<g2, 64, 0, stream>>>(cb1, cb0, tw, -1.f, 1.f);
  k_mulHf<<<(2 * PLANE + 255) / 256, 256, 0, stream>>>(cb0, Hf, cb1);
  k_rowT<6, false><<<g2, 64, 0, stream>>>(cb1, cb0, tw, 1.f);
  k_colT<6, true ><<<g2, 64, 0, stream>>>(cb0, rtm, tw, 1.f, 1.f / (float)PLANE);
  k_taper<<<(2 * PLANE + 255) / 256, 256, 0, stream>>>(xp, rtm, ahw);

  // Y = fft2(xp)
  k_rowT<6, true ><<<g2, 64, 0, stream>>>(xp, cb1, tw, -1.f);
  k_colT<6, false><<<g2, 64, 0, stream>>>(cb1, Yb, tw, -1.f, 1.f);

  // z = ifft2(T*Y).real for all 8 (b,d)
  k_mulTY<<<(8 * PLANE + 255) / 256, 256, 0, stream>>>(Tb, Yb, cb0);
  k_rowT<6, false><<<g8, 64, 0, stream>>>(cb0, cb1, tw, 1.f);
  k_colT<6, true ><<<g8, 64, 0, stream>>>(cb1, zb, tw, 1.f, 1.f / (float)PLANE);

  // conv net, 2 chunks of 4 samples
  for (int c = 0; c < 2; ++c) {
    const float* zc = zb + (size_t)c * 4 * PLANE;
    float* ybc = yb + (size_t)c * 4 * PLANE;
    k_conv5<<<dim3(285, 4), 256, 0, stream>>>(zc, cwn, bf, p1, act1);
    for (int i = 0; i < 5; ++i) {
      k_mconv<32, 64, false, true><<<dim3(289, 4), 256, 0, stream>>>(
          act1, w1f + (size_t)i * 36864, b1 + i * 64, p2 + i * 64, (uint2*)act2, nullptr, nullptr, nullptr, nullptr);
      if (i == 0)
        k_mconv<64, 32, true, true><<<dim3(289, 4), 256, 0, stream>>>(
            act2, w2f + (size_t)i * 36864, b2 + i * 32, p1 + (i + 1) * 32, (uint2*)act1, nullptr, (const uint2*)act1, inv, nullptr);
      else if (i < 4)
        k_mconv<64, 32, false, true><<<dim3(289, 4), 256, 0, stream>>>(
            act2, w2f + (size_t)i * 36864, b2 + i * 32, p1 + (i + 1) * 32, (uint2*)act1, nullptr, nullptr, nullptr, nullptr);
      else
        k_mconv<64, 32, false, false><<<dim3(289, 4), 256, 0, stream>>>(
            act2, w2f + (size_t)i * 36864, b2 + i * 32, nullptr, nullptr, sOb, nullptr, nullptr, wTt);
    }
    k_convT2<<<dim3(285, 4), 256, 0, stream>>>(sOb, bt, ybc);
  }

  // projection + final mix
  k_nrm<<<8, 256, 0, stream>>>(yb, red);
  k_final<<<(131072 + 255) / 256, 256, 0, stream>>>(zb, yb, red, mwp, out);
}

// Round 10
// 2142.115 us; speedup vs baseline: 1.0539x; 1.0539x over previous
//
#include <hip/hip_runtime.h>
#include <math.h>

#define HP     270
#define PLANE  72900      // 270*270
#define PW     272
#define PPLANE 73984      // 272*272

typedef unsigned int uint32;
typedef __attribute__((ext_vector_type(8))) short bf16x8;
typedef __attribute__((ext_vector_type(4))) float f32x4;

// ---------------- reduction helper ----------------
__device__ __forceinline__ float blockReduceSum(float val) {
  __shared__ float sh[16];
  int lane = threadIdx.x & 63, wid = threadIdx.x >> 6;
#pragma unroll
  for (int o = 32; o > 0; o >>= 1) val += __shfl_down(val, o, 64);
  __syncthreads();
  if (lane == 0) sh[wid] = val;
  __syncthreads();
  float tot = 0.f;
  int nw = (blockDim.x + 63) >> 6;
  for (int i = 0; i < nw; ++i) tot += sh[i];
  return tot;
}

// ---------------- twiddle matrix ----------------
__global__ __launch_bounds__(256) void k_twiddle(float2* __restrict__ tw) {
  int idx = blockIdx.x * 256 + threadIdx.x;
  if (idx >= PLANE) return;
  int j = idx / HP, k = idx % HP;
  int m = (j * k) % HP;
  double ang = (2.0 * M_PI * (double)m) / 270.0;
  tw[idx] = make_float2((float)cos(ang), (float)sin(ang));
}

// ---------------- symmetric pad x (2,256,256) -> xp (2,270,270), pad 7 ----------------
__global__ __launch_bounds__(256) void k_sympad(const float* __restrict__ x, float* __restrict__ xp) {
  int idx = blockIdx.x * 256 + threadIdx.x;
  if (idx >= 2 * PLANE) return;
  int b = idx / PLANE, p = idx % PLANE;
  int i = p / HP, j = p % HP;
  int si = i - 7; si = si < 0 ? -1 - si : (si > 255 ? 511 - si : si);
  int sj = j - 7; sj = sj < 0 ? -1 - sj : (sj > 255 ? 511 - sj : sj);
  xp[idx] = x[(b * 256 + si) * 256 + sj];
}

// ---------------- edgetaper 1D weights ----------------
__global__ __launch_bounds__(512) void k_edget(const float* __restrict__ bk, float* __restrict__ ahw) {
  __shared__ float pr[15], pc[15], acr[15], accl[15];
  int t = threadIdx.x;
  if (t < 15) {
    float sr = 0.f, scv = 0.f;
    for (int k = 0; k < 15; ++k) { sr += bk[t * 15 + k]; scv += bk[k * 15 + t]; }
    pr[t] = sr; pc[t] = scv;
  }
  __syncthreads();
  if (t < 30) {
    int l = t % 15; bool isr = (t < 15);
    const float* p = isr ? pr : pc;
    float s = 0.f;
    for (int j = 0; j + l < 15; ++j) s += p[j] * p[j + l];
    if (isr) acr[l] = s; else accl[l] = s;
  }
  __syncthreads();
  for (int i = t; i < 540; i += blockDim.x) {
    bool isr = (i < 270);
    int ii = isr ? i : i - 270;
    const float* ac = isr ? acr : accl;
    int m = (ii == 269) ? 0 : ii;
    float zv;
    if (m < 15) zv = ac[m];
    else if (m >= 255) zv = ac[269 - m];
    else zv = 0.f;
    ahw[i] = 1.f - zv / ac[0];
  }
}

// ---------------- Hf = psf2otf(blur 15x15) ----------------
__global__ __launch_bounds__(256) void k_Hf(const float* __restrict__ bk, float2* __restrict__ Hf) {
  int p = blockIdx.x * 256 + threadIdx.x;
  if (p >= PLANE) return;
  int u = p / HP, v = p % HP;
  float2 er[15], es[15];
#pragma unroll
  for (int r = 0; r < 15; ++r) {
    int m = ((u * (r - 7)) % HP + HP) % HP;
    float sn, cs;
    sincosf(2.f * (float)M_PI * (float)m / 270.f, &sn, &cs);
    er[r] = make_float2(cs, -sn);
    int m2 = ((v * (r - 7)) % HP + HP) % HP;
    sincosf(2.f * (float)M_PI * (float)m2 / 270.f, &sn, &cs);
    es[r] = make_float2(cs, -sn);
  }
  float ar = 0.f, ai = 0.f;
#pragma unroll 1
  for (int r = 0; r < 15; ++r) {
    float rr = 0.f, ri = 0.f;
#pragma unroll
    for (int s = 0; s < 15; ++s) {
      float wv = bk[r * 15 + s];
      rr += wv * es[s].x; ri += wv * es[s].y;
    }
    ar += er[r].x * rr - er[r].y * ri;
    ai += er[r].x * ri + er[r].y * rr;
  }
  Hf[p] = make_float2(ar, ai);
}

// ---------------- weight normalization, plain layout ----------------
__global__ __launch_bounds__(256) void k_wnorm(const float* __restrict__ w, const float* __restrict__ scale,
                                               float* __restrict__ out, int fsize) {
  int f = blockIdx.x;
  const float* wf = w + (size_t)f * fsize;
  float s = 0.f;
  for (int i = threadIdx.x; i < fsize; i += 256) s += wf[i];
  float mean = blockReduceSum(s) / (float)fsize;
  float s2 = 0.f;
  for (int i = threadIdx.x; i < fsize; i += 256) { float d = wf[i] - mean; s2 += d * d; }
  float nrm = sqrtf(blockReduceSum(s2));
  float sc = scale[f] / nrm;
  for (int i = threadIdx.x; i < fsize; i += 256) out[(size_t)f * fsize + i] = (wf[i] - mean) * sc;
}

// ---------------- transpose conv5 weights to tap-major (flipped) ----------------
__global__ void k_wT(const float* __restrict__ cwn, float* __restrict__ wT) {
  int idx = blockIdx.x * 256 + threadIdx.x;
  if (idx >= 800) return;
  int t = idx >> 5, f = idx & 31;
  int dri = t / 5, dci = t % 5;           // input offsets dr = dri-2, dc = dci-2
  wT[t * 32 + f] = cwn[f * 25 + (4 - dri) * 5 + (4 - dci)];
}

// ---------------- weight normalization -> split-bf16 MFMA fragment layout ----------------
template <int CIN, int COUT>
__global__ __launch_bounds__(256) void k_wfrag(const float* __restrict__ w, const float* __restrict__ scale,
                                               unsigned short* __restrict__ outb) {
  constexpr int KC = CIN / 32, MT = COUT / 16, FS = CIN * 9;
  int fg = blockIdx.x;
  int f = fg % COUT, iter = fg / COUT;
  const float* wf = w + (size_t)fg * FS;
  float s = 0.f;
  for (int i = threadIdx.x; i < FS; i += 256) s += wf[i];
  float mean = blockReduceSum(s) / (float)FS;
  float s2 = 0.f;
  for (int i = threadIdx.x; i < FS; i += 256) { float d = wf[i] - mean; s2 += d * d; }
  float nrm = sqrtf(blockReduceSum(s2));
  float scv = scale[fg] / nrm;
  unsigned short* dst0 = outb + (size_t)iter * (9 * KC * MT * 64 * 16);
  for (int i = threadIdx.x; i < FS; i += 256) {
    float val = (wf[i] - mean) * scv;
    int ci = i / 9, rs = i - ci * 9;
    int kc = ci >> 5, cil = ci & 31, q = cil >> 3, j = cil & 7;
    int mt = f >> 4, ocl = f & 15, lane = q * 16 + ocl;
    unsigned short* d2 = dst0 + ((((rs * KC + kc) * MT + mt) * 64 + lane) * 16);
    uint32 u = __float_as_uint(val);
    d2[j] = (unsigned short)(u >> 16);
    float lof = val - __uint_as_float(u & 0xFFFF0000u);
    d2[8 + j] = (unsigned short)(__float_as_uint(lof) >> 16);
  }
}

// ---------------- S = sum_f |FT(ww_f 5x5)|^2 ----------------
__global__ __launch_bounds__(256) void k_S(const float* __restrict__ wwn, float* __restrict__ S) {
  int p = blockIdx.x * 256 + threadIdx.x;
  if (p >= PLANE) return;
  int u = p / HP, v = p % HP;
  float2 er[5], es[5];
#pragma unroll
  for (int r = 0; r < 5; ++r) {
    float sn, cs;
    int m = (u * r) % HP;
    sincosf(2.f * (float)M_PI * (float)m / 270.f, &sn, &cs);
    er[r] = make_float2(cs, -sn);
    int m2 = (v * r) % HP;
    sincosf(2.f * (float)M_PI * (float)m2 / 270.f, &sn, &cs);
    es[r] = make_float2(cs, -sn);
  }
  float prr[25], pii[25];
#pragma unroll
  for (int r = 0; r < 5; ++r)
#pragma unroll
    for (int s = 0; s < 5; ++s) {
      prr[r * 5 + s] = er[r].x * es[s].x - er[r].y * es[s].y;
      pii[r * 5 + s] = er[r].x * es[s].y + er[r].y * es[s].x;
    }
  float acc = 0.f;
#pragma unroll 1
  for (int f = 0; f < 24; ++f) {
    float xr = 0.f, xi = 0.f;
#pragma unroll
    for (int t = 0; t < 25; ++t) {
      float wv = wwn[f * 25 + t];
      xr += wv * prr[t]; xi += wv * pii[t];
    }
    acc += xr * xr + xi * xi;
  }
  S[p] = acc;
}

// ---------------- T = conj(Hf)/(|Hf|^2 + a_d S) ----------------
__global__ __launch_bounds__(256) void k_T(const float2* __restrict__ Hf, const float* __restrict__ S,
                                           const float* __restrict__ alpha, float2* __restrict__ T) {
  int idx = blockIdx.x * 256 + threadIdx.x;
  if (idx >= 4 * PLANE) return;
  int d = idx / PLANE, p = idx % PLANE;
  float a = expf(alpha[d]);
  float2 h = Hf[p];
  float den = h.x * h.x + h.y * h.y + a * S[p];
  T[idx] = make_float2(h.x / den, -h.y / den);
}

__global__ __launch_bounds__(256) void k_amp(const float2* __restrict__ T, float* __restrict__ red) {
  int d = blockIdx.x;
  const float2* Td = T + (size_t)d * PLANE;
  float acc = 0.f;
  for (int i = threadIdx.x; i < PLANE; i += 256) { float2 t = Td[i]; acc += t.x * t.x + t.y * t.y; }
  float tot = blockReduceSum(acc);
  if (threadIdx.x == 0) red[d] = tot / (float)PLANE;
}

__global__ void k_eps(const float* __restrict__ apj, const float* __restrict__ stdn, float* __restrict__ red) {
  int s = threadIdx.x;
  if (s < 8) {
    int b = s >> 2, d = s & 3;
    red[8 + s] = expf(apj[0]) * stdn[b] * sqrtf(red[d]) * sqrtf(72899.f);
  }
}

__global__ void k_inv(const float* __restrict__ p, float* __restrict__ inv) {
  int t = threadIdx.x;
  if (t < 32) inv[t] = 1.f / p[t];
}

// ---------------- register-tiled DFT passes ----------------
template <int NR, bool REALIN>
__global__ __launch_bounds__(64) void k_rowT(const void* __restrict__ inv_, float2* __restrict__ out,
                                             const float2* __restrict__ tw, float sgn) {
  int v = blockIdx.x * 64 + threadIdx.x;
  int r0 = blockIdx.y * NR;
  int m = blockIdx.z;
  bool ok = v < HP;
  int vc = ok ? v : 0;
  float P[NR], R[NR], Q[NR], Sm[NR];
#pragma unroll
  for (int i = 0; i < NR; ++i) { P[i] = R[i] = 0.f; if (!REALIN) { Q[i] = Sm[i] = 0.f; } }
  const float*  inR = (const float*)inv_  + ((size_t)m * HP + r0) * HP;
  const float2* inC = (const float2*)inv_ + ((size_t)m * HP + r0) * HP;
#pragma unroll 3
  for (int w = 0; w < HP; ++w) {
    float2 t = tw[w * HP + vc];
#pragma unroll
    for (int i = 0; i < NR; ++i) {
      if (REALIN) {
        float a = inR[i * HP + w];
        P[i] += a * t.x; R[i] += a * t.y;
      } else {
        float2 g = inC[i * HP + w];
        P[i] += g.x * t.x; Q[i] += g.y * t.y;
        R[i] += g.x * t.y; Sm[i] += g.y * t.x;
      }
    }
  }
  if (ok) {
#pragma unroll
    for (int i = 0; i < NR; ++i) {
      float ar, ai;
      if (REALIN) { ar = P[i]; ai = sgn * R[i]; }
      else        { ar = P[i] - sgn * Q[i]; ai = sgn * R[i] + Sm[i]; }
      out[((size_t)m * HP + r0 + i) * HP + v] = make_float2(ar, ai);
    }
  }
}

template <int NU, bool REALOUT>
__global__ __launch_bounds__(64) void k_colT(const float2* __restrict__ in, void* __restrict__ outv,
                                             const float2* __restrict__ tw, float sgn, float scale) {
  int v = blockIdx.x * 64 + threadIdx.x;
  int u0 = blockIdx.y * NU;
  int m = blockIdx.z;
  bool ok = v < HP;
  int vc = ok ? v : 0;
  float P[NU], Q[NU], R[NU], Sm[NU];
#pragma unroll
  for (int j = 0; j < NU; ++j) { P[j] = Q[j] = 0.f; if (!REALOUT) { R[j] = Sm[j] = 0.f; } }
  const float2* cp = in + (size_t)m * PLANE + vc;
#pragma unroll 3
  for (int h = 0; h < HP; ++h) {
    float2 g = cp[(size_t)h * HP];
    const float2* tr = tw + h * HP + u0;
#pragma unroll
    for (int j = 0; j < NU; ++j) {
      float2 t = tr[j];
      P[j] += g.x * t.x; Q[j] += g.y * t.y;
      if (!REALOUT) { R[j] += g.x * t.y; Sm[j] += g.y * t.x; }
    }
  }
  if (ok) {
#pragma unroll
    for (int j = 0; j < NU; ++j) {
      float ar = (P[j] - sgn * Q[j]) * scale;
      if (REALOUT) ((float*)outv)[((size_t)m * HP + u0 + j) * HP + v] = ar;
      else {
        float ai = (sgn * R[j] + Sm[j]) * scale;
        ((float2*)outv)[((size_t)m * HP + u0 + j) * HP + v] = make_float2(ar, ai);
      }
    }
  }
}

// ---------------- pointwise ----------------
__global__ __launch_bounds__(256) void k_mulHf(const float2* __restrict__ in, const float2* __restrict__ Hf,
                                               float2* __restrict__ out) {
  int idx = blockIdx.x * 256 + threadIdx.x;
  if (idx >= 2 * PLANE) return;
  int p = idx % PLANE;
  float2 a = in[idx], b = Hf[p];
  out[idx] = make_float2(a.x * b.x - a.y * b.y, a.x * b.y + a.y * b.x);
}

__global__ __launch_bounds__(256) void k_taper(float* __restrict__ xp, const float* __restrict__ blr,
                                               const float* __restrict__ ahw) {
  int idx = blockIdx.x * 256 + threadIdx.x;
  if (idx >= 2 * PLANE) return;
  int p = idx % PLANE;
  int i = p / HP, j = p % HP;
  float al = ahw[i] * ahw[270 + j];
  xp[idx] = al * xp[idx] + (1.f - al) * blr[idx];
}

__global__ __launch_bounds__(256) void k_mulTY(const float2* __restrict__ T, const float2* __restrict__ Y,
                                               float2* __restrict__ out) {
  int idx = blockIdx.x * 256 + threadIdx.x;
  if (idx >= 8 * PLANE) return;
  int s = idx / PLANE, p = idx % PLANE;
  int b = s >> 2, d = s & 3;
  float2 a = T[(size_t)d * PLANE + p], y = Y[(size_t)b * PLANE + p];
  out[idx] = make_float2(a.x * y.x - a.y * y.y, a.x * y.y + a.y * y.x);
}

// ---------------- split+pack helper ----------------
__device__ __forceinline__ uint2 split_pack(float t0, float t1) {
  uint32 u0 = __float_as_uint(t0), u1 = __float_as_uint(t1);
  uint32 hiw = (u0 >> 16) | (u1 & 0xFFFF0000u);
  float r0 = t0 - __uint_as_float(u0 & 0xFFFF0000u);
  float r1 = t1 - __uint_as_float(u1 & 0xFFFF0000u);
  uint32 low = (__float_as_uint(r0) >> 16) | (__float_as_uint(r1) & 0xFFFF0000u);
  return make_uint2(hiw, low);
}

template <typename T, int STRIDE>
__device__ __forceinline__ void store_halo_s(T* __restrict__ op, int xx, int yy, int o, T val) {
  op[o] = val;
  bool xl = (xx == 0), xr = (xx == 269), yt = (yy == 0), yb = (yy == 269);
  if (xl) op[o - STRIDE] = val;
  if (xr) op[o + STRIDE] = val;
  if (yt) { op[o - PW * STRIDE] = val; if (xl) op[o - (PW + 1) * STRIDE] = val; if (xr) op[o - (PW - 1) * STRIDE] = val; }
  if (yb) { op[o + PW * STRIDE] = val; if (xl) op[o + (PW - 1) * STRIDE] = val; if (xr) op[o + (PW + 1) * STRIDE] = val; }
}

// ---------------- first conv 5x5 1->32 -> grouped split act records ----------------
__global__ __launch_bounds__(256) void k_conv5(const float* __restrict__ z, const float* __restrict__ cw,
                                               const float* __restrict__ bias, const float* __restrict__ pre,
                                               uint4* __restrict__ actout) {
  int p = blockIdx.x * 256 + threadIdx.x;
  if (p >= PLANE) return;
  int sc = blockIdx.y;
  int i = p / HP, j = p % HP;
  const float* zs = z + (size_t)sc * PLANE;
  float v[25];
#pragma unroll
  for (int r = 0; r < 5; ++r) {
    int ii = i + r - 2; ii = ii < 0 ? -1 - ii : (ii > 269 ? 539 - ii : ii);
#pragma unroll
    for (int s = 0; s < 5; ++s) {
      int jj = j + s - 2; jj = jj < 0 ? -1 - jj : (jj > 269 ? 539 - jj : jj);
      v[r * 5 + s] = zs[ii * HP + jj];
    }
  }
  int o = (i + 1) * PW + (j + 1);
#pragma unroll 1
  for (int g = 0; g < 4; ++g) {
    float tt[8];
#pragma unroll
    for (int r8 = 0; r8 < 8; ++r8) {
      int oc = 8 * g + r8;
      float a = bias[oc];
#pragma unroll
      for (int k = 0; k < 25; ++k) a += cw[oc * 25 + k] * v[k];
      float pa = pre[oc];
      tt[r8] = fmaxf(a, 0.f) + pa * fminf(a, 0.f);
    }
    uint2 sp0 = split_pack(tt[0], tt[1]), sp1 = split_pack(tt[2], tt[3]);
    uint2 sp2 = split_pack(tt[4], tt[5]), sp3 = split_pack(tt[6], tt[7]);
    uint4 hi = make_uint4(sp0.x, sp1.x, sp2.x, sp3.x);
    uint4 lo = make_uint4(sp0.y, sp1.y, sp2.y, sp3.y);
    uint4* opb = actout + (size_t)(sc * 4 + g) * PPLANE * 2;
    store_halo_s<uint4, 2>(opb, j, i, o * 2, hi);
    store_halo_s<uint4, 2>(opb, j, i, o * 2 + 1, lo);
  }
}

// ---------------- MFMA 3x3 conv, 16x16 pixel tiles + XCD band swizzle ----------------
// Wave = 16 cols x 4 rows; block = 16x16 tile. Out-of-range lanes clamp LOADS to
// (269,269) but are masked from all epilogue reads/writes (vld).
// Occupancy is throttled to 4 blocks/CU via 40 KiB dynamic LDS at launch:
// VGPR(84) would allow 6 blocks/CU and that thrashes L2 (R9: FETCH 132->315 MB).
template <int CIN, int COUT, bool SC, bool SPLIT>
__global__ __launch_bounds__(256) void k_mconv(
    const uint4* __restrict__ act, const unsigned short* __restrict__ wf,
    const float* __restrict__ bias, const float* __restrict__ pre,
    uint2* __restrict__ actout, float* __restrict__ sout,
    const uint2* __restrict__ scact, const float* __restrict__ scinv,
    const float* __restrict__ wTt) {
  constexpr int KC = CIN / 32, MT = COUT / 16;
  const int lane = threadIdx.x & 63, wv = threadIdx.x >> 6;
  const int quad = lane >> 4, col = lane & 15;
  const int sc = blockIdx.y;
  // XCD band swizzle: 289 tiles -> 8 bands of 36 (+1 tail)
  int bx = blockIdx.x;
  int tile = (bx < 288) ? ((bx & 7) * 36 + (bx >> 3)) : 288;
  const int tx0 = (tile % 17) * 16, ty0 = (tile / 17) * 16;

  uint32 py[4], px[4], boff[4];
  bool vld[4];
#pragma unroll
  for (int nt = 0; nt < 4; ++nt) {
    int xr = tx0 + col, yr = ty0 + wv * 4 + nt;
    vld[nt] = (xr < 270) && (yr < 270);
    int xx = xr > 269 ? 269 : xr;
    int yy = yr > 269 ? 269 : yr;
    px[nt] = xx; py[nt] = yy;
    boff[nt] = (yy + 1) * PW + xx;
  }
  uint32 bo[KC][4];
#pragma unroll
  for (int kc = 0; kc < KC; ++kc)
#pragma unroll
    for (int nt = 0; nt < 4; ++nt)
      bo[kc][nt] = ((uint32)(sc * (CIN / 8) + kc * 4 + quad) * PPLANE + boff[nt]) * 2;

  f32x4 acc[MT][4];
#pragma unroll
  for (int mt = 0; mt < MT; ++mt)
#pragma unroll
    for (int nt = 0; nt < 4; ++nt) { f32x4 z = {0.f, 0.f, 0.f, 0.f}; acc[mt][nt] = z; }

#pragma unroll
  for (int o = 0; o < 9; ++o) {
    const int dy = o / 3, dx = o % 3;
    const int doff2 = ((dy - 1) * PW + dx) * 2;
#pragma unroll
    for (int kc = 0; kc < KC; ++kc) {
      union { uint4 u; bf16x8 v; } Wh[MT], Wl[MT];
#pragma unroll
      for (int mt = 0; mt < MT; ++mt) {
        const uint4* wp = (const uint4*)wf + ((((o * KC + kc) * MT + mt) * 64 + lane) * 2);
        Wh[mt].u = wp[0]; Wl[mt].u = wp[1];
      }
      // batch the 8 B loads for this (o,kc) before any MFMA
      union { uint4 u; bf16x8 v; } Bh[4], Bl[4];
#pragma unroll
      for (int nt = 0; nt < 4; ++nt) {
        Bh[nt].u = act[bo[kc][nt] + doff2];
        Bl[nt].u = act[bo[kc][nt] + doff2 + 1];
      }
#pragma unroll
      for (int nt = 0; nt < 4; ++nt) {
#pragma unroll
        for (int mt = 0; mt < MT; ++mt)
          acc[mt][nt] = __builtin_amdgcn_mfma_f32_16x16x32_bf16(Wh[mt].v, Bh[nt].v, acc[mt][nt], 0, 0, 0);
#pragma unroll
        for (int mt = 0; mt < MT; ++mt)
          acc[mt][nt] = __builtin_amdgcn_mfma_f32_16x16x32_bf16(Wl[mt].v, Bh[nt].v, acc[mt][nt], 0, 0, 0);
#pragma unroll
        for (int mt = 0; mt < MT; ++mt)
          acc[mt][nt] = __builtin_amdgcn_mfma_f32_16x16x32_bf16(Wh[mt].v, Bl[nt].v, acc[mt][nt], 0, 0, 0);
      }
    }
  }

  if (SPLIT) {
#pragma unroll
    for (int mt = 0; mt < MT; ++mt) {
      const int ocb = mt * 16 + quad * 4;
      const int g2 = 2 * mt + (quad >> 1), slot = quad & 1;
      f32x4 bias4 = *(const f32x4*)(bias + ocb);
      f32x4 pr4 = *(const f32x4*)(pre + ocb);
      f32x4 inv4;
      if (SC) inv4 = *(const f32x4*)(scinv + ocb);
#pragma unroll
      for (int nt = 0; nt < 4; ++nt) {
        if (!vld[nt]) continue;        // masked: clamped duplicates must not read/write
        const uint32 ppix = boff[nt] + 1;
        float v[4];
#pragma unroll
        for (int r = 0; r < 4; ++r) v[r] = acc[mt][nt][r] + bias4[r];
        if (SC) {
          const uint2* rec = scact + ((size_t)(sc * (COUT / 8) + g2) * PPLANE + ppix) * 4;
          uint2 hi = rec[slot], lo = rec[2 + slot];
          float s0 = __uint_as_float(hi.x << 16) + __uint_as_float(lo.x << 16);
          float s1 = __uint_as_float(hi.x & 0xFFFF0000u) + __uint_as_float(lo.x & 0xFFFF0000u);
          float s2 = __uint_as_float(hi.y << 16) + __uint_as_float(lo.y << 16);
          float s3 = __uint_as_float(hi.y & 0xFFFF0000u) + __uint_as_float(lo.y & 0xFFFF0000u);
          v[0] += (s0 >= 0.f) ? s0 : s0 * inv4[0];
          v[1] += (s1 >= 0.f) ? s1 : s1 * inv4[1];
          v[2] += (s2 >= 0.f) ? s2 : s2 * inv4[2];
          v[3] += (s3 >= 0.f) ? s3 : s3 * inv4[3];
        }
        float t0 = fmaxf(v[0], 0.f) + pr4[0] * fminf(v[0], 0.f);
        float t1 = fmaxf(v[1], 0.f) + pr4[1] * fminf(v[1], 0.f);
        float t2 = fmaxf(v[2], 0.f) + pr4[2] * fminf(v[2], 0.f);
        float t3 = fmaxf(v[3], 0.f) + pr4[3] * fminf(v[3], 0.f);
        uint2 sp0 = split_pack(t0, t1), sp1 = split_pack(t2, t3);
        uint2* opb = actout + (size_t)(sc * (COUT / 8) + g2) * PPLANE * 4;
        int oidx = (int)ppix * 4;
        store_halo_s<uint2, 4>(opb, (int)px[nt], (int)py[nt], oidx + slot,     make_uint2(sp0.x, sp1.x));
        store_halo_s<uint2, 4>(opb, (int)px[nt], (int)py[nt], oidx + 2 + slot, make_uint2(sp0.y, sp1.y));
      }
    }
  } else {
    // fused convT channel contraction: s_t = sum_ch wT[t][ch]*(acc+bias)
    float4 b4[MT];
#pragma unroll
    for (int mt = 0; mt < MT; ++mt) b4[mt] = *(const float4*)(bias + mt * 16 + quad * 4);
#pragma unroll
    for (int nt = 0; nt < 4; ++nt) {
      float vv[MT][4];
#pragma unroll
      for (int mt = 0; mt < MT; ++mt) {
        vv[mt][0] = acc[mt][nt][0] + b4[mt].x;
        vv[mt][1] = acc[mt][nt][1] + b4[mt].y;
        vv[mt][2] = acc[mt][nt][2] + b4[mt].z;
        vv[mt][3] = acc[mt][nt][3] + b4[mt].w;
      }
      float* sp = sout + (size_t)sc * 25 * PLANE + (int)(py[nt] * 270 + px[nt]);
#pragma unroll
      for (int t = 0; t < 25; ++t) {
        const float* wp = wTt + t * 32 + quad * 4;
        float c = 0.f;
#pragma unroll
        for (int mt = 0; mt < MT; ++mt) {
          float4 w4 = *(const float4*)(wp + mt * 16);
          c += w4.x * vv[mt][0] + w4.y * vv[mt][1] + w4.z * vv[mt][2] + w4.w * vv[mt][3];
        }
        c += __shfl_xor(c, 16, 64);        // vld is quad-uniform: shuffles stay uniform
        c += __shfl_xor(c, 32, 64);
        if (quad == 0 && vld[nt]) sp[(size_t)t * PLANE] = c;
      }
    }
  }
}

// ---------------- convT pass 2: out = bt + sum_t s_t(shifted) ----------------
__global__ __launch_bounds__(256) void k_convT2(const float* __restrict__ s, const float* __restrict__ bt,
                                                float* __restrict__ yo) {
  int p = blockIdx.x * 256 + threadIdx.x;
  if (p >= PLANE) return;
  int sc = blockIdx.y;
  int y = p / 270, x = p - y * 270;
  float acc = bt[0];
  const float* sb = s + (size_t)sc * 25 * PLANE;
#pragma unroll
  for (int a = 0; a < 5; ++a) {
    int yy = y + a - 2;
    if ((unsigned)yy >= 270u) continue;
    const float* row = sb + (size_t)(a * 5) * PLANE + yy * 270;
#pragma unroll
    for (int b = 0; b < 5; ++b) {
      int xx = x + b - 2;
      if ((unsigned)xx < 270u) acc += row[(size_t)b * PLANE + xx];
    }
  }
  yo[(size_t)sc * PLANE + p] = acc;
}

// ---------------- norm projection scale ----------------
__global__ __launch_bounds__(256) void k_nrm(const float* __restrict__ yb, float* __restrict__ red) {
  int s = blockIdx.x;
  const float* ys = yb + (size_t)s * PLANE;
  float acc = 0.f;
  for (int i = threadIdx.x; i < PLANE; i += 256) { float v = ys[i]; acc += v * v; }
  float tot = blockReduceSum(acc);
  if (threadIdx.x == 0) {
    float nrm = sqrtf(tot);
    float eps = red[8 + s];
    red[16 + s] = (nrm > eps) ? eps / fmaxf(nrm, 1e-12f) : 1.0f;
  }
}

// ---------------- final: clip(z - scl*y), crop, mix ----------------
__global__ __launch_bounds__(256) void k_final(const float* __restrict__ z, const float* __restrict__ yb,
                                               const float* __restrict__ red, const float* __restrict__ mw,
                                               float* __restrict__ out) {
  int idx = blockIdx.x * 256 + threadIdx.x;
  if (idx >= 131072) return;
  int b = idx >> 16;
  int rem = idx & 65535;
  int h = rem >> 8, w = rem & 255;
  int p = (h + 7) * HP + (w + 7);
  float acc = 0.f;
#pragma unroll
  for (int d = 0; d < 4; ++d) {
    int s = b * 4 + d;
    float v = z[(size_t)s * PLANE + p] - red[16 + s] * yb[(size_t)s * PLANE + p];
    v = fminf(fmaxf(v, 0.f), 255.f);
    acc += mw[d] * v;
  }
  out[idx] = acc;
}

// =====================================================================
extern "C" void kernel_launch(void* const* d_in, const int* in_sizes, int n_in,
                              void* d_out, int out_size, void* d_ws, size_t ws_size,
                              hipStream_t stream) {
  (void)in_sizes; (void)n_in; (void)out_size;
  const float* x    = (const float*)d_in[0];
  const float* bk   = (const float*)d_in[1];
  const float* stdn = (const float*)d_in[2];
  const float* ww   = (const float*)d_in[3];
  const float* wwsc = (const float*)d_in[4];
  const float* alph = (const float*)d_in[5];
  const float* cw   = (const float*)d_in[6];
  const float* sf   = (const float*)d_in[7];
  const float* bf   = (const float*)d_in[8];
  const float* bt   = (const float*)d_in[9];
  const float* p1   = (const float*)d_in[10];
  const float* w1   = (const float*)d_in[11];
  const float* s1   = (const float*)d_in[12];
  const float* b1   = (const float*)d_in[13];
  const float* p2   = (const float*)d_in[14];
  const float* w2   = (const float*)d_in[15];
  const float* s2   = (const float*)d_in[16];
  const float* b2   = (const float*)d_in[17];
  const float* apj  = (const float*)d_in[18];
  const float* mwp  = (const float*)d_in[19];
  float* out = (float*)d_out;

  char* wsbase = (char*)d_ws;
  size_t off = 0;
  auto alloc = [&](size_t nbytes) -> char* {
    char* p = wsbase + off;
    off = (off + nbytes + 255) & ~(size_t)255;
    return p;
  };
  // ---- persistent region ----
  float*  zb  = (float*)alloc(8 * (size_t)PLANE * 4);
  float*  yb  = (float*)alloc(8 * (size_t)PLANE * 4);
  float*  red = (float*)alloc(64 * 4);
  float*  inv = (float*)alloc(32 * 4);
  float*  cwn = (float*)alloc(800 * 4);
  float*  wTt = (float*)alloc(800 * 4);
  unsigned short* w1f = (unsigned short*)alloc(5 * 36864 * (size_t)2);
  unsigned short* w2f = (unsigned short*)alloc(5 * 36864 * (size_t)2);
  // ---- union region ----
  size_t U0 = off;
  // DFT view
  float2* tw  = (float2*)alloc(2 * (size_t)PLANE * 4);
  float*  xp  = (float*)alloc(2 * (size_t)PLANE * 4);
  float*  rtm = (float*)alloc(2 * (size_t)PLANE * 4);
  float2* cb0 = (float2*)alloc(2 * 8 * (size_t)PLANE * 8);
  float2* cb1 = (float2*)alloc(2 * 8 * (size_t)PLANE * 8);
  float2* Yb  = (float2*)alloc(2 * 2 * (size_t)PLANE * 8);
  float2* Hf  = (float2*)alloc(2 * (size_t)PLANE * 4);
  float*  Sb  = (float*)alloc((size_t)PLANE * 4);
  float2* Tb  = (float2*)alloc(2 * 4 * (size_t)PLANE * 4);
  float*  ahw = (float*)alloc(540 * 4);
  float*  wwn = (float*)alloc(600 * 4);
  // conv view (aliases the DFT view). Chunk size S = 8 if workspace allows, else 4.
  size_t conv8 = (size_t)8 * 4 * PPLANE * 32 + 256 + (size_t)8 * 8 * PPLANE * 32 + 256;
  int S = (ws_size >= U0 + conv8) ? 8 : 4;
  int nc = 8 / S;
  off = U0;
  uint4* act1 = (uint4*)alloc((size_t)S * 4 * PPLANE * 32);   // 32ch split acts; aliases sOb (S*25*PLANE f32)
  uint4* act2 = (uint4*)alloc((size_t)S * 8 * PPLANE * 32);   // 64ch split acts
  float* sOb = (float*)act1;

  // setup
  k_twiddle<<<285, 256, 0, stream>>>(tw);
  k_sympad<<<(2 * PLANE + 255) / 256, 256, 0, stream>>>(x, xp);
  k_edget<<<1, 512, 0, stream>>>(bk, ahw);
  k_Hf<<<285, 256, 0, stream>>>(bk, Hf);
  k_wnorm<<<24, 256, 0, stream>>>(ww, wwsc, wwn, 25);
  k_wnorm<<<32, 256, 0, stream>>>(cw, sf, cwn, 25);
  k_wT<<<4, 256, 0, stream>>>(cwn, wTt);
  k_wfrag<32, 64><<<320, 256, 0, stream>>>(w1, s1, w1f);
  k_wfrag<64, 32><<<160, 256, 0, stream>>>(w2, s2, w2f);
  k_inv<<<1, 32, 0, stream>>>(p1, inv);
  k_S<<<285, 256, 0, stream>>>(wwn, Sb);
  k_T<<<(4 * PLANE + 255) / 256, 256, 0, stream>>>(Hf, Sb, alph, Tb);
  k_amp<<<4, 256, 0, stream>>>(Tb, red);
  k_eps<<<1, 64, 0, stream>>>(apj, stdn, red);

  dim3 g2(5, 45, 2), g8(5, 45, 8);

  // edgetaper
  k_rowT<6, true ><<<g2, 64, 0, stream>>>(xp, cb1, tw, -1.f);
  k_colT<6, false><<<g2, 64, 0, stream>>>(cb1, cb0, tw, -1.f, 1.f);
  k_mulHf<<<(2 * PLANE + 255) / 256, 256, 0, stream>>>(cb0, Hf, cb1);
  k_rowT<6, false><<<g2, 64, 0, stream>>>(cb1, cb0, tw, 1.f);
  k_colT<6, true ><<<g2, 64, 0, stream>>>(cb0, rtm, tw, 1.f, 1.f / (float)PLANE);
  k_taper<<<(2 * PLANE + 255) / 256, 256, 0, stream>>>(xp, rtm, ahw);

  // Y = fft2(xp)
  k_rowT<6, true ><<<g2, 64, 0, stream>>>(xp, cb1, tw, -1.f);
  k_colT<6, false><<<g2, 64, 0, stream>>>(cb1, Yb, tw, -1.f, 1.f);

  // z = ifft2(T*Y).real for all 8 (b,d)
  k_mulTY<<<(8 * PLANE + 255) / 256, 256, 0, stream>>>(Tb, Yb, cb0);
  k_rowT<6, false><<<g8, 64, 0, stream>>>(cb0, cb1, tw, 1.f);
  k_colT<6, true ><<<g8, 64, 0, stream>>>(cb1, zb, tw, 1.f, 1.f / (float)PLANE);

  // conv net, nc chunks of S samples; 40 KiB dynamic LDS throttles mconv to 4 blocks/CU
  const uint32 THROT = 40960;
  for (int c = 0; c < nc; ++c) {
    const float* zc = zb + (size_t)c * S * PLANE;
    float* ybc = yb + (size_t)c * S * PLANE;
    k_conv5<<<dim3(285, S), 256, 0, stream>>>(zc, cwn, bf, p1, act1);
    for (int i = 0; i < 5; ++i) {
      k_mconv<32, 64, false, true><<<dim3(289, S), 256, THROT, stream>>>(
          act1, w1f + (size_t)i * 36864, b1 + i * 64, p2 + i * 64, (uint2*)act2, nullptr, nullptr, nullptr, nullptr);
      if (i == 0)
        k_mconv<64, 32, true, true><<<dim3(289, S), 256, THROT, stream>>>(
            act2, w2f + (size_t)i * 36864, b2 + i * 32, p1 + (i + 1) * 32, (uint2*)act1, nullptr, (const uint2*)act1, inv, nullptr);
      else if (i < 4)
        k_mconv<64, 32, false, true><<<dim3(289, S), 256, THROT, stream>>>(
            act2, w2f + (size_t)i * 36864, b2 + i * 32, p1 + (i + 1) * 32, (uint2*)act1, nullptr, nullptr, nullptr, nullptr);
      else
        k_mconv<64, 32, false, false><<<dim3(289, S), 256, THROT, stream>>>(
            act2, w2f + (size_t)i * 36864, b2 + i * 32, nullptr, nullptr, sOb, nullptr, nullptr, wTt);
    }
    k_convT2<<<dim3(285, S), 256, 0, stream>>>(sOb, bt, ybc);
  }

  // projection + final mix
  k_nrm<<<8, 256, 0, stream>>>(yb, red);
  k_final<<<(131072 + 255) / 256, 256, 0, stream>>>(zb, yb, red, mwp, out);
}

// Round 11
// 1807.169 us; speedup vs baseline: 1.2493x; 1.1853x over previous
//
#include <hip/hip_runtime.h>
#include <math.h>

#define HP     270
#define PLANE  72900      // 270*270
#define PW     272
#define PPLANE 73984      // 272*272

typedef unsigned int uint32;
typedef __attribute__((ext_vector_type(8))) short bf16x8;
typedef __attribute__((ext_vector_type(4))) float f32x4;

// ---------------- reduction helper ----------------
__device__ __forceinline__ float blockReduceSum(float val) {
  __shared__ float sh[16];
  int lane = threadIdx.x & 63, wid = threadIdx.x >> 6;
#pragma unroll
  for (int o = 32; o > 0; o >>= 1) val += __shfl_down(val, o, 64);
  __syncthreads();
  if (lane == 0) sh[wid] = val;
  __syncthreads();
  float tot = 0.f;
  int nw = (blockDim.x + 63) >> 6;
  for (int i = 0; i < nw; ++i) tot += sh[i];
  return tot;
}

// ---------------- twiddle matrix ----------------
__global__ __launch_bounds__(256) void k_twiddle(float2* __restrict__ tw) {
  int idx = blockIdx.x * 256 + threadIdx.x;
  if (idx >= PLANE) return;
  int j = idx / HP, k = idx % HP;
  int m = (j * k) % HP;
  double ang = (2.0 * M_PI * (double)m) / 270.0;
  tw[idx] = make_float2((float)cos(ang), (float)sin(ang));
}

// ---------------- symmetric pad x (2,256,256) -> xp (2,270,270), pad 7 ----------------
__global__ __launch_bounds__(256) void k_sympad(const float* __restrict__ x, float* __restrict__ xp) {
  int idx = blockIdx.x * 256 + threadIdx.x;
  if (idx >= 2 * PLANE) return;
  int b = idx / PLANE, p = idx % PLANE;
  int i = p / HP, j = p % HP;
  int si = i - 7; si = si < 0 ? -1 - si : (si > 255 ? 511 - si : si);
  int sj = j - 7; sj = sj < 0 ? -1 - sj : (sj > 255 ? 511 - sj : sj);
  xp[idx] = x[(b * 256 + si) * 256 + sj];
}

// ---------------- edgetaper 1D weights ----------------
__global__ __launch_bounds__(512) void k_edget(const float* __restrict__ bk, float* __restrict__ ahw) {
  __shared__ float pr[15], pc[15], acr[15], accl[15];
  int t = threadIdx.x;
  if (t < 15) {
    float sr = 0.f, scv = 0.f;
    for (int k = 0; k < 15; ++k) { sr += bk[t * 15 + k]; scv += bk[k * 15 + t]; }
    pr[t] = sr; pc[t] = scv;
  }
  __syncthreads();
  if (t < 30) {
    int l = t % 15; bool isr = (t < 15);
    const float* p = isr ? pr : pc;
    float s = 0.f;
    for (int j = 0; j + l < 15; ++j) s += p[j] * p[j + l];
    if (isr) acr[l] = s; else accl[l] = s;
  }
  __syncthreads();
  for (int i = t; i < 540; i += blockDim.x) {
    bool isr = (i < 270);
    int ii = isr ? i : i - 270;
    const float* ac = isr ? acr : accl;
    int m = (ii == 269) ? 0 : ii;
    float zv;
    if (m < 15) zv = ac[m];
    else if (m >= 255) zv = ac[269 - m];
    else zv = 0.f;
    ahw[i] = 1.f - zv / ac[0];
  }
}

// ---------------- Hf = psf2otf(blur 15x15) ----------------
__global__ __launch_bounds__(256) void k_Hf(const float* __restrict__ bk, float2* __restrict__ Hf) {
  int p = blockIdx.x * 256 + threadIdx.x;
  if (p >= PLANE) return;
  int u = p / HP, v = p % HP;
  float2 er[15], es[15];
#pragma unroll
  for (int r = 0; r < 15; ++r) {
    int m = ((u * (r - 7)) % HP + HP) % HP;
    float sn, cs;
    sincosf(2.f * (float)M_PI * (float)m / 270.f, &sn, &cs);
    er[r] = make_float2(cs, -sn);
    int m2 = ((v * (r - 7)) % HP + HP) % HP;
    sincosf(2.f * (float)M_PI * (float)m2 / 270.f, &sn, &cs);
    es[r] = make_float2(cs, -sn);
  }
  float ar = 0.f, ai = 0.f;
#pragma unroll 1
  for (int r = 0; r < 15; ++r) {
    float rr = 0.f, ri = 0.f;
#pragma unroll
    for (int s = 0; s < 15; ++s) {
      float wv = bk[r * 15 + s];
      rr += wv * es[s].x; ri += wv * es[s].y;
    }
    ar += er[r].x * rr - er[r].y * ri;
    ai += er[r].x * ri + er[r].y * rr;
  }
  Hf[p] = make_float2(ar, ai);
}

// ---------------- weight normalization, plain layout ----------------
__global__ __launch_bounds__(256) void k_wnorm(const float* __restrict__ w, const float* __restrict__ scale,
                                               float* __restrict__ out, int fsize) {
  int f = blockIdx.x;
  const float* wf = w + (size_t)f * fsize;
  float s = 0.f;
  for (int i = threadIdx.x; i < fsize; i += 256) s += wf[i];
  float mean = blockReduceSum(s) / (float)fsize;
  float s2 = 0.f;
  for (int i = threadIdx.x; i < fsize; i += 256) { float d = wf[i] - mean; s2 += d * d; }
  float nrm = sqrtf(blockReduceSum(s2));
  float sc = scale[f] / nrm;
  for (int i = threadIdx.x; i < fsize; i += 256) out[(size_t)f * fsize + i] = (wf[i] - mean) * sc;
}

// ---------------- transpose conv5 weights to tap-major (flipped) ----------------
__global__ void k_wT(const float* __restrict__ cwn, float* __restrict__ wT) {
  int idx = blockIdx.x * 256 + threadIdx.x;
  if (idx >= 800) return;
  int t = idx >> 5, f = idx & 31;
  int dri = t / 5, dci = t % 5;           // input offsets dr = dri-2, dc = dci-2
  wT[t * 32 + f] = cwn[f * 25 + (4 - dri) * 5 + (4 - dci)];
}

// ---------------- weight normalization -> split-bf16 MFMA fragment layout ----------------
template <int CIN, int COUT>
__global__ __launch_bounds__(256) void k_wfrag(const float* __restrict__ w, const float* __restrict__ scale,
                                               unsigned short* __restrict__ outb) {
  constexpr int KC = CIN / 32, MT = COUT / 16, FS = CIN * 9;
  int fg = blockIdx.x;
  int f = fg % COUT, iter = fg / COUT;
  const float* wf = w + (size_t)fg * FS;
  float s = 0.f;
  for (int i = threadIdx.x; i < FS; i += 256) s += wf[i];
  float mean = blockReduceSum(s) / (float)FS;
  float s2 = 0.f;
  for (int i = threadIdx.x; i < FS; i += 256) { float d = wf[i] - mean; s2 += d * d; }
  float nrm = sqrtf(blockReduceSum(s2));
  float scv = scale[fg] / nrm;
  unsigned short* dst0 = outb + (size_t)iter * (9 * KC * MT * 64 * 16);
  for (int i = threadIdx.x; i < FS; i += 256) {
    float val = (wf[i] - mean) * scv;
    int ci = i / 9, rs = i - ci * 9;
    int kc = ci >> 5, cil = ci & 31, q = cil >> 3, j = cil & 7;
    int mt = f >> 4, ocl = f & 15, lane = q * 16 + ocl;
    unsigned short* d2 = dst0 + ((((rs * KC + kc) * MT + mt) * 64 + lane) * 16);
    uint32 u = __float_as_uint(val);
    d2[j] = (unsigned short)(u >> 16);
    float lof = val - __uint_as_float(u & 0xFFFF0000u);
    d2[8 + j] = (unsigned short)(__float_as_uint(lof) >> 16);
  }
}

// ---------------- S = sum_f |FT(ww_f 5x5)|^2 ----------------
__global__ __launch_bounds__(256) void k_S(const float* __restrict__ wwn, float* __restrict__ S) {
  int p = blockIdx.x * 256 + threadIdx.x;
  if (p >= PLANE) return;
  int u = p / HP, v = p % HP;
  float2 er[5], es[5];
#pragma unroll
  for (int r = 0; r < 5; ++r) {
    float sn, cs;
    int m = (u * r) % HP;
    sincosf(2.f * (float)M_PI * (float)m / 270.f, &sn, &cs);
    er[r] = make_float2(cs, -sn);
    int m2 = (v * r) % HP;
    sincosf(2.f * (float)M_PI * (float)m2 / 270.f, &sn, &cs);
    es[r] = make_float2(cs, -sn);
  }
  float prr[25], pii[25];
#pragma unroll
  for (int r = 0; r < 5; ++r)
#pragma unroll
    for (int s = 0; s < 5; ++s) {
      prr[r * 5 + s] = er[r].x * es[s].x - er[r].y * es[s].y;
      pii[r * 5 + s] = er[r].x * es[s].y + er[r].y * es[s].x;
    }
  float acc = 0.f;
#pragma unroll 1
  for (int f = 0; f < 24; ++f) {
    float xr = 0.f, xi = 0.f;
#pragma unroll
    for (int t = 0; t < 25; ++t) {
      float wv = wwn[f * 25 + t];
      xr += wv * prr[t]; xi += wv * pii[t];
    }
    acc += xr * xr + xi * xi;
  }
  S[p] = acc;
}

// ---------------- T = conj(Hf)/(|Hf|^2 + a_d S) ----------------
__global__ __launch_bounds__(256) void k_T(const float2* __restrict__ Hf, const float* __restrict__ S,
                                           const float* __restrict__ alpha, float2* __restrict__ T) {
  int idx = blockIdx.x * 256 + threadIdx.x;
  if (idx >= 4 * PLANE) return;
  int d = idx / PLANE, p = idx % PLANE;
  float a = expf(alpha[d]);
  float2 h = Hf[p];
  float den = h.x * h.x + h.y * h.y + a * S[p];
  T[idx] = make_float2(h.x / den, -h.y / den);
}

__global__ __launch_bounds__(256) void k_amp(const float2* __restrict__ T, float* __restrict__ red) {
  int d = blockIdx.x;
  const float2* Td = T + (size_t)d * PLANE;
  float acc = 0.f;
  for (int i = threadIdx.x; i < PLANE; i += 256) { float2 t = Td[i]; acc += t.x * t.x + t.y * t.y; }
  float tot = blockReduceSum(acc);
  if (threadIdx.x == 0) red[d] = tot / (float)PLANE;
}

__global__ void k_eps(const float* __restrict__ apj, const float* __restrict__ stdn, float* __restrict__ red) {
  int s = threadIdx.x;
  if (s < 8) {
    int b = s >> 2, d = s & 3;
    red[8 + s] = expf(apj[0]) * stdn[b] * sqrtf(red[d]) * sqrtf(72899.f);
  }
}

__global__ void k_inv(const float* __restrict__ p, float* __restrict__ inv) {
  int t = threadIdx.x;
  if (t < 32) inv[t] = 1.f / p[t];
}

// ---------------- register-tiled DFT passes ----------------
template <int NR, bool REALIN>
__global__ __launch_bounds__(64) void k_rowT(const void* __restrict__ inv_, float2* __restrict__ out,
                                             const float2* __restrict__ tw, float sgn) {
  int v = blockIdx.x * 64 + threadIdx.x;
  int r0 = blockIdx.y * NR;
  int m = blockIdx.z;
  bool ok = v < HP;
  int vc = ok ? v : 0;
  float P[NR], R[NR], Q[NR], Sm[NR];
#pragma unroll
  for (int i = 0; i < NR; ++i) { P[i] = R[i] = 0.f; if (!REALIN) { Q[i] = Sm[i] = 0.f; } }
  const float*  inR = (const float*)inv_  + ((size_t)m * HP + r0) * HP;
  const float2* inC = (const float2*)inv_ + ((size_t)m * HP + r0) * HP;
#pragma unroll 3
  for (int w = 0; w < HP; ++w) {
    float2 t = tw[w * HP + vc];
#pragma unroll
    for (int i = 0; i < NR; ++i) {
      if (REALIN) {
        float a = inR[i * HP + w];
        P[i] += a * t.x; R[i] += a * t.y;
      } else {
        float2 g = inC[i * HP + w];
        P[i] += g.x * t.x; Q[i] += g.y * t.y;
        R[i] += g.x * t.y; Sm[i] += g.y * t.x;
      }
    }
  }
  if (ok) {
#pragma unroll
    for (int i = 0; i < NR; ++i) {
      float ar, ai;
      if (REALIN) { ar = P[i]; ai = sgn * R[i]; }
      else        { ar = P[i] - sgn * Q[i]; ai = sgn * R[i] + Sm[i]; }
      out[((size_t)m * HP + r0 + i) * HP + v] = make_float2(ar, ai);
    }
  }
}

template <int NU, bool REALOUT>
__global__ __launch_bounds__(64) void k_colT(const float2* __restrict__ in, void* __restrict__ outv,
                                             const float2* __restrict__ tw, float sgn, float scale) {
  int v = blockIdx.x * 64 + threadIdx.x;
  int u0 = blockIdx.y * NU;
  int m = blockIdx.z;
  bool ok = v < HP;
  int vc = ok ? v : 0;
  float P[NU], Q[NU], R[NU], Sm[NU];
#pragma unroll
  for (int j = 0; j < NU; ++j) { P[j] = Q[j] = 0.f; if (!REALOUT) { R[j] = Sm[j] = 0.f; } }
  const float2* cp = in + (size_t)m * PLANE + vc;
#pragma unroll 3
  for (int h = 0; h < HP; ++h) {
    float2 g = cp[(size_t)h * HP];
    const float2* tr = tw + h * HP + u0;
#pragma unroll
    for (int j = 0; j < NU; ++j) {
      float2 t = tr[j];
      P[j] += g.x * t.x; Q[j] += g.y * t.y;
      if (!REALOUT) { R[j] += g.x * t.y; Sm[j] += g.y * t.x; }
    }
  }
  if (ok) {
#pragma unroll
    for (int j = 0; j < NU; ++j) {
      float ar = (P[j] - sgn * Q[j]) * scale;
      if (REALOUT) ((float*)outv)[((size_t)m * HP + u0 + j) * HP + v] = ar;
      else {
        float ai = (sgn * R[j] + Sm[j]) * scale;
        ((float2*)outv)[((size_t)m * HP + u0 + j) * HP + v] = make_float2(ar, ai);
      }
    }
  }
}

// ---------------- pointwise ----------------
__global__ __launch_bounds__(256) void k_mulHf(const float2* __restrict__ in, const float2* __restrict__ Hf,
                                               float2* __restrict__ out) {
  int idx = blockIdx.x * 256 + threadIdx.x;
  if (idx >= 2 * PLANE) return;
  int p = idx % PLANE;
  float2 a = in[idx], b = Hf[p];
  out[idx] = make_float2(a.x * b.x - a.y * b.y, a.x * b.y + a.y * b.x);
}

__global__ __launch_bounds__(256) void k_taper(float* __restrict__ xp, const float* __restrict__ blr,
                                               const float* __restrict__ ahw) {
  int idx = blockIdx.x * 256 + threadIdx.x;
  if (idx >= 2 * PLANE) return;
  int p = idx % PLANE;
  int i = p / HP, j = p % HP;
  float al = ahw[i] * ahw[270 + j];
  xp[idx] = al * xp[idx] + (1.f - al) * blr[idx];
}

__global__ __launch_bounds__(256) void k_mulTY(const float2* __restrict__ T, const float2* __restrict__ Y,
                                               float2* __restrict__ out) {
  int idx = blockIdx.x * 256 + threadIdx.x;
  if (idx >= 8 * PLANE) return;
  int s = idx / PLANE, p = idx % PLANE;
  int b = s >> 2, d = s & 3;
  float2 a = T[(size_t)d * PLANE + p], y = Y[(size_t)b * PLANE + p];
  out[idx] = make_float2(a.x * y.x - a.y * y.y, a.x * y.y + a.y * y.x);
}

// ---------------- split+pack helper ----------------
__device__ __forceinline__ uint2 split_pack(float t0, float t1) {
  uint32 u0 = __float_as_uint(t0), u1 = __float_as_uint(t1);
  uint32 hiw = (u0 >> 16) | (u1 & 0xFFFF0000u);
  float r0 = t0 - __uint_as_float(u0 & 0xFFFF0000u);
  float r1 = t1 - __uint_as_float(u1 & 0xFFFF0000u);
  uint32 low = (__float_as_uint(r0) >> 16) | (__float_as_uint(r1) & 0xFFFF0000u);
  return make_uint2(hiw, low);
}

template <typename T, int STRIDE>
__device__ __forceinline__ void store_halo_s(T* __restrict__ op, int xx, int yy, int o, T val) {
  op[o] = val;
  bool xl = (xx == 0), xr = (xx == 269), yt = (yy == 0), yb = (yy == 269);
  if (xl) op[o - STRIDE] = val;
  if (xr) op[o + STRIDE] = val;
  if (yt) { op[o - PW * STRIDE] = val; if (xl) op[o - (PW + 1) * STRIDE] = val; if (xr) op[o - (PW - 1) * STRIDE] = val; }
  if (yb) { op[o + PW * STRIDE] = val; if (xl) op[o + (PW - 1) * STRIDE] = val; if (xr) op[o + (PW + 1) * STRIDE] = val; }
}

// ---------------- first conv 5x5 1->32 -> grouped split act records ----------------
__global__ __launch_bounds__(256) void k_conv5(const float* __restrict__ z, const float* __restrict__ cw,
                                               const float* __restrict__ bias, const float* __restrict__ pre,
                                               uint4* __restrict__ actout) {
  int p = blockIdx.x * 256 + threadIdx.x;
  if (p >= PLANE) return;
  int sc = blockIdx.y;
  int i = p / HP, j = p % HP;
  const float* zs = z + (size_t)sc * PLANE;
  float v[25];
#pragma unroll
  for (int r = 0; r < 5; ++r) {
    int ii = i + r - 2; ii = ii < 0 ? -1 - ii : (ii > 269 ? 539 - ii : ii);
#pragma unroll
    for (int s = 0; s < 5; ++s) {
      int jj = j + s - 2; jj = jj < 0 ? -1 - jj : (jj > 269 ? 539 - jj : jj);
      v[r * 5 + s] = zs[ii * HP + jj];
    }
  }
  int o = (i + 1) * PW + (j + 1);
#pragma unroll 1
  for (int g = 0; g < 4; ++g) {
    float tt[8];
#pragma unroll
    for (int r8 = 0; r8 < 8; ++r8) {
      int oc = 8 * g + r8;
      float a = bias[oc];
#pragma unroll
      for (int k = 0; k < 25; ++k) a += cw[oc * 25 + k] * v[k];
      float pa = pre[oc];
      tt[r8] = fmaxf(a, 0.f) + pa * fminf(a, 0.f);
    }
    uint2 sp0 = split_pack(tt[0], tt[1]), sp1 = split_pack(tt[2], tt[3]);
    uint2 sp2 = split_pack(tt[4], tt[5]), sp3 = split_pack(tt[6], tt[7]);
    uint4 hi = make_uint4(sp0.x, sp1.x, sp2.x, sp3.x);
    uint4 lo = make_uint4(sp0.y, sp1.y, sp2.y, sp3.y);
    uint4* opb = actout + (size_t)(sc * 4 + g) * PPLANE * 2;
    store_halo_s<uint4, 2>(opb, j, i, o * 2, hi);
    store_halo_s<uint4, 2>(opb, j, i, o * 2 + 1, lo);
  }
}

// ---------------- MFMA 3x3 conv with LDS tile staging ----------------
// Block = 16x16 pixel tile. Per 32-channel kc slice: stage the 18x18 input tile
// (4 records x 32B per pixel, pixel stride padded to 144B for b128 alignment)
// into LDS with coalesced global reads; all 9 taps then read B via ds_read_b128.
// Out-of-range lanes clamp loads; masked from all epilogue reads/writes (vld).
#define TSTRIDE 144
template <int CIN, int COUT, bool SC, bool SPLIT>
__global__ __launch_bounds__(256, 3) void k_mconv(
    const uint4* __restrict__ act, const unsigned short* __restrict__ wf,
    const float* __restrict__ bias, const float* __restrict__ pre,
    uint2* __restrict__ actout, float* __restrict__ sout,
    const uint2* __restrict__ scact, const float* __restrict__ scinv,
    const float* __restrict__ wTt) {
  constexpr int KC = CIN / 32, MT = COUT / 16;
  __shared__ uint4 smem4[18 * 18 * TSTRIDE / 16];
  unsigned char* smem = (unsigned char*)smem4;

  const int lane = threadIdx.x & 63, wv = threadIdx.x >> 6;
  const int quad = lane >> 4, col = lane & 15;
  const int sc = blockIdx.y;
  // XCD band swizzle: 289 tiles -> 8 bands of 36 (+1 tail)
  int bx = blockIdx.x;
  int tile = (bx < 288) ? ((bx & 7) * 36 + (bx >> 3)) : 288;
  const int tx0 = (tile % 17) * 16, ty0 = (tile / 17) * 16;

  uint32 py[4], px[4], boff[4];
  bool vld[4];
#pragma unroll
  for (int nt = 0; nt < 4; ++nt) {
    int xr = tx0 + col, yr = ty0 + wv * 4 + nt;
    vld[nt] = (xr < 270) && (yr < 270);
    int xx = xr > 269 ? 269 : xr;
    int yy = yr > 269 ? 269 : yr;
    px[nt] = xx; py[nt] = yy;
    boff[nt] = (yy + 1) * PW + xx;
  }

  f32x4 acc[MT][4];
#pragma unroll
  for (int mt = 0; mt < MT; ++mt)
#pragma unroll
    for (int nt = 0; nt < 4; ++nt) { f32x4 z = {0.f, 0.f, 0.f, 0.f}; acc[mt][nt] = z; }

#pragma unroll 1
  for (int kc = 0; kc < KC; ++kc) {
    if (kc > 0) __syncthreads();
    // ---- stage: 18x18 pixels x 4 records x {hi,lo} = 2592 uint4, coalesced ----
    {
      const uint4* srcb = act + ((size_t)(sc * (CIN / 8) + kc * 4)) * PPLANE * 2;
      for (int i = threadIdx.x; i < 2592; i += 256) {
        int h = i & 1;
        int pp = i >> 1;
        int g = pp / 324;
        int pxl = pp - g * 324;
        int pyy = pxl / 18, pxx = pxl - pyy * 18;
        int gy = ty0 + pyy; if (gy > 271) gy = 271;
        int gx = tx0 + pxx; if (gx > 271) gx = 271;
        uint4 v = srcb[((size_t)g * PPLANE + gy * PW + gx) * 2 + h];
        *(uint4*)(smem + pxl * TSTRIDE + g * 32 + h * 16) = v;
      }
    }
    __syncthreads();

    // ---- compute 9 taps from LDS ----
#pragma unroll
    for (int o = 0; o < 9; ++o) {
      const int dy = o / 3, dx = o % 3;
      union { uint4 u; bf16x8 v; } Wh[MT], Wl[MT];
#pragma unroll
      for (int mt = 0; mt < MT; ++mt) {
        const uint4* wp = (const uint4*)wf + ((((o * KC + kc) * MT + mt) * 64 + lane) * 2);
        Wh[mt].u = wp[0]; Wl[mt].u = wp[1];
      }
      const int lx = col + dx;
#pragma unroll
      for (int nt = 0; nt < 4; ++nt) {
        const int ly = wv * 4 + nt + dy;
        unsigned char* bp = smem + (ly * 18 + lx) * TSTRIDE + quad * 32;
        union { uint4 u; bf16x8 v; } Bh, Bl;
        Bh.u = *(const uint4*)bp;
        Bl.u = *(const uint4*)(bp + 16);
#pragma unroll
        for (int mt = 0; mt < MT; ++mt)
          acc[mt][nt] = __builtin_amdgcn_mfma_f32_16x16x32_bf16(Wh[mt].v, Bh.v, acc[mt][nt], 0, 0, 0);
#pragma unroll
        for (int mt = 0; mt < MT; ++mt)
          acc[mt][nt] = __builtin_amdgcn_mfma_f32_16x16x32_bf16(Wl[mt].v, Bh.v, acc[mt][nt], 0, 0, 0);
#pragma unroll
        for (int mt = 0; mt < MT; ++mt)
          acc[mt][nt] = __builtin_amdgcn_mfma_f32_16x16x32_bf16(Wh[mt].v, Bl.v, acc[mt][nt], 0, 0, 0);
      }
    }
  }

  if (SPLIT) {
#pragma unroll
    for (int mt = 0; mt < MT; ++mt) {
      const int ocb = mt * 16 + quad * 4;
      const int g2 = 2 * mt + (quad >> 1), slot = quad & 1;
      f32x4 bias4 = *(const f32x4*)(bias + ocb);
      f32x4 pr4 = *(const f32x4*)(pre + ocb);
      f32x4 inv4;
      if (SC) inv4 = *(const f32x4*)(scinv + ocb);
#pragma unroll
      for (int nt = 0; nt < 4; ++nt) {
        if (!vld[nt]) continue;        // masked: clamped duplicates must not read/write
        const uint32 ppix = boff[nt] + 1;
        float v[4];
#pragma unroll
        for (int r = 0; r < 4; ++r) v[r] = acc[mt][nt][r] + bias4[r];
        if (SC) {
          const uint2* rec = scact + ((size_t)(sc * (COUT / 8) + g2) * PPLANE + ppix) * 4;
          uint2 hi = rec[slot], lo = rec[2 + slot];
          float s0 = __uint_as_float(hi.x << 16) + __uint_as_float(lo.x << 16);
          float s1 = __uint_as_float(hi.x & 0xFFFF0000u) + __uint_as_float(lo.x & 0xFFFF0000u);
          float s2 = __uint_as_float(hi.y << 16) + __uint_as_float(lo.y << 16);
          float s3 = __uint_as_float(hi.y & 0xFFFF0000u) + __uint_as_float(lo.y & 0xFFFF0000u);
          v[0] += (s0 >= 0.f) ? s0 : s0 * inv4[0];
          v[1] += (s1 >= 0.f) ? s1 : s1 * inv4[1];
          v[2] += (s2 >= 0.f) ? s2 : s2 * inv4[2];
          v[3] += (s3 >= 0.f) ? s3 : s3 * inv4[3];
        }
        float t0 = fmaxf(v[0], 0.f) + pr4[0] * fminf(v[0], 0.f);
        float t1 = fmaxf(v[1], 0.f) + pr4[1] * fminf(v[1], 0.f);
        float t2 = fmaxf(v[2], 0.f) + pr4[2] * fminf(v[2], 0.f);
        float t3 = fmaxf(v[3], 0.f) + pr4[3] * fminf(v[3], 0.f);
        uint2 sp0 = split_pack(t0, t1), sp1 = split_pack(t2, t3);
        uint2* opb = actout + (size_t)(sc * (COUT / 8) + g2) * PPLANE * 4;
        int oidx = (int)ppix * 4;
        store_halo_s<uint2, 4>(opb, (int)px[nt], (int)py[nt], oidx + slot,     make_uint2(sp0.x, sp1.x));
        store_halo_s<uint2, 4>(opb, (int)px[nt], (int)py[nt], oidx + 2 + slot, make_uint2(sp0.y, sp1.y));
      }
    }
  } else {
    // fused convT channel contraction: s_t = sum_ch wT[t][ch]*(acc+bias)
    float4 b4[MT];
#pragma unroll
    for (int mt = 0; mt < MT; ++mt) b4[mt] = *(const float4*)(bias + mt * 16 + quad * 4);
#pragma unroll
    for (int nt = 0; nt < 4; ++nt) {
      float vv[MT][4];
#pragma unroll
      for (int mt = 0; mt < MT; ++mt) {
        vv[mt][0] = acc[mt][nt][0] + b4[mt].x;
        vv[mt][1] = acc[mt][nt][1] + b4[mt].y;
        vv[mt][2] = acc[mt][nt][2] + b4[mt].z;
        vv[mt][3] = acc[mt][nt][3] + b4[mt].w;
      }
      float* sp = sout + (size_t)sc * 25 * PLANE + (int)(py[nt] * 270 + px[nt]);
#pragma unroll
      for (int t = 0; t < 25; ++t) {
        const float* wp = wTt + t * 32 + quad * 4;
        float c = 0.f;
#pragma unroll
        for (int mt = 0; mt < MT; ++mt) {
          float4 w4 = *(const float4*)(wp + mt * 16);
          c += w4.x * vv[mt][0] + w4.y * vv[mt][1] + w4.z * vv[mt][2] + w4.w * vv[mt][3];
        }
        c += __shfl_xor(c, 16, 64);        // vld is quad-uniform: shuffles stay uniform
        c += __shfl_xor(c, 32, 64);
        if (quad == 0 && vld[nt]) sp[(size_t)t * PLANE] = c;
      }
    }
  }
}

// ---------------- convT pass 2: out = bt + sum_t s_t(shifted) ----------------
__global__ __launch_bounds__(256) void k_convT2(const float* __restrict__ s, const float* __restrict__ bt,
                                                float* __restrict__ yo) {
  int p = blockIdx.x * 256 + threadIdx.x;
  if (p >= PLANE) return;
  int sc = blockIdx.y;
  int y = p / 270, x = p - y * 270;
  float acc = bt[0];
  const float* sb = s + (size_t)sc * 25 * PLANE;
#pragma unroll
  for (int a = 0; a < 5; ++a) {
    int yy = y + a - 2;
    if ((unsigned)yy >= 270u) continue;
    const float* row = sb + (size_t)(a * 5) * PLANE + yy * 270;
#pragma unroll
    for (int b = 0; b < 5; ++b) {
      int xx = x + b - 2;
      if ((unsigned)xx < 270u) acc += row[(size_t)b * PLANE + xx];
    }
  }
  yo[(size_t)sc * PLANE + p] = acc;
}

// ---------------- norm projection scale ----------------
__global__ __launch_bounds__(256) void k_nrm(const float* __restrict__ yb, float* __restrict__ red) {
  int s = blockIdx.x;
  const float* ys = yb + (size_t)s * PLANE;
  float acc = 0.f;
  for (int i = threadIdx.x; i < PLANE; i += 256) { float v = ys[i]; acc += v * v; }
  float tot = blockReduceSum(acc);
  if (threadIdx.x == 0) {
    float nrm = sqrtf(tot);
    float eps = red[8 + s];
    red[16 + s] = (nrm > eps) ? eps / fmaxf(nrm, 1e-12f) : 1.0f;
  }
}

// ---------------- final: clip(z - scl*y), crop, mix ----------------
__global__ __launch_bounds__(256) void k_final(const float* __restrict__ z, const float* __restrict__ yb,
                                               const float* __restrict__ red, const float* __restrict__ mw,
                                               float* __restrict__ out) {
  int idx = blockIdx.x * 256 + threadIdx.x;
  if (idx >= 131072) return;
  int b = idx >> 16;
  int rem = idx & 65535;
  int h = rem >> 8, w = rem & 255;
  int p = (h + 7) * HP + (w + 7);
  float acc = 0.f;
#pragma unroll
  for (int d = 0; d < 4; ++d) {
    int s = b * 4 + d;
    float v = z[(size_t)s * PLANE + p] - red[16 + s] * yb[(size_t)s * PLANE + p];
    v = fminf(fmaxf(v, 0.f), 255.f);
    acc += mw[d] * v;
  }
  out[idx] = acc;
}

// =====================================================================
extern "C" void kernel_launch(void* const* d_in, const int* in_sizes, int n_in,
                              void* d_out, int out_size, void* d_ws, size_t ws_size,
                              hipStream_t stream) {
  (void)in_sizes; (void)n_in; (void)out_size;
  const float* x    = (const float*)d_in[0];
  const float* bk   = (const float*)d_in[1];
  const float* stdn = (const float*)d_in[2];
  const float* ww   = (const float*)d_in[3];
  const float* wwsc = (const float*)d_in[4];
  const float* alph = (const float*)d_in[5];
  const float* cw   = (const float*)d_in[6];
  const float* sf   = (const float*)d_in[7];
  const float* bf   = (const float*)d_in[8];
  const float* bt   = (const float*)d_in[9];
  const float* p1   = (const float*)d_in[10];
  const float* w1   = (const float*)d_in[11];
  const float* s1   = (const float*)d_in[12];
  const float* b1   = (const float*)d_in[13];
  const float* p2   = (const float*)d_in[14];
  const float* w2   = (const float*)d_in[15];
  const float* s2   = (const float*)d_in[16];
  const float* b2   = (const float*)d_in[17];
  const float* apj  = (const float*)d_in[18];
  const float* mwp  = (const float*)d_in[19];
  float* out = (float*)d_out;

  char* wsbase = (char*)d_ws;
  size_t off = 0;
  auto alloc = [&](size_t nbytes) -> char* {
    char* p = wsbase + off;
    off = (off + nbytes + 255) & ~(size_t)255;
    return p;
  };
  // ---- persistent region ----
  float*  zb  = (float*)alloc(8 * (size_t)PLANE * 4);
  float*  yb  = (float*)alloc(8 * (size_t)PLANE * 4);
  float*  red = (float*)alloc(64 * 4);
  float*  inv = (float*)alloc(32 * 4);
  float*  cwn = (float*)alloc(800 * 4);
  float*  wTt = (float*)alloc(800 * 4);
  unsigned short* w1f = (unsigned short*)alloc(5 * 36864 * (size_t)2);
  unsigned short* w2f = (unsigned short*)alloc(5 * 36864 * (size_t)2);
  // ---- union region ----
  size_t U0 = off;
  // DFT view
  float2* tw  = (float2*)alloc(2 * (size_t)PLANE * 4);
  float*  xp  = (float*)alloc(2 * (size_t)PLANE * 4);
  float*  rtm = (float*)alloc(2 * (size_t)PLANE * 4);
  float2* cb0 = (float2*)alloc(2 * 8 * (size_t)PLANE * 8);
  float2* cb1 = (float2*)alloc(2 * 8 * (size_t)PLANE * 8);
  float2* Yb  = (float2*)alloc(2 * 2 * (size_t)PLANE * 8);
  float2* Hf  = (float2*)alloc(2 * (size_t)PLANE * 4);
  float*  Sb  = (float*)alloc((size_t)PLANE * 4);
  float2* Tb  = (float2*)alloc(2 * 4 * (size_t)PLANE * 4);
  float*  ahw = (float*)alloc(540 * 4);
  float*  wwn = (float*)alloc(600 * 4);
  // conv view (aliases the DFT view). Chunk size S = 8 if workspace allows, else 4.
  size_t conv8 = (size_t)8 * 4 * PPLANE * 32 + 256 + (size_t)8 * 8 * PPLANE * 32 + 256;
  int S = (ws_size >= U0 + conv8) ? 8 : 4;
  int nc = 8 / S;
  off = U0;
  uint4* act1 = (uint4*)alloc((size_t)S * 4 * PPLANE * 32);   // 32ch split acts; aliases sOb (S*25*PLANE f32)
  uint4* act2 = (uint4*)alloc((size_t)S * 8 * PPLANE * 32);   // 64ch split acts
  float* sOb = (float*)act1;

  // setup
  k_twiddle<<<285, 256, 0, stream>>>(tw);
  k_sympad<<<(2 * PLANE + 255) / 256, 256, 0, stream>>>(x, xp);
  k_edget<<<1, 512, 0, stream>>>(bk, ahw);
  k_Hf<<<285, 256, 0, stream>>>(bk, Hf);
  k_wnorm<<<24, 256, 0, stream>>>(ww, wwsc, wwn, 25);
  k_wnorm<<<32, 256, 0, stream>>>(cw, sf, cwn, 25);
  k_wT<<<4, 256, 0, stream>>>(cwn, wTt);
  k_wfrag<32, 64><<<320, 256, 0, stream>>>(w1, s1, w1f);
  k_wfrag<64, 32><<<160, 256, 0, stream>>>(w2, s2, w2f);
  k_inv<<<1, 32, 0, stream>>>(p1, inv);
  k_S<<<285, 256, 0, stream>>>(wwn, Sb);
  k_T<<<(4 * PLANE + 255) / 256, 256, 0, stream>>>(Hf, Sb, alph, Tb);
  k_amp<<<4, 256, 0, stream>>>(Tb, red);
  k_eps<<<1, 64, 0, stream>>>(apj, stdn, red);

  dim3 g2(5, 45, 2), g8(5, 45, 8);

  // edgetaper
  k_rowT<6, true ><<<g2, 64, 0, stream>>>(xp, cb1, tw, -1.f);
  k_colT<6, false><<<g2, 64, 0, stream>>>(cb1, cb0, tw, -1.f, 1.f);
  k_mulHf<<<(2 * PLANE + 255) / 256, 256, 0, stream>>>(cb0, Hf, cb1);
  k_rowT<6, false><<<g2, 64, 0, stream>>>(cb1, cb0, tw, 1.f);
  k_colT<6, true ><<<g2, 64, 0, stream>>>(cb0, rtm, tw, 1.f, 1.f / (float)PLANE);
  k_taper<<<(2 * PLANE + 255) / 256, 256, 0, stream>>>(xp, rtm, ahw);

  // Y = fft2(xp)
  k_rowT<6, true ><<<g2, 64, 0, stream>>>(xp, cb1, tw, -1.f);
  k_colT<6, false><<<g2, 64, 0, stream>>>(cb1, Yb, tw, -1.f, 1.f);

  // z = ifft2(T*Y).real for all 8 (b,d)
  k_mulTY<<<(8 * PLANE + 255) / 256, 256, 0, stream>>>(Tb, Yb, cb0);
  k_rowT<6, false><<<g8, 64, 0, stream>>>(cb0, cb1, tw, 1.f);
  k_colT<6, true ><<<g8, 64, 0, stream>>>(cb1, zb, tw, 1.f, 1.f / (float)PLANE);

  // conv net, nc chunks of S samples
  for (int c = 0; c < nc; ++c) {
    const float* zc = zb + (size_t)c * S * PLANE;
    float* ybc = yb + (size_t)c * S * PLANE;
    k_conv5<<<dim3(285, S), 256, 0, stream>>>(zc, cwn, bf, p1, act1);
    for (int i = 0; i < 5; ++i) {
      k_mconv<32, 64, false, true><<<dim3(289, S), 256, 0, stream>>>(
          act1, w1f + (size_t)i * 36864, b1 + i * 64, p2 + i * 64, (uint2*)act2, nullptr, nullptr, nullptr, nullptr);
      if (i == 0)
        k_mconv<64, 32, true, true><<<dim3(289, S), 256, 0, stream>>>(
            act2, w2f + (size_t)i * 36864, b2 + i * 32, p1 + (i + 1) * 32, (uint2*)act1, nullptr, (const uint2*)act1, inv, nullptr);
      else if (i < 4)
        k_mconv<64, 32, false, true><<<dim3(289, S), 256, 0, stream>>>(
            act2, w2f + (size_t)i * 36864, b2 + i * 32, p1 + (i + 1) * 32, (uint2*)act1, nullptr, nullptr, nullptr, nullptr);
      else
        k_mconv<64, 32, false, false><<<dim3(289, S), 256, 0, stream>>>(
            act2, w2f + (size_t)i * 36864, b2 + i * 32, nullptr, nullptr, sOb, nullptr, nullptr, wTt);
    }
    k_convT2<<<dim3(285, S), 256, 0, stream>>>(sOb, bt, ybc);
  }

  // projection + final mix
  k_nrm<<<8, 256, 0, stream>>>(yb, red);
  k_final<<<(131072 + 255) / 256, 256, 0, stream>>>(zb, yb, red, mwp, out);
}

// Round 12
// 1770.969 us; speedup vs baseline: 1.2748x; 1.0204x over previous
//
#include <hip/hip_runtime.h>
#include <math.h>

#define HP     270
#define PLANE  72900      // 270*270
#define PW     272
#define PPLANE 73984      // 272*272

typedef unsigned int uint32;
typedef __attribute__((ext_vector_type(8))) short bf16x8;
typedef __attribute__((ext_vector_type(4))) float f32x4;

// ---------------- reduction helper ----------------
__device__ __forceinline__ float blockReduceSum(float val) {
  __shared__ float sh[16];
  int lane = threadIdx.x & 63, wid = threadIdx.x >> 6;
#pragma unroll
  for (int o = 32; o > 0; o >>= 1) val += __shfl_down(val, o, 64);
  __syncthreads();
  if (lane == 0) sh[wid] = val;
  __syncthreads();
  float tot = 0.f;
  int nw = (blockDim.x + 63) >> 6;
  for (int i = 0; i < nw; ++i) tot += sh[i];
  return tot;
}

// ---------------- twiddle matrix ----------------
__global__ __launch_bounds__(256) void k_twiddle(float2* __restrict__ tw) {
  int idx = blockIdx.x * 256 + threadIdx.x;
  if (idx >= PLANE) return;
  int j = idx / HP, k = idx % HP;
  int m = (j * k) % HP;
  double ang = (2.0 * M_PI * (double)m) / 270.0;
  tw[idx] = make_float2((float)cos(ang), (float)sin(ang));
}

// ---------------- symmetric pad x (2,256,256) -> xp (2,270,270), pad 7 ----------------
__global__ __launch_bounds__(256) void k_sympad(const float* __restrict__ x, float* __restrict__ xp) {
  int idx = blockIdx.x * 256 + threadIdx.x;
  if (idx >= 2 * PLANE) return;
  int b = idx / PLANE, p = idx % PLANE;
  int i = p / HP, j = p % HP;
  int si = i - 7; si = si < 0 ? -1 - si : (si > 255 ? 511 - si : si);
  int sj = j - 7; sj = sj < 0 ? -1 - sj : (sj > 255 ? 511 - sj : sj);
  xp[idx] = x[(b * 256 + si) * 256 + sj];
}

// ---------------- edgetaper 1D weights ----------------
__global__ __launch_bounds__(512) void k_edget(const float* __restrict__ bk, float* __restrict__ ahw) {
  __shared__ float pr[15], pc[15], acr[15], accl[15];
  int t = threadIdx.x;
  if (t < 15) {
    float sr = 0.f, scv = 0.f;
    for (int k = 0; k < 15; ++k) { sr += bk[t * 15 + k]; scv += bk[k * 15 + t]; }
    pr[t] = sr; pc[t] = scv;
  }
  __syncthreads();
  if (t < 30) {
    int l = t % 15; bool isr = (t < 15);
    const float* p = isr ? pr : pc;
    float s = 0.f;
    for (int j = 0; j + l < 15; ++j) s += p[j] * p[j + l];
    if (isr) acr[l] = s; else accl[l] = s;
  }
  __syncthreads();
  for (int i = t; i < 540; i += blockDim.x) {
    bool isr = (i < 270);
    int ii = isr ? i : i - 270;
    const float* ac = isr ? acr : accl;
    int m = (ii == 269) ? 0 : ii;
    float zv;
    if (m < 15) zv = ac[m];
    else if (m >= 255) zv = ac[269 - m];
    else zv = 0.f;
    ahw[i] = 1.f - zv / ac[0];
  }
}

// ---------------- Hf = psf2otf(blur 15x15) ----------------
__global__ __launch_bounds__(256) void k_Hf(const float* __restrict__ bk, float2* __restrict__ Hf) {
  int p = blockIdx.x * 256 + threadIdx.x;
  if (p >= PLANE) return;
  int u = p / HP, v = p % HP;
  float2 er[15], es[15];
#pragma unroll
  for (int r = 0; r < 15; ++r) {
    int m = ((u * (r - 7)) % HP + HP) % HP;
    float sn, cs;
    sincosf(2.f * (float)M_PI * (float)m / 270.f, &sn, &cs);
    er[r] = make_float2(cs, -sn);
    int m2 = ((v * (r - 7)) % HP + HP) % HP;
    sincosf(2.f * (float)M_PI * (float)m2 / 270.f, &sn, &cs);
    es[r] = make_float2(cs, -sn);
  }
  float ar = 0.f, ai = 0.f;
#pragma unroll 1
  for (int r = 0; r < 15; ++r) {
    float rr = 0.f, ri = 0.f;
#pragma unroll
    for (int s = 0; s < 15; ++s) {
      float wv = bk[r * 15 + s];
      rr += wv * es[s].x; ri += wv * es[s].y;
    }
    ar += er[r].x * rr - er[r].y * ri;
    ai += er[r].x * ri + er[r].y * rr;
  }
  Hf[p] = make_float2(ar, ai);
}

// ---------------- weight normalization, plain layout ----------------
__global__ __launch_bounds__(256) void k_wnorm(const float* __restrict__ w, const float* __restrict__ scale,
                                               float* __restrict__ out, int fsize) {
  int f = blockIdx.x;
  const float* wf = w + (size_t)f * fsize;
  float s = 0.f;
  for (int i = threadIdx.x; i < fsize; i += 256) s += wf[i];
  float mean = blockReduceSum(s) / (float)fsize;
  float s2 = 0.f;
  for (int i = threadIdx.x; i < fsize; i += 256) { float d = wf[i] - mean; s2 += d * d; }
  float nrm = sqrtf(blockReduceSum(s2));
  float sc = scale[f] / nrm;
  for (int i = threadIdx.x; i < fsize; i += 256) out[(size_t)f * fsize + i] = (wf[i] - mean) * sc;
}

// ---------------- transpose conv5 weights to tap-major (flipped) ----------------
__global__ void k_wT(const float* __restrict__ cwn, float* __restrict__ wT) {
  int idx = blockIdx.x * 256 + threadIdx.x;
  if (idx >= 800) return;
  int t = idx >> 5, f = idx & 31;
  int dri = t / 5, dci = t % 5;           // input offsets dr = dri-2, dc = dci-2
  wT[t * 32 + f] = cwn[f * 25 + (4 - dri) * 5 + (4 - dci)];
}

// ---------------- weight normalization -> split-bf16 MFMA fragment layout ----------------
template <int CIN, int COUT>
__global__ __launch_bounds__(256) void k_wfrag(const float* __restrict__ w, const float* __restrict__ scale,
                                               unsigned short* __restrict__ outb) {
  constexpr int KC = CIN / 32, MT = COUT / 16, FS = CIN * 9;
  int fg = blockIdx.x;
  int f = fg % COUT, iter = fg / COUT;
  const float* wf = w + (size_t)fg * FS;
  float s = 0.f;
  for (int i = threadIdx.x; i < FS; i += 256) s += wf[i];
  float mean = blockReduceSum(s) / (float)FS;
  float s2 = 0.f;
  for (int i = threadIdx.x; i < FS; i += 256) { float d = wf[i] - mean; s2 += d * d; }
  float nrm = sqrtf(blockReduceSum(s2));
  float scv = scale[fg] / nrm;
  unsigned short* dst0 = outb + (size_t)iter * (9 * KC * MT * 64 * 16);
  for (int i = threadIdx.x; i < FS; i += 256) {
    float val = (wf[i] - mean) * scv;
    int ci = i / 9, rs = i - ci * 9;
    int kc = ci >> 5, cil = ci & 31, q = cil >> 3, j = cil & 7;
    int mt = f >> 4, ocl = f & 15, lane = q * 16 + ocl;
    unsigned short* d2 = dst0 + ((((rs * KC + kc) * MT + mt) * 64 + lane) * 16);
    uint32 u = __float_as_uint(val);
    d2[j] = (unsigned short)(u >> 16);
    float lof = val - __uint_as_float(u & 0xFFFF0000u);
    d2[8 + j] = (unsigned short)(__float_as_uint(lof) >> 16);
  }
}

// ---------------- S = sum_f |FT(ww_f 5x5)|^2 ----------------
__global__ __launch_bounds__(256) void k_S(const float* __restrict__ wwn, float* __restrict__ S) {
  int p = blockIdx.x * 256 + threadIdx.x;
  if (p >= PLANE) return;
  int u = p / HP, v = p % HP;
  float2 er[5], es[5];
#pragma unroll
  for (int r = 0; r < 5; ++r) {
    float sn, cs;
    int m = (u * r) % HP;
    sincosf(2.f * (float)M_PI * (float)m / 270.f, &sn, &cs);
    er[r] = make_float2(cs, -sn);
    int m2 = (v * r) % HP;
    sincosf(2.f * (float)M_PI * (float)m2 / 270.f, &sn, &cs);
    es[r] = make_float2(cs, -sn);
  }
  float prr[25], pii[25];
#pragma unroll
  for (int r = 0; r < 5; ++r)
#pragma unroll
    for (int s = 0; s < 5; ++s) {
      prr[r * 5 + s] = er[r].x * es[s].x - er[r].y * es[s].y;
      pii[r * 5 + s] = er[r].x * es[s].y + er[r].y * es[s].x;
    }
  float acc = 0.f;
#pragma unroll 1
  for (int f = 0; f < 24; ++f) {
    float xr = 0.f, xi = 0.f;
#pragma unroll
    for (int t = 0; t < 25; ++t) {
      float wv = wwn[f * 25 + t];
      xr += wv * prr[t]; xi += wv * pii[t];
    }
    acc += xr * xr + xi * xi;
  }
  S[p] = acc;
}

// ---------------- T = conj(Hf)/(|Hf|^2 + a_d S) ----------------
__global__ __launch_bounds__(256) void k_T(const float2* __restrict__ Hf, const float* __restrict__ S,
                                           const float* __restrict__ alpha, float2* __restrict__ T) {
  int idx = blockIdx.x * 256 + threadIdx.x;
  if (idx >= 4 * PLANE) return;
  int d = idx / PLANE, p = idx % PLANE;
  float a = expf(alpha[d]);
  float2 h = Hf[p];
  float den = h.x * h.x + h.y * h.y + a * S[p];
  T[idx] = make_float2(h.x / den, -h.y / den);
}

__global__ __launch_bounds__(256) void k_amp(const float2* __restrict__ T, float* __restrict__ red) {
  int d = blockIdx.x;
  const float2* Td = T + (size_t)d * PLANE;
  float acc = 0.f;
  for (int i = threadIdx.x; i < PLANE; i += 256) { float2 t = Td[i]; acc += t.x * t.x + t.y * t.y; }
  float tot = blockReduceSum(acc);
  if (threadIdx.x == 0) red[d] = tot / (float)PLANE;
}

__global__ void k_eps(const float* __restrict__ apj, const float* __restrict__ stdn, float* __restrict__ red) {
  int s = threadIdx.x;
  if (s < 8) {
    int b = s >> 2, d = s & 3;
    red[8 + s] = expf(apj[0]) * stdn[b] * sqrtf(red[d]) * sqrtf(72899.f);
  }
}

__global__ void k_inv(const float* __restrict__ p, float* __restrict__ inv) {
  int t = threadIdx.x;
  if (t < 32) inv[t] = 1.f / p[t];
}

// ---------------- register-tiled DFT passes ----------------
template <int NR, bool REALIN>
__global__ __launch_bounds__(64) void k_rowT(const void* __restrict__ inv_, float2* __restrict__ out,
                                             const float2* __restrict__ tw, float sgn) {
  int v = blockIdx.x * 64 + threadIdx.x;
  int r0 = blockIdx.y * NR;
  int m = blockIdx.z;
  bool ok = v < HP;
  int vc = ok ? v : 0;
  float P[NR], R[NR], Q[NR], Sm[NR];
#pragma unroll
  for (int i = 0; i < NR; ++i) { P[i] = R[i] = 0.f; if (!REALIN) { Q[i] = Sm[i] = 0.f; } }
  const float*  inR = (const float*)inv_  + ((size_t)m * HP + r0) * HP;
  const float2* inC = (const float2*)inv_ + ((size_t)m * HP + r0) * HP;
#pragma unroll 3
  for (int w = 0; w < HP; ++w) {
    float2 t = tw[w * HP + vc];
#pragma unroll
    for (int i = 0; i < NR; ++i) {
      if (REALIN) {
        float a = inR[i * HP + w];
        P[i] += a * t.x; R[i] += a * t.y;
      } else {
        float2 g = inC[i * HP + w];
        P[i] += g.x * t.x; Q[i] += g.y * t.y;
        R[i] += g.x * t.y; Sm[i] += g.y * t.x;
      }
    }
  }
  if (ok) {
#pragma unroll
    for (int i = 0; i < NR; ++i) {
      float ar, ai;
      if (REALIN) { ar = P[i]; ai = sgn * R[i]; }
      else        { ar = P[i] - sgn * Q[i]; ai = sgn * R[i] + Sm[i]; }
      out[((size_t)m * HP + r0 + i) * HP + v] = make_float2(ar, ai);
    }
  }
}

template <int NU, bool REALOUT>
__global__ __launch_bounds__(64) void k_colT(const float2* __restrict__ in, void* __restrict__ outv,
                                             const float2* __restrict__ tw, float sgn, float scale) {
  int v = blockIdx.x * 64 + threadIdx.x;
  int u0 = blockIdx.y * NU;
  int m = blockIdx.z;
  bool ok = v < HP;
  int vc = ok ? v : 0;
  float P[NU], Q[NU], R[NU], Sm[NU];
#pragma unroll
  for (int j = 0; j < NU; ++j) { P[j] = Q[j] = 0.f; if (!REALOUT) { R[j] = Sm[j] = 0.f; } }
  const float2* cp = in + (size_t)m * PLANE + vc;
#pragma unroll 3
  for (int h = 0; h < HP; ++h) {
    float2 g = cp[(size_t)h * HP];
    const float2* tr = tw + h * HP + u0;
#pragma unroll
    for (int j = 0; j < NU; ++j) {
      float2 t = tr[j];
      P[j] += g.x * t.x; Q[j] += g.y * t.y;
      if (!REALOUT) { R[j] += g.x * t.y; Sm[j] += g.y * t.x; }
    }
  }
  if (ok) {
#pragma unroll
    for (int j = 0; j < NU; ++j) {
      float ar = (P[j] - sgn * Q[j]) * scale;
      if (REALOUT) ((float*)outv)[((size_t)m * HP + u0 + j) * HP + v] = ar;
      else {
        float ai = (sgn * R[j] + Sm[j]) * scale;
        ((float2*)outv)[((size_t)m * HP + u0 + j) * HP + v] = make_float2(ar, ai);
      }
    }
  }
}

// ---------------- pointwise ----------------
__global__ __launch_bounds__(256) void k_mulHf(const float2* __restrict__ in, const float2* __restrict__ Hf,
                                               float2* __restrict__ out) {
  int idx = blockIdx.x * 256 + threadIdx.x;
  if (idx >= 2 * PLANE) return;
  int p = idx % PLANE;
  float2 a = in[idx], b = Hf[p];
  out[idx] = make_float2(a.x * b.x - a.y * b.y, a.x * b.y + a.y * b.x);
}

__global__ __launch_bounds__(256) void k_taper(float* __restrict__ xp, const float* __restrict__ blr,
                                               const float* __restrict__ ahw) {
  int idx = blockIdx.x * 256 + threadIdx.x;
  if (idx >= 2 * PLANE) return;
  int p = idx % PLANE;
  int i = p / HP, j = p % HP;
  float al = ahw[i] * ahw[270 + j];
  xp[idx] = al * xp[idx] + (1.f - al) * blr[idx];
}

__global__ __launch_bounds__(256) void k_mulTY(const float2* __restrict__ T, const float2* __restrict__ Y,
                                               float2* __restrict__ out) {
  int idx = blockIdx.x * 256 + threadIdx.x;
  if (idx >= 8 * PLANE) return;
  int s = idx / PLANE, p = idx % PLANE;
  int b = s >> 2, d = s & 3;
  float2 a = T[(size_t)d * PLANE + p], y = Y[(size_t)b * PLANE + p];
  out[idx] = make_float2(a.x * y.x - a.y * y.y, a.x * y.y + a.y * y.x);
}

// ---------------- split+pack helper ----------------
__device__ __forceinline__ uint2 split_pack(float t0, float t1) {
  uint32 u0 = __float_as_uint(t0), u1 = __float_as_uint(t1);
  uint32 hiw = (u0 >> 16) | (u1 & 0xFFFF0000u);
  float r0 = t0 - __uint_as_float(u0 & 0xFFFF0000u);
  float r1 = t1 - __uint_as_float(u1 & 0xFFFF0000u);
  uint32 low = (__float_as_uint(r0) >> 16) | (__float_as_uint(r1) & 0xFFFF0000u);
  return make_uint2(hiw, low);
}

template <typename T, int STRIDE>
__device__ __forceinline__ void store_halo_s(T* __restrict__ op, int xx, int yy, int o, T val) {
  op[o] = val;
  bool xl = (xx == 0), xr = (xx == 269), yt = (yy == 0), yb = (yy == 269);
  if (xl) op[o - STRIDE] = val;
  if (xr) op[o + STRIDE] = val;
  if (yt) { op[o - PW * STRIDE] = val; if (xl) op[o - (PW + 1) * STRIDE] = val; if (xr) op[o - (PW - 1) * STRIDE] = val; }
  if (yb) { op[o + PW * STRIDE] = val; if (xl) op[o + (PW - 1) * STRIDE] = val; if (xr) op[o + (PW + 1) * STRIDE] = val; }
}

// ---------------- first conv 5x5 1->32 -> grouped split act records ----------------
__global__ __launch_bounds__(256) void k_conv5(const float* __restrict__ z, const float* __restrict__ cw,
                                               const float* __restrict__ bias, const float* __restrict__ pre,
                                               uint4* __restrict__ actout) {
  int p = blockIdx.x * 256 + threadIdx.x;
  if (p >= PLANE) return;
  int sc = blockIdx.y;
  int i = p / HP, j = p % HP;
  const float* zs = z + (size_t)sc * PLANE;
  float v[25];
#pragma unroll
  for (int r = 0; r < 5; ++r) {
    int ii = i + r - 2; ii = ii < 0 ? -1 - ii : (ii > 269 ? 539 - ii : ii);
#pragma unroll
    for (int s = 0; s < 5; ++s) {
      int jj = j + s - 2; jj = jj < 0 ? -1 - jj : (jj > 269 ? 539 - jj : jj);
      v[r * 5 + s] = zs[ii * HP + jj];
    }
  }
  int o = (i + 1) * PW + (j + 1);
#pragma unroll 1
  for (int g = 0; g < 4; ++g) {
    float tt[8];
#pragma unroll
    for (int r8 = 0; r8 < 8; ++r8) {
      int oc = 8 * g + r8;
      float a = bias[oc];
#pragma unroll
      for (int k = 0; k < 25; ++k) a += cw[oc * 25 + k] * v[k];
      float pa = pre[oc];
      tt[r8] = fmaxf(a, 0.f) + pa * fminf(a, 0.f);
    }
    uint2 sp0 = split_pack(tt[0], tt[1]), sp1 = split_pack(tt[2], tt[3]);
    uint2 sp2 = split_pack(tt[4], tt[5]), sp3 = split_pack(tt[6], tt[7]);
    uint4 hi = make_uint4(sp0.x, sp1.x, sp2.x, sp3.x);
    uint4 lo = make_uint4(sp0.y, sp1.y, sp2.y, sp3.y);
    uint4* opb = actout + (size_t)(sc * 4 + g) * PPLANE * 2;
    store_halo_s<uint4, 2>(opb, j, i, o * 2, hi);
    store_halo_s<uint4, 2>(opb, j, i, o * 2 + 1, lo);
  }
}

// ---------------- MFMA 3x3 conv with LDS tile staging ----------------
// Block = 16x16 pixel tile. Per 32-channel kc slice: stage the 18x18 input tile
// into LDS (coalesced); 9 taps read B via ds_read_b128. Epilogue exchanges record
// halves across quad-pair lanes (shfl_xor 16) so every store is a full 16 B uint4,
// 512 B contiguous per wave-instruction -> no partial-line RMW (R11: WRITE 261 MB).
#define TSTRIDE 144
template <int CIN, int COUT, bool SC, bool SPLIT>
__global__ __launch_bounds__(256, 3) void k_mconv(
    const uint4* __restrict__ act, const unsigned short* __restrict__ wf,
    const float* __restrict__ bias, const float* __restrict__ pre,
    uint2* __restrict__ actout, float* __restrict__ sout,
    const uint2* __restrict__ scact, const float* __restrict__ scinv,
    const float* __restrict__ wTt) {
  constexpr int KC = CIN / 32, MT = COUT / 16;
  __shared__ uint4 smem4[18 * 18 * TSTRIDE / 16];
  unsigned char* smem = (unsigned char*)smem4;

  const int lane = threadIdx.x & 63, wv = threadIdx.x >> 6;
  const int quad = lane >> 4, col = lane & 15;
  const int sc = blockIdx.y;
  // XCD band swizzle: 289 tiles -> 8 bands of 36 (+1 tail)
  int bx = blockIdx.x;
  int tile = (bx < 288) ? ((bx & 7) * 36 + (bx >> 3)) : 288;
  const int tx0 = (tile % 17) * 16, ty0 = (tile / 17) * 16;

  uint32 py[4], px[4], boff[4];
  bool vld[4];
#pragma unroll
  for (int nt = 0; nt < 4; ++nt) {
    int xr = tx0 + col, yr = ty0 + wv * 4 + nt;
    vld[nt] = (xr < 270) && (yr < 270);
    int xx = xr > 269 ? 269 : xr;
    int yy = yr > 269 ? 269 : yr;
    px[nt] = xx; py[nt] = yy;
    boff[nt] = (yy + 1) * PW + xx;
  }

  f32x4 acc[MT][4];
#pragma unroll
  for (int mt = 0; mt < MT; ++mt)
#pragma unroll
    for (int nt = 0; nt < 4; ++nt) { f32x4 z = {0.f, 0.f, 0.f, 0.f}; acc[mt][nt] = z; }

#pragma unroll 1
  for (int kc = 0; kc < KC; ++kc) {
    if (kc > 0) __syncthreads();
    // ---- stage: 18x18 pixels x 4 records x {hi,lo} = 2592 uint4, coalesced ----
    {
      const uint4* srcb = act + ((size_t)(sc * (CIN / 8) + kc * 4)) * PPLANE * 2;
      for (int i = threadIdx.x; i < 2592; i += 256) {
        int h = i & 1;
        int pp = i >> 1;
        int g = pp / 324;
        int pxl = pp - g * 324;
        int pyy = pxl / 18, pxx = pxl - pyy * 18;
        int gy = ty0 + pyy; if (gy > 271) gy = 271;
        int gx = tx0 + pxx; if (gx > 271) gx = 271;
        uint4 v = srcb[((size_t)g * PPLANE + gy * PW + gx) * 2 + h];
        *(uint4*)(smem + pxl * TSTRIDE + g * 32 + h * 16) = v;
      }
    }
    __syncthreads();

    // ---- compute 9 taps from LDS ----
#pragma unroll
    for (int o = 0; o < 9; ++o) {
      const int dy = o / 3, dx = o % 3;
      union { uint4 u; bf16x8 v; } Wh[MT], Wl[MT];
#pragma unroll
      for (int mt = 0; mt < MT; ++mt) {
        const uint4* wp = (const uint4*)wf + ((((o * KC + kc) * MT + mt) * 64 + lane) * 2);
        Wh[mt].u = wp[0]; Wl[mt].u = wp[1];
      }
      const int lx = col + dx;
#pragma unroll
      for (int nt = 0; nt < 4; ++nt) {
        const int ly = wv * 4 + nt + dy;
        unsigned char* bp = smem + (ly * 18 + lx) * TSTRIDE + quad * 32;
        union { uint4 u; bf16x8 v; } Bh, Bl;
        Bh.u = *(const uint4*)bp;
        Bl.u = *(const uint4*)(bp + 16);
#pragma unroll
        for (int mt = 0; mt < MT; ++mt)
          acc[mt][nt] = __builtin_amdgcn_mfma_f32_16x16x32_bf16(Wh[mt].v, Bh.v, acc[mt][nt], 0, 0, 0);
#pragma unroll
        for (int mt = 0; mt < MT; ++mt)
          acc[mt][nt] = __builtin_amdgcn_mfma_f32_16x16x32_bf16(Wl[mt].v, Bh.v, acc[mt][nt], 0, 0, 0);
#pragma unroll
        for (int mt = 0; mt < MT; ++mt)
          acc[mt][nt] = __builtin_amdgcn_mfma_f32_16x16x32_bf16(Wh[mt].v, Bl.v, acc[mt][nt], 0, 0, 0);
      }
    }
  }

  if (SPLIT) {
#pragma unroll
    for (int mt = 0; mt < MT; ++mt) {
      const int ocb = mt * 16 + quad * 4;
      const int g2 = 2 * mt + (quad >> 1), slot = quad & 1;
      f32x4 bias4 = *(const f32x4*)(bias + ocb);
      f32x4 pr4 = *(const f32x4*)(pre + ocb);
      f32x4 inv4;
      if (SC) inv4 = *(const f32x4*)(scinv + ocb);
#pragma unroll
      for (int nt = 0; nt < 4; ++nt) {
        const uint32 ppix = boff[nt] + 1;    // clamped-safe address
        float v[4];
#pragma unroll
        for (int r = 0; r < 4; ++r) v[r] = acc[mt][nt][r] + bias4[r];
        if (SC) {
          // read valid for clamped lanes (value discarded by the guarded store)
          const uint2* rec = scact + ((size_t)(sc * (COUT / 8) + g2) * PPLANE + ppix) * 4;
          uint2 hi = rec[slot], lo = rec[2 + slot];
          float s0 = __uint_as_float(hi.x << 16) + __uint_as_float(lo.x << 16);
          float s1 = __uint_as_float(hi.x & 0xFFFF0000u) + __uint_as_float(lo.x & 0xFFFF0000u);
          float s2 = __uint_as_float(hi.y << 16) + __uint_as_float(lo.y << 16);
          float s3 = __uint_as_float(hi.y & 0xFFFF0000u) + __uint_as_float(lo.y & 0xFFFF0000u);
          v[0] += (s0 >= 0.f) ? s0 : s0 * inv4[0];
          v[1] += (s1 >= 0.f) ? s1 : s1 * inv4[1];
          v[2] += (s2 >= 0.f) ? s2 : s2 * inv4[2];
          v[3] += (s3 >= 0.f) ? s3 : s3 * inv4[3];
        }
        float t0 = fmaxf(v[0], 0.f) + pr4[0] * fminf(v[0], 0.f);
        float t1 = fmaxf(v[1], 0.f) + pr4[1] * fminf(v[1], 0.f);
        float t2 = fmaxf(v[2], 0.f) + pr4[2] * fminf(v[2], 0.f);
        float t3 = fmaxf(v[3], 0.f) + pr4[3] * fminf(v[3], 0.f);
        uint2 sp0 = split_pack(t0, t1), sp1 = split_pack(t2, t3);
        // quad-pair exchange (lane^16): vld identical across the pair (col/wv/nt only)
        uint2 q0 = make_uint2((uint32)__shfl_xor((int)sp0.x, 16, 64),
                              (uint32)__shfl_xor((int)sp0.y, 16, 64));
        uint2 q1 = make_uint2((uint32)__shfl_xor((int)sp1.x, 16, 64),
                              (uint32)__shfl_xor((int)sp1.y, 16, 64));
        uint4 val = (slot == 0) ? make_uint4(sp0.x, sp1.x, q0.x, q1.x)    // full hi record
                                : make_uint4(q0.y, q1.y, sp0.y, sp1.y);   // full lo record
        if (vld[nt]) {
          uint4* opb4 = (uint4*)actout + (size_t)(sc * (COUT / 8) + g2) * PPLANE * 2;
          store_halo_s<uint4, 2>(opb4, (int)px[nt], (int)py[nt], (int)ppix * 2 + slot, val);
        }
      }
    }
  } else {
    // fused convT channel contraction: s_t = sum_ch wT[t][ch]*(acc+bias)
    float4 b4[MT];
#pragma unroll
    for (int mt = 0; mt < MT; ++mt) b4[mt] = *(const float4*)(bias + mt * 16 + quad * 4);
#pragma unroll
    for (int nt = 0; nt < 4; ++nt) {
      float vv[MT][4];
#pragma unroll
      for (int mt = 0; mt < MT; ++mt) {
        vv[mt][0] = acc[mt][nt][0] + b4[mt].x;
        vv[mt][1] = acc[mt][nt][1] + b4[mt].y;
        vv[mt][2] = acc[mt][nt][2] + b4[mt].z;
        vv[mt][3] = acc[mt][nt][3] + b4[mt].w;
      }
      float* sp = sout + (size_t)sc * 25 * PLANE + (int)(py[nt] * 270 + px[nt]);
#pragma unroll
      for (int t = 0; t < 25; ++t) {
        const float* wp = wTt + t * 32 + quad * 4;
        float c = 0.f;
#pragma unroll
        for (int mt = 0; mt < MT; ++mt) {
          float4 w4 = *(const float4*)(wp + mt * 16);
          c += w4.x * vv[mt][0] + w4.y * vv[mt][1] + w4.z * vv[mt][2] + w4.w * vv[mt][3];
        }
        c += __shfl_xor(c, 16, 64);        // vld is quad-uniform: shuffles stay uniform
        c += __shfl_xor(c, 32, 64);
        if (quad == 0 && vld[nt]) sp[(size_t)t * PLANE] = c;
      }
    }
  }
}

// ---------------- convT pass 2: out = bt + sum_t s_t(shifted) ----------------
__global__ __launch_bounds__(256) void k_convT2(const float* __restrict__ s, const float* __restrict__ bt,
                                                float* __restrict__ yo) {
  int p = blockIdx.x * 256 + threadIdx.x;
  if (p >= PLANE) return;
  int sc = blockIdx.y;
  int y = p / 270, x = p - y * 270;
  float acc = bt[0];
  const float* sb = s + (size_t)sc * 25 * PLANE;
#pragma unroll
  for (int a = 0; a < 5; ++a) {
    int yy = y + a - 2;
    if ((unsigned)yy >= 270u) continue;
    const float* row = sb + (size_t)(a * 5) * PLANE + yy * 270;
#pragma unroll
    for (int b = 0; b < 5; ++b) {
      int xx = x + b - 2;
      if ((unsigned)xx < 270u) acc += row[(size_t)b * PLANE + xx];
    }
  }
  yo[(size_t)sc * PLANE + p] = acc;
}

// ---------------- norm projection scale ----------------
__global__ __launch_bounds__(256) void k_nrm(const float* __restrict__ yb, float* __restrict__ red) {
  int s = blockIdx.x;
  const float* ys = yb + (size_t)s * PLANE;
  float acc = 0.f;
  for (int i = threadIdx.x; i < PLANE; i += 256) { float v = ys[i]; acc += v * v; }
  float tot = blockReduceSum(acc);
  if (threadIdx.x == 0) {
    float nrm = sqrtf(tot);
    float eps = red[8 + s];
    red[16 + s] = (nrm > eps) ? eps / fmaxf(nrm, 1e-12f) : 1.0f;
  }
}

// ---------------- final: clip(z - scl*y), crop, mix ----------------
__global__ __launch_bounds__(256) void k_final(const float* __restrict__ z, const float* __restrict__ yb,
                                               const float* __restrict__ red, const float* __restrict__ mw,
                                               float* __restrict__ out) {
  int idx = blockIdx.x * 256 + threadIdx.x;
  if (idx >= 131072) return;
  int b = idx >> 16;
  int rem = idx & 65535;
  int h = rem >> 8, w = rem & 255;
  int p = (h + 7) * HP + (w + 7);
  float acc = 0.f;
#pragma unroll
  for (int d = 0; d < 4; ++d) {
    int s = b * 4 + d;
    float v = z[(size_t)s * PLANE + p] - red[16 + s] * yb[(size_t)s * PLANE + p];
    v = fminf(fmaxf(v, 0.f), 255.f);
    acc += mw[d] * v;
  }
  out[idx] = acc;
}

// =====================================================================
extern "C" void kernel_launch(void* const* d_in, const int* in_sizes, int n_in,
                              void* d_out, int out_size, void* d_ws, size_t ws_size,
                              hipStream_t stream) {
  (void)in_sizes; (void)n_in; (void)out_size;
  const float* x    = (const float*)d_in[0];
  const float* bk   = (const float*)d_in[1];
  const float* stdn = (const float*)d_in[2];
  const float* ww   = (const float*)d_in[3];
  const float* wwsc = (const float*)d_in[4];
  const float* alph = (const float*)d_in[5];
  const float* cw   = (const float*)d_in[6];
  const float* sf   = (const float*)d_in[7];
  const float* bf   = (const float*)d_in[8];
  const float* bt   = (const float*)d_in[9];
  const float* p1   = (const float*)d_in[10];
  const float* w1   = (const float*)d_in[11];
  const float* s1   = (const float*)d_in[12];
  const float* b1   = (const float*)d_in[13];
  const float* p2   = (const float*)d_in[14];
  const float* w2   = (const float*)d_in[15];
  const float* s2   = (const float*)d_in[16];
  const float* b2   = (const float*)d_in[17];
  const float* apj  = (const float*)d_in[18];
  const float* mwp  = (const float*)d_in[19];
  float* out = (float*)d_out;

  char* wsbase = (char*)d_ws;
  size_t off = 0;
  auto alloc = [&](size_t nbytes) -> char* {
    char* p = wsbase + off;
    off = (off + nbytes + 255) & ~(size_t)255;
    return p;
  };
  // ---- persistent region ----
  float*  zb  = (float*)alloc(8 * (size_t)PLANE * 4);
  float*  yb  = (float*)alloc(8 * (size_t)PLANE * 4);
  float*  red = (float*)alloc(64 * 4);
  float*  inv = (float*)alloc(32 * 4);
  float*  cwn = (float*)alloc(800 * 4);
  float*  wTt = (float*)alloc(800 * 4);
  unsigned short* w1f = (unsigned short*)alloc(5 * 36864 * (size_t)2);
  unsigned short* w2f = (unsigned short*)alloc(5 * 36864 * (size_t)2);
  // ---- union region ----
  size_t U0 = off;
  // DFT view
  float2* tw  = (float2*)alloc(2 * (size_t)PLANE * 4);
  float*  xp  = (float*)alloc(2 * (size_t)PLANE * 4);
  float*  rtm = (float*)alloc(2 * (size_t)PLANE * 4);
  float2* cb0 = (float2*)alloc(2 * 8 * (size_t)PLANE * 8);
  float2* cb1 = (float2*)alloc(2 * 8 * (size_t)PLANE * 8);
  float2* Yb  = (float2*)alloc(2 * 2 * (size_t)PLANE * 8);
  float2* Hf  = (float2*)alloc(2 * (size_t)PLANE * 4);
  float*  Sb  = (float*)alloc((size_t)PLANE * 4);
  float2* Tb  = (float2*)alloc(2 * 4 * (size_t)PLANE * 4);
  float*  ahw = (float*)alloc(540 * 4);
  float*  wwn = (float*)alloc(600 * 4);
  // conv view (aliases the DFT view). Chunk size S = 8 if workspace allows, else 4.
  size_t conv8 = (size_t)8 * 4 * PPLANE * 32 + 256 + (size_t)8 * 8 * PPLANE * 32 + 256;
  int S = (ws_size >= U0 + conv8) ? 8 : 4;
  int nc = 8 / S;
  off = U0;
  uint4* act1 = (uint4*)alloc((size_t)S * 4 * PPLANE * 32);   // 32ch split acts; aliases sOb (S*25*PLANE f32)
  uint4* act2 = (uint4*)alloc((size_t)S * 8 * PPLANE * 32);   // 64ch split acts
  float* sOb = (float*)act1;

  // setup
  k_twiddle<<<285, 256, 0, stream>>>(tw);
  k_sympad<<<(2 * PLANE + 255) / 256, 256, 0, stream>>>(x, xp);
  k_edget<<<1, 512, 0, stream>>>(bk, ahw);
  k_Hf<<<285, 256, 0, stream>>>(bk, Hf);
  k_wnorm<<<24, 256, 0, stream>>>(ww, wwsc, wwn, 25);
  k_wnorm<<<32, 256, 0, stream>>>(cw, sf, cwn, 25);
  k_wT<<<4, 256, 0, stream>>>(cwn, wTt);
  k_wfrag<32, 64><<<320, 256, 0, stream>>>(w1, s1, w1f);
  k_wfrag<64, 32><<<160, 256, 0, stream>>>(w2, s2, w2f);
  k_inv<<<1, 32, 0, stream>>>(p1, inv);
  k_S<<<285, 256, 0, stream>>>(wwn, Sb);
  k_T<<<(4 * PLANE + 255) / 256, 256, 0, stream>>>(Hf, Sb, alph, Tb);
  k_amp<<<4, 256, 0, stream>>>(Tb, red);
  k_eps<<<1, 64, 0, stream>>>(apj, stdn, red);

  dim3 g2(5, 45, 2), g8(5, 45, 8);

  // edgetaper
  k_rowT<6, true ><<<g2, 64, 0, stream>>>(xp, cb1, tw, -1.f);
  k_colT<6, false><<<g2, 64, 0, stream>>>(cb1, cb0, tw, -1.f, 1.f);
  k_mulHf<<<(2 * PLANE + 255) / 256, 256, 0, stream>>>(cb0, Hf, cb1);
  k_rowT<6, false><<<g2, 64, 0, stream>>>(cb1, cb0, tw, 1.f);
  k_colT<6, true ><<<g2, 64, 0, stream>>>(cb0, rtm, tw, 1.f, 1.f / (float)PLANE);
  k_taper<<<(2 * PLANE + 255) / 256, 256, 0, stream>>>(xp, rtm, ahw);

  // Y = fft2(xp)
  k_rowT<6, true ><<<g2, 64, 0, stream>>>(xp, cb1, tw, -1.f);
  k_colT<6, false><<<g2, 64, 0, stream>>>(cb1, Yb, tw, -1.f, 1.f);

  // z = ifft2(T*Y).real for all 8 (b,d)
  k_mulTY<<<(8 * PLANE + 255) / 256, 256, 0, stream>>>(Tb, Yb, cb0);
  k_rowT<6, false><<<g8, 64, 0, stream>>>(cb0, cb1, tw, 1.f);
  k_colT<6, true ><<<g8, 64, 0, stream>>>(cb1, zb, tw, 1.f, 1.f / (float)PLANE);

  // conv net, nc chunks of S samples
  for (int c = 0; c < nc; ++c) {
    const float* zc = zb + (size_t)c * S * PLANE;
    float* ybc = yb + (size_t)c * S * PLANE;
    k_conv5<<<dim3(285, S), 256, 0, stream>>>(zc, cwn, bf, p1, act1);
    for (int i = 0; i < 5; ++i) {
      k_mconv<32, 64, false, true><<<dim3(289, S), 256, 0, stream>>>(
          act1, w1f + (size_t)i * 36864, b1 + i * 64, p2 + i * 64, (uint2*)act2, nullptr, nullptr, nullptr, nullptr);
      if (i == 0)
        k_mconv<64, 32, true, true><<<dim3(289, S), 256, 0, stream>>>(
            act2, w2f + (size_t)i * 36864, b2 + i * 32, p1 + (i + 1) * 32, (uint2*)act1, nullptr, (const uint2*)act1, inv, nullptr);
      else if (i < 4)
        k_mconv<64, 32, false, true><<<dim3(289, S), 256, 0, stream>>>(
            act2, w2f + (size_t)i * 36864, b2 + i * 32, p1 + (i + 1) * 32, (uint2*)act1, nullptr, nullptr, nullptr, nullptr);
      else
        k_mconv<64, 32, false, false><<<dim3(289, S), 256, 0, stream>>>(
            act2, w2f + (size_t)i * 36864, b2 + i * 32, nullptr, nullptr, sOb, nullptr, nullptr, wTt);
    }
    k_convT2<<<dim3(285, S), 256, 0, stream>>>(sOb, bt, ybc);
  }

  // projection + final mix
  k_nrm<<<8, 256, 0, stream>>>(yb, red);
  k_final<<<(131072 + 255) / 256, 256, 0, stream>>>(zb, yb, red, mwp, out);
}

// Round 13
// 1552.295 us; speedup vs baseline: 1.4544x; 1.1409x over previous
//
#include <hip/hip_runtime.h>
#include <math.h>

#define HP     270
#define PLANE  72900      // 270*270
#define PW     272
#define PPLANE 73984      // 272*272

typedef unsigned int uint32;
typedef __attribute__((ext_vector_type(8))) short bf16x8;
typedef __attribute__((ext_vector_type(4))) float f32x4;

// ---------------- reduction helper ----------------
__device__ __forceinline__ float blockReduceSum(float val) {
  __shared__ float sh[16];
  int lane = threadIdx.x & 63, wid = threadIdx.x >> 6;
#pragma unroll
  for (int o = 32; o > 0; o >>= 1) val += __shfl_down(val, o, 64);
  __syncthreads();
  if (lane == 0) sh[wid] = val;
  __syncthreads();
  float tot = 0.f;
  int nw = (blockDim.x + 63) >> 6;
  for (int i = 0; i < nw; ++i) tot += sh[i];
  return tot;
}

// ---------------- twiddle matrix ----------------
__global__ __launch_bounds__(256) void k_twiddle(float2* __restrict__ tw) {
  int idx = blockIdx.x * 256 + threadIdx.x;
  if (idx >= PLANE) return;
  int j = idx / HP, k = idx % HP;
  int m = (j * k) % HP;
  double ang = (2.0 * M_PI * (double)m) / 270.0;
  tw[idx] = make_float2((float)cos(ang), (float)sin(ang));
}

// ---------------- symmetric pad x (2,256,256) -> xp (2,270,270), pad 7 ----------------
__global__ __launch_bounds__(256) void k_sympad(const float* __restrict__ x, float* __restrict__ xp) {
  int idx = blockIdx.x * 256 + threadIdx.x;
  if (idx >= 2 * PLANE) return;
  int b = idx / PLANE, p = idx % PLANE;
  int i = p / HP, j = p % HP;
  int si = i - 7; si = si < 0 ? -1 - si : (si > 255 ? 511 - si : si);
  int sj = j - 7; sj = sj < 0 ? -1 - sj : (sj > 255 ? 511 - sj : sj);
  xp[idx] = x[(b * 256 + si) * 256 + sj];
}

// ---------------- edgetaper 1D weights ----------------
__global__ __launch_bounds__(512) void k_edget(const float* __restrict__ bk, float* __restrict__ ahw) {
  __shared__ float pr[15], pc[15], acr[15], accl[15];
  int t = threadIdx.x;
  if (t < 15) {
    float sr = 0.f, scv = 0.f;
    for (int k = 0; k < 15; ++k) { sr += bk[t * 15 + k]; scv += bk[k * 15 + t]; }
    pr[t] = sr; pc[t] = scv;
  }
  __syncthreads();
  if (t < 30) {
    int l = t % 15; bool isr = (t < 15);
    const float* p = isr ? pr : pc;
    float s = 0.f;
    for (int j = 0; j + l < 15; ++j) s += p[j] * p[j + l];
    if (isr) acr[l] = s; else accl[l] = s;
  }
  __syncthreads();
  for (int i = t; i < 540; i += blockDim.x) {
    bool isr = (i < 270);
    int ii = isr ? i : i - 270;
    const float* ac = isr ? acr : accl;
    int m = (ii == 269) ? 0 : ii;
    float zv;
    if (m < 15) zv = ac[m];
    else if (m >= 255) zv = ac[269 - m];
    else zv = 0.f;
    ahw[i] = 1.f - zv / ac[0];
  }
}

// ---------------- Hf = psf2otf(blur 15x15) ----------------
__global__ __launch_bounds__(256) void k_Hf(const float* __restrict__ bk, float2* __restrict__ Hf) {
  int p = blockIdx.x * 256 + threadIdx.x;
  if (p >= PLANE) return;
  int u = p / HP, v = p % HP;
  float2 er[15], es[15];
#pragma unroll
  for (int r = 0; r < 15; ++r) {
    int m = ((u * (r - 7)) % HP + HP) % HP;
    float sn, cs;
    sincosf(2.f * (float)M_PI * (float)m / 270.f, &sn, &cs);
    er[r] = make_float2(cs, -sn);
    int m2 = ((v * (r - 7)) % HP + HP) % HP;
    sincosf(2.f * (float)M_PI * (float)m2 / 270.f, &sn, &cs);
    es[r] = make_float2(cs, -sn);
  }
  float ar = 0.f, ai = 0.f;
#pragma unroll 1
  for (int r = 0; r < 15; ++r) {
    float rr = 0.f, ri = 0.f;
#pragma unroll
    for (int s = 0; s < 15; ++s) {
      float wv = bk[r * 15 + s];
      rr += wv * es[s].x; ri += wv * es[s].y;
    }
    ar += er[r].x * rr - er[r].y * ri;
    ai += er[r].x * ri + er[r].y * rr;
  }
  Hf[p] = make_float2(ar, ai);
}

// ---------------- weight normalization, plain layout ----------------
__global__ __launch_bounds__(256) void k_wnorm(const float* __restrict__ w, const float* __restrict__ scale,
                                               float* __restrict__ out, int fsize) {
  int f = blockIdx.x;
  const float* wf = w + (size_t)f * fsize;
  float s = 0.f;
  for (int i = threadIdx.x; i < fsize; i += 256) s += wf[i];
  float mean = blockReduceSum(s) / (float)fsize;
  float s2 = 0.f;
  for (int i = threadIdx.x; i < fsize; i += 256) { float d = wf[i] - mean; s2 += d * d; }
  float nrm = sqrtf(blockReduceSum(s2));
  float sc = scale[f] / nrm;
  for (int i = threadIdx.x; i < fsize; i += 256) out[(size_t)f * fsize + i] = (wf[i] - mean) * sc;
}

// ---------------- transpose conv5 weights to tap-major (flipped) ----------------
__global__ void k_wT(const float* __restrict__ cwn, float* __restrict__ wT) {
  int idx = blockIdx.x * 256 + threadIdx.x;
  if (idx >= 800) return;
  int t = idx >> 5, f = idx & 31;
  int dri = t / 5, dci = t % 5;           // input offsets dr = dri-2, dc = dci-2
  wT[t * 32 + f] = cwn[f * 25 + (4 - dri) * 5 + (4 - dci)];
}

// ---------------- weight normalization -> split-bf16 MFMA fragment layout ----------------
template <int CIN, int COUT>
__global__ __launch_bounds__(256) void k_wfrag(const float* __restrict__ w, const float* __restrict__ scale,
                                               unsigned short* __restrict__ outb) {
  constexpr int KC = CIN / 32, MT = COUT / 16, FS = CIN * 9;
  int fg = blockIdx.x;
  int f = fg % COUT, iter = fg / COUT;
  const float* wf = w + (size_t)fg * FS;
  float s = 0.f;
  for (int i = threadIdx.x; i < FS; i += 256) s += wf[i];
  float mean = blockReduceSum(s) / (float)FS;
  float s2 = 0.f;
  for (int i = threadIdx.x; i < FS; i += 256) { float d = wf[i] - mean; s2 += d * d; }
  float nrm = sqrtf(blockReduceSum(s2));
  float scv = scale[fg] / nrm;
  unsigned short* dst0 = outb + (size_t)iter * (9 * KC * MT * 64 * 16);
  for (int i = threadIdx.x; i < FS; i += 256) {
    float val = (wf[i] - mean) * scv;
    int ci = i / 9, rs = i - ci * 9;
    int kc = ci >> 5, cil = ci & 31, q = cil >> 3, j = cil & 7;
    int mt = f >> 4, ocl = f & 15, lane = q * 16 + ocl;
    unsigned short* d2 = dst0 + ((((rs * KC + kc) * MT + mt) * 64 + lane) * 16);
    uint32 u = __float_as_uint(val);
    d2[j] = (unsigned short)(u >> 16);
    float lof = val - __uint_as_float(u & 0xFFFF0000u);
    d2[8 + j] = (unsigned short)(__float_as_uint(lof) >> 16);
  }
}

// ---------------- S = sum_f |FT(ww_f 5x5)|^2 ----------------
__global__ __launch_bounds__(256) void k_S(const float* __restrict__ wwn, float* __restrict__ S) {
  int p = blockIdx.x * 256 + threadIdx.x;
  if (p >= PLANE) return;
  int u = p / HP, v = p % HP;
  float2 er[5], es[5];
#pragma unroll
  for (int r = 0; r < 5; ++r) {
    float sn, cs;
    int m = (u * r) % HP;
    sincosf(2.f * (float)M_PI * (float)m / 270.f, &sn, &cs);
    er[r] = make_float2(cs, -sn);
    int m2 = (v * r) % HP;
    sincosf(2.f * (float)M_PI * (float)m2 / 270.f, &sn, &cs);
    es[r] = make_float2(cs, -sn);
  }
  float prr[25], pii[25];
#pragma unroll
  for (int r = 0; r < 5; ++r)
#pragma unroll
    for (int s = 0; s < 5; ++s) {
      prr[r * 5 + s] = er[r].x * es[s].x - er[r].y * es[s].y;
      pii[r * 5 + s] = er[r].x * es[s].y + er[r].y * es[s].x;
    }
  float acc = 0.f;
#pragma unroll 1
  for (int f = 0; f < 24; ++f) {
    float xr = 0.f, xi = 0.f;
#pragma unroll
    for (int t = 0; t < 25; ++t) {
      float wv = wwn[f * 25 + t];
      xr += wv * prr[t]; xi += wv * pii[t];
    }
    acc += xr * xr + xi * xi;
  }
  S[p] = acc;
}

// ---------------- T = conj(Hf)/(|Hf|^2 + a_d S) ----------------
__global__ __launch_bounds__(256) void k_T(const float2* __restrict__ Hf, const float* __restrict__ S,
                                           const float* __restrict__ alpha, float2* __restrict__ T) {
  int idx = blockIdx.x * 256 + threadIdx.x;
  if (idx >= 4 * PLANE) return;
  int d = idx / PLANE, p = idx % PLANE;
  float a = expf(alpha[d]);
  float2 h = Hf[p];
  float den = h.x * h.x + h.y * h.y + a * S[p];
  T[idx] = make_float2(h.x / den, -h.y / den);
}

__global__ __launch_bounds__(256) void k_amp(const float2* __restrict__ T, float* __restrict__ red) {
  int d = blockIdx.x;
  const float2* Td = T + (size_t)d * PLANE;
  float acc = 0.f;
  for (int i = threadIdx.x; i < PLANE; i += 256) { float2 t = Td[i]; acc += t.x * t.x + t.y * t.y; }
  float tot = blockReduceSum(acc);
  if (threadIdx.x == 0) red[d] = tot / (float)PLANE;
}

__global__ void k_eps(const float* __restrict__ apj, const float* __restrict__ stdn, float* __restrict__ red) {
  int s = threadIdx.x;
  if (s < 8) {
    int b = s >> 2, d = s & 3;
    red[8 + s] = expf(apj[0]) * stdn[b] * sqrtf(red[d]) * sqrtf(72899.f);
  }
}

__global__ void k_inv(const float* __restrict__ p, float* __restrict__ inv) {
  int t = threadIdx.x;
  if (t < 32) inv[t] = 1.f / p[t];
}

// ---------------- register-tiled DFT passes ----------------
template <int NR, bool REALIN>
__global__ __launch_bounds__(64) void k_rowT(const void* __restrict__ inv_, float2* __restrict__ out,
                                             const float2* __restrict__ tw, float sgn) {
  int v = blockIdx.x * 64 + threadIdx.x;
  int r0 = blockIdx.y * NR;
  int m = blockIdx.z;
  bool ok = v < HP;
  int vc = ok ? v : 0;
  float P[NR], R[NR], Q[NR], Sm[NR];
#pragma unroll
  for (int i = 0; i < NR; ++i) { P[i] = R[i] = 0.f; if (!REALIN) { Q[i] = Sm[i] = 0.f; } }
  const float*  inR = (const float*)inv_  + ((size_t)m * HP + r0) * HP;
  const float2* inC = (const float2*)inv_ + ((size_t)m * HP + r0) * HP;
#pragma unroll 3
  for (int w = 0; w < HP; ++w) {
    float2 t = tw[w * HP + vc];
#pragma unroll
    for (int i = 0; i < NR; ++i) {
      if (REALIN) {
        float a = inR[i * HP + w];
        P[i] += a * t.x; R[i] += a * t.y;
      } else {
        float2 g = inC[i * HP + w];
        P[i] += g.x * t.x; Q[i] += g.y * t.y;
        R[i] += g.x * t.y; Sm[i] += g.y * t.x;
      }
    }
  }
  if (ok) {
#pragma unroll
    for (int i = 0; i < NR; ++i) {
      float ar, ai;
      if (REALIN) { ar = P[i]; ai = sgn * R[i]; }
      else        { ar = P[i] - sgn * Q[i]; ai = sgn * R[i] + Sm[i]; }
      out[((size_t)m * HP + r0 + i) * HP + v] = make_float2(ar, ai);
    }
  }
}

template <int NU, bool REALOUT>
__global__ __launch_bounds__(64) void k_colT(const float2* __restrict__ in, void* __restrict__ outv,
                                             const float2* __restrict__ tw, float sgn, float scale) {
  int v = blockIdx.x * 64 + threadIdx.x;
  int u0 = blockIdx.y * NU;
  int m = blockIdx.z;
  bool ok = v < HP;
  int vc = ok ? v : 0;
  float P[NU], Q[NU], R[NU], Sm[NU];
#pragma unroll
  for (int j = 0; j < NU; ++j) { P[j] = Q[j] = 0.f; if (!REALOUT) { R[j] = Sm[j] = 0.f; } }
  const float2* cp = in + (size_t)m * PLANE + vc;
#pragma unroll 3
  for (int h = 0; h < HP; ++h) {
    float2 g = cp[(size_t)h * HP];
    const float2* tr = tw + h * HP + u0;
#pragma unroll
    for (int j = 0; j < NU; ++j) {
      float2 t = tr[j];
      P[j] += g.x * t.x; Q[j] += g.y * t.y;
      if (!REALOUT) { R[j] += g.x * t.y; Sm[j] += g.y * t.x; }
    }
  }
  if (ok) {
#pragma unroll
    for (int j = 0; j < NU; ++j) {
      float ar = (P[j] - sgn * Q[j]) * scale;
      if (REALOUT) ((float*)outv)[((size_t)m * HP + u0 + j) * HP + v] = ar;
      else {
        float ai = (sgn * R[j] + Sm[j]) * scale;
        ((float2*)outv)[((size_t)m * HP + u0 + j) * HP + v] = make_float2(ar, ai);
      }
    }
  }
}

// ---------------- pointwise ----------------
__global__ __launch_bounds__(256) void k_mulHf(const float2* __restrict__ in, const float2* __restrict__ Hf,
                                               float2* __restrict__ out) {
  int idx = blockIdx.x * 256 + threadIdx.x;
  if (idx >= 2 * PLANE) return;
  int p = idx % PLANE;
  float2 a = in[idx], b = Hf[p];
  out[idx] = make_float2(a.x * b.x - a.y * b.y, a.x * b.y + a.y * b.x);
}

__global__ __launch_bounds__(256) void k_taper(float* __restrict__ xp, const float* __restrict__ blr,
                                               const float* __restrict__ ahw) {
  int idx = blockIdx.x * 256 + threadIdx.x;
  if (idx >= 2 * PLANE) return;
  int p = idx % PLANE;
  int i = p / HP, j = p % HP;
  float al = ahw[i] * ahw[270 + j];
  xp[idx] = al * xp[idx] + (1.f - al) * blr[idx];
}

__global__ __launch_bounds__(256) void k_mulTY(const float2* __restrict__ T, const float2* __restrict__ Y,
                                               float2* __restrict__ out) {
  int idx = blockIdx.x * 256 + threadIdx.x;
  if (idx >= 8 * PLANE) return;
  int s = idx / PLANE, p = idx % PLANE;
  int b = s >> 2, d = s & 3;
  float2 a = T[(size_t)d * PLANE + p], y = Y[(size_t)b * PLANE + p];
  out[idx] = make_float2(a.x * y.x - a.y * y.y, a.x * y.y + a.y * y.x);
}

// ---------------- pack helpers ----------------
__device__ __forceinline__ uint2 split_pack(float t0, float t1) {
  uint32 u0 = __float_as_uint(t0), u1 = __float_as_uint(t1);
  uint32 hiw = (u0 >> 16) | (u1 & 0xFFFF0000u);
  float r0 = t0 - __uint_as_float(u0 & 0xFFFF0000u);
  float r1 = t1 - __uint_as_float(u1 & 0xFFFF0000u);
  uint32 low = (__float_as_uint(r0) >> 16) | (__float_as_uint(r1) & 0xFFFF0000u);
  return make_uint2(hiw, low);
}

__device__ __forceinline__ uint32 rne_pack(float a, float b) {
  uint32 ua = __float_as_uint(a), ub = __float_as_uint(b);
  ua += 0x7FFFu + ((ua >> 16) & 1u);
  ub += 0x7FFFu + ((ub >> 16) & 1u);
  return (ua >> 16) | (ub & 0xFFFF0000u);
}

template <typename T, int STRIDE>
__device__ __forceinline__ void store_halo_s(T* __restrict__ op, int xx, int yy, int o, T val) {
  op[o] = val;
  bool xl = (xx == 0), xr = (xx == 269), yt = (yy == 0), yb = (yy == 269);
  if (xl) op[o - STRIDE] = val;
  if (xr) op[o + STRIDE] = val;
  if (yt) { op[o - PW * STRIDE] = val; if (xl) op[o - (PW + 1) * STRIDE] = val; if (xr) op[o - (PW - 1) * STRIDE] = val; }
  if (yb) { op[o + PW * STRIDE] = val; if (xl) op[o + (PW - 1) * STRIDE] = val; if (xr) op[o + (PW + 1) * STRIDE] = val; }
}

// ---------------- first conv 5x5 1->32 -> grouped split act records ----------------
__global__ __launch_bounds__(256) void k_conv5(const float* __restrict__ z, const float* __restrict__ cw,
                                               const float* __restrict__ bias, const float* __restrict__ pre,
                                               uint4* __restrict__ actout) {
  int p = blockIdx.x * 256 + threadIdx.x;
  if (p >= PLANE) return;
  int sc = blockIdx.y;
  int i = p / HP, j = p % HP;
  const float* zs = z + (size_t)sc * PLANE;
  float v[25];
#pragma unroll
  for (int r = 0; r < 5; ++r) {
    int ii = i + r - 2; ii = ii < 0 ? -1 - ii : (ii > 269 ? 539 - ii : ii);
#pragma unroll
    for (int s = 0; s < 5; ++s) {
      int jj = j + s - 2; jj = jj < 0 ? -1 - jj : (jj > 269 ? 539 - jj : jj);
      v[r * 5 + s] = zs[ii * HP + jj];
    }
  }
  int o = (i + 1) * PW + (j + 1);
#pragma unroll 1
  for (int g = 0; g < 4; ++g) {
    float tt[8];
#pragma unroll
    for (int r8 = 0; r8 < 8; ++r8) {
      int oc = 8 * g + r8;
      float a = bias[oc];
#pragma unroll
      for (int k = 0; k < 25; ++k) a += cw[oc * 25 + k] * v[k];
      float pa = pre[oc];
      tt[r8] = fmaxf(a, 0.f) + pa * fminf(a, 0.f);
    }
    uint2 sp0 = split_pack(tt[0], tt[1]), sp1 = split_pack(tt[2], tt[3]);
    uint2 sp2 = split_pack(tt[4], tt[5]), sp3 = split_pack(tt[6], tt[7]);
    uint4 hi = make_uint4(sp0.x, sp1.x, sp2.x, sp3.x);
    uint4 lo = make_uint4(sp0.y, sp1.y, sp2.y, sp3.y);
    uint4* opb = actout + (size_t)(sc * 4 + g) * PPLANE * 2;
    store_halo_s<uint4, 2>(opb, j, i, o * 2, hi);
    store_halo_s<uint4, 2>(opb, j, i, o * 2 + 1, lo);
  }
}

// ---------------- MFMA 3x3 conv with LDS tile staging ----------------
// Block = 16x16 pixel tile. BSINGLE=false: input is split records (hi/lo uint4 per
// 8-ch group), staged per-kc. BSINGLE=true: input is single-bf16 records (uint4 per
// 8-ch group), ALL 64 ch staged once; 2 MFMAs (Wh,Wl x B) per fragment.
// OMODE: 0 = split store (act1), 1 = single-bf16 RNE store (act2), 2 = fused convT.
#define TSTRIDE 144
template <int CIN, int COUT, bool SC, int OMODE, bool BSINGLE>
__global__ __launch_bounds__(256, 3) void k_mconv(
    const uint4* __restrict__ act, const unsigned short* __restrict__ wf,
    const float* __restrict__ bias, const float* __restrict__ pre,
    uint2* __restrict__ actout, float* __restrict__ sout,
    const uint2* __restrict__ scact, const float* __restrict__ scinv,
    const float* __restrict__ wTt) {
  constexpr int KC = CIN / 32, MT = COUT / 16;
  __shared__ uint4 smem4[18 * 18 * TSTRIDE / 16];
  unsigned char* smem = (unsigned char*)smem4;

  const int lane = threadIdx.x & 63, wv = threadIdx.x >> 6;
  const int quad = lane >> 4, col = lane & 15;
  const int sc = blockIdx.y;
  int bx = blockIdx.x;
  int tile = (bx < 288) ? ((bx & 7) * 36 + (bx >> 3)) : 288;
  const int tx0 = (tile % 17) * 16, ty0 = (tile / 17) * 16;

  uint32 py[4], px[4], boff[4];
  bool vld[4];
#pragma unroll
  for (int nt = 0; nt < 4; ++nt) {
    int xr = tx0 + col, yr = ty0 + wv * 4 + nt;
    vld[nt] = (xr < 270) && (yr < 270);
    int xx = xr > 269 ? 269 : xr;
    int yy = yr > 269 ? 269 : yr;
    px[nt] = xx; py[nt] = yy;
    boff[nt] = (yy + 1) * PW + xx;
  }

  f32x4 acc[MT][4];
#pragma unroll
  for (int mt = 0; mt < MT; ++mt)
#pragma unroll
    for (int nt = 0; nt < 4; ++nt) { f32x4 z = {0.f, 0.f, 0.f, 0.f}; acc[mt][nt] = z; }

  if (BSINGLE) {
    // ---- stage all CIN/8 single records once: 18x18 x 8 groups = 2592 uint4 ----
    const uint4* srcb = act + (size_t)(sc * (CIN / 8)) * PPLANE;
    for (int i = threadIdx.x; i < 324 * (CIN / 8); i += 256) {
      int g = i / 324, pxl = i - g * 324;
      int pyy = pxl / 18, pxx = pxl - pyy * 18;
      int gy = ty0 + pyy; if (gy > 271) gy = 271;
      int gx = tx0 + pxx; if (gx > 271) gx = 271;
      uint4 v = srcb[(size_t)g * PPLANE + gy * PW + gx];
      *(uint4*)(smem + pxl * TSTRIDE + g * 16) = v;
    }
    __syncthreads();
#pragma unroll 1
    for (int kc = 0; kc < KC; ++kc) {
#pragma unroll
      for (int o = 0; o < 9; ++o) {
        const int dy = o / 3, dx = o % 3;
        union { uint4 u; bf16x8 v; } Wh[MT], Wl[MT];
#pragma unroll
        for (int mt = 0; mt < MT; ++mt) {
          const uint4* wp = (const uint4*)wf + ((((o * KC + kc) * MT + mt) * 64 + lane) * 2);
          Wh[mt].u = wp[0]; Wl[mt].u = wp[1];
        }
        const int lx = col + dx;
#pragma unroll
        for (int nt = 0; nt < 4; ++nt) {
          const int ly = wv * 4 + nt + dy;
          union { uint4 u; bf16x8 v; } B;
          B.u = *(const uint4*)(smem + (ly * 18 + lx) * TSTRIDE + (kc * 4 + quad) * 16);
#pragma unroll
          for (int mt = 0; mt < MT; ++mt)
            acc[mt][nt] = __builtin_amdgcn_mfma_f32_16x16x32_bf16(Wh[mt].v, B.v, acc[mt][nt], 0, 0, 0);
#pragma unroll
          for (int mt = 0; mt < MT; ++mt)
            acc[mt][nt] = __builtin_amdgcn_mfma_f32_16x16x32_bf16(Wl[mt].v, B.v, acc[mt][nt], 0, 0, 0);
        }
      }
    }
  } else {
#pragma unroll 1
    for (int kc = 0; kc < KC; ++kc) {
      if (kc > 0) __syncthreads();
      const uint4* srcb = act + ((size_t)(sc * (CIN / 8) + kc * 4)) * PPLANE * 2;
      for (int i = threadIdx.x; i < 2592; i += 256) {
        int h = i & 1;
        int pp = i >> 1;
        int g = pp / 324;
        int pxl = pp - g * 324;
        int pyy = pxl / 18, pxx = pxl - pyy * 18;
        int gy = ty0 + pyy; if (gy > 271) gy = 271;
        int gx = tx0 + pxx; if (gx > 271) gx = 271;
        uint4 v = srcb[((size_t)g * PPLANE + gy * PW + gx) * 2 + h];
        *(uint4*)(smem + pxl * TSTRIDE + g * 32 + h * 16) = v;
      }
      __syncthreads();
#pragma unroll
      for (int o = 0; o < 9; ++o) {
        const int dy = o / 3, dx = o % 3;
        union { uint4 u; bf16x8 v; } Wh[MT], Wl[MT];
#pragma unroll
        for (int mt = 0; mt < MT; ++mt) {
          const uint4* wp = (const uint4*)wf + ((((o * KC + kc) * MT + mt) * 64 + lane) * 2);
          Wh[mt].u = wp[0]; Wl[mt].u = wp[1];
        }
        const int lx = col + dx;
#pragma unroll
        for (int nt = 0; nt < 4; ++nt) {
          const int ly = wv * 4 + nt + dy;
          unsigned char* bp = smem + (ly * 18 + lx) * TSTRIDE + quad * 32;
          union { uint4 u; bf16x8 v; } Bh, Bl;
          Bh.u = *(const uint4*)bp;
          Bl.u = *(const uint4*)(bp + 16);
#pragma unroll
          for (int mt = 0; mt < MT; ++mt)
            acc[mt][nt] = __builtin_amdgcn_mfma_f32_16x16x32_bf16(Wh[mt].v, Bh.v, acc[mt][nt], 0, 0, 0);
#pragma unroll
          for (int mt = 0; mt < MT; ++mt)
            acc[mt][nt] = __builtin_amdgcn_mfma_f32_16x16x32_bf16(Wl[mt].v, Bh.v, acc[mt][nt], 0, 0, 0);
#pragma unroll
          for (int mt = 0; mt < MT; ++mt)
            acc[mt][nt] = __builtin_amdgcn_mfma_f32_16x16x32_bf16(Wh[mt].v, Bl.v, acc[mt][nt], 0, 0, 0);
        }
      }
    }
  }

  if (OMODE == 0) {
    // split store (to act1), with optional shortcut reconstruction
#pragma unroll
    for (int mt = 0; mt < MT; ++mt) {
      const int ocb = mt * 16 + quad * 4;
      const int g2 = 2 * mt + (quad >> 1), slot = quad & 1;
      f32x4 bias4 = *(const f32x4*)(bias + ocb);
      f32x4 pr4 = *(const f32x4*)(pre + ocb);
      f32x4 inv4;
      if (SC) inv4 = *(const f32x4*)(scinv + ocb);
#pragma unroll
      for (int nt = 0; nt < 4; ++nt) {
        const uint32 ppix = boff[nt] + 1;
        float v[4];
#pragma unroll
        for (int r = 0; r < 4; ++r) v[r] = acc[mt][nt][r] + bias4[r];
        if (SC) {
          const uint2* rec = scact + ((size_t)(sc * (COUT / 8) + g2) * PPLANE + ppix) * 4;
          uint2 hi = rec[slot], lo = rec[2 + slot];
          float s0 = __uint_as_float(hi.x << 16) + __uint_as_float(lo.x << 16);
          float s1 = __uint_as_float(hi.x & 0xFFFF0000u) + __uint_as_float(lo.x & 0xFFFF0000u);
          float s2 = __uint_as_float(hi.y << 16) + __uint_as_float(lo.y << 16);
          float s3 = __uint_as_float(hi.y & 0xFFFF0000u) + __uint_as_float(lo.y & 0xFFFF0000u);
          v[0] += (s0 >= 0.f) ? s0 : s0 * inv4[0];
          v[1] += (s1 >= 0.f) ? s1 : s1 * inv4[1];
          v[2] += (s2 >= 0.f) ? s2 : s2 * inv4[2];
          v[3] += (s3 >= 0.f) ? s3 : s3 * inv4[3];
        }
        float t0 = fmaxf(v[0], 0.f) + pr4[0] * fminf(v[0], 0.f);
        float t1 = fmaxf(v[1], 0.f) + pr4[1] * fminf(v[1], 0.f);
        float t2 = fmaxf(v[2], 0.f) + pr4[2] * fminf(v[2], 0.f);
        float t3 = fmaxf(v[3], 0.f) + pr4[3] * fminf(v[3], 0.f);
        uint2 sp0 = split_pack(t0, t1), sp1 = split_pack(t2, t3);
        uint2 q0 = make_uint2((uint32)__shfl_xor((int)sp0.x, 16, 64),
                              (uint32)__shfl_xor((int)sp0.y, 16, 64));
        uint2 q1 = make_uint2((uint32)__shfl_xor((int)sp1.x, 16, 64),
                              (uint32)__shfl_xor((int)sp1.y, 16, 64));
        uint4 val = (slot == 0) ? make_uint4(sp0.x, sp1.x, q0.x, q1.x)
                                : make_uint4(q0.y, q1.y, sp0.y, sp1.y);
        if (vld[nt]) {
          uint4* opb4 = (uint4*)actout + (size_t)(sc * (COUT / 8) + g2) * PPLANE * 2;
          store_halo_s<uint4, 2>(opb4, (int)px[nt], (int)py[nt], (int)ppix * 2 + slot, val);
        }
      }
    }
  } else if (OMODE == 1) {
    // single-bf16 RNE store (to act2)
#pragma unroll
    for (int mt = 0; mt < MT; ++mt) {
      const int ocb = mt * 16 + quad * 4;
      const int g2 = 2 * mt + (quad >> 1), slot = quad & 1;
      f32x4 bias4 = *(const f32x4*)(bias + ocb);
      f32x4 pr4 = *(const f32x4*)(pre + ocb);
#pragma unroll
      for (int nt = 0; nt < 4; ++nt) {
        if (!vld[nt]) continue;
        const uint32 ppix = boff[nt] + 1;
        float v0 = acc[mt][nt][0] + bias4[0], v1 = acc[mt][nt][1] + bias4[1];
        float v2 = acc[mt][nt][2] + bias4[2], v3 = acc[mt][nt][3] + bias4[3];
        float t0 = fmaxf(v0, 0.f) + pr4[0] * fminf(v0, 0.f);
        float t1 = fmaxf(v1, 0.f) + pr4[1] * fminf(v1, 0.f);
        float t2 = fmaxf(v2, 0.f) + pr4[2] * fminf(v2, 0.f);
        float t3 = fmaxf(v3, 0.f) + pr4[3] * fminf(v3, 0.f);
        uint2 sp = make_uint2(rne_pack(t0, t1), rne_pack(t2, t3));
        uint2* opb = actout + (size_t)(sc * (COUT / 8) + g2) * PPLANE * 2;
        store_halo_s<uint2, 2>(opb, (int)px[nt], (int)py[nt], (int)ppix * 2 + slot, sp);
      }
    }
  } else {
    // fused convT channel contraction: s_t = sum_ch wT[t][ch]*(acc+bias)
    float4 b4[MT];
#pragma unroll
    for (int mt = 0; mt < MT; ++mt) b4[mt] = *(const float4*)(bias + mt * 16 + quad * 4);
#pragma unroll
    for (int nt = 0; nt < 4; ++nt) {
      float vv[MT][4];
#pragma unroll
      for (int mt = 0; mt < MT; ++mt) {
        vv[mt][0] = acc[mt][nt][0] + b4[mt].x;
        vv[mt][1] = acc[mt][nt][1] + b4[mt].y;
        vv[mt][2] = acc[mt][nt][2] + b4[mt].z;
        vv[mt][3] = acc[mt][nt][3] + b4[mt].w;
      }
      float* sp = sout + (size_t)sc * 25 * PLANE + (int)(py[nt] * 270 + px[nt]);
#pragma unroll
      for (int t = 0; t < 25; ++t) {
        const float* wp = wTt + t * 32 + quad * 4;
        float c = 0.f;
#pragma unroll
        for (int mt = 0; mt < MT; ++mt) {
          float4 w4 = *(const float4*)(wp + mt * 16);
          c += w4.x * vv[mt][0] + w4.y * vv[mt][1] + w4.z * vv[mt][2] + w4.w * vv[mt][3];
        }
        c += __shfl_xor(c, 16, 64);
        c += __shfl_xor(c, 32, 64);
        if (quad == 0 && vld[nt]) sp[(size_t)t * PLANE] = c;
      }
    }
  }
}

// ---------------- convT pass 2: out = bt + sum_t s_t(shifted) ----------------
__global__ __launch_bounds__(256) void k_convT2(const float* __restrict__ s, const float* __restrict__ bt,
                                                float* __restrict__ yo) {
  int p = blockIdx.x * 256 + threadIdx.x;
  if (p >= PLANE) return;
  int sc = blockIdx.y;
  int y = p / 270, x = p - y * 270;
  float acc = bt[0];
  const float* sb = s + (size_t)sc * 25 * PLANE;
#pragma unroll
  for (int a = 0; a < 5; ++a) {
    int yy = y + a - 2;
    if ((unsigned)yy >= 270u) continue;
    const float* row = sb + (size_t)(a * 5) * PLANE + yy * 270;
#pragma unroll
    for (int b = 0; b < 5; ++b) {
      int xx = x + b - 2;
      if ((unsigned)xx < 270u) acc += row[(size_t)b * PLANE + xx];
    }
  }
  yo[(size_t)sc * PLANE + p] = acc;
}

// ---------------- norm projection scale ----------------
__global__ __launch_bounds__(256) void k_nrm(const float* __restrict__ yb, float* __restrict__ red) {
  int s = blockIdx.x;
  const float* ys = yb + (size_t)s * PLANE;
  float acc = 0.f;
  for (int i = threadIdx.x; i < PLANE; i += 256) { float v = ys[i]; acc += v * v; }
  float tot = blockReduceSum(acc);
  if (threadIdx.x == 0) {
    float nrm = sqrtf(tot);
    float eps = red[8 + s];
    red[16 + s] = (nrm > eps) ? eps / fmaxf(nrm, 1e-12f) : 1.0f;
  }
}

// ---------------- final: clip(z - scl*y), crop, mix ----------------
__global__ __launch_bounds__(256) void k_final(const float* __restrict__ z, const float* __restrict__ yb,
                                               const float* __restrict__ red, const float* __restrict__ mw,
                                               float* __restrict__ out) {
  int idx = blockIdx.x * 256 + threadIdx.x;
  if (idx >= 131072) return;
  int b = idx >> 16;
  int rem = idx & 65535;
  int h = rem >> 8, w = rem & 255;
  int p = (h + 7) * HP + (w + 7);
  float acc = 0.f;
#pragma unroll
  for (int d = 0; d < 4; ++d) {
    int s = b * 4 + d;
    float v = z[(size_t)s * PLANE + p] - red[16 + s] * yb[(size_t)s * PLANE + p];
    v = fminf(fmaxf(v, 0.f), 255.f);
    acc += mw[d] * v;
  }
  out[idx] = acc;
}

// =====================================================================
extern "C" void kernel_launch(void* const* d_in, const int* in_sizes, int n_in,
                              void* d_out, int out_size, void* d_ws, size_t ws_size,
                              hipStream_t stream) {
  (void)in_sizes; (void)n_in; (void)out_size;
  const float* x    = (const float*)d_in[0];
  const float* bk   = (const float*)d_in[1];
  const float* stdn = (const float*)d_in[2];
  const float* ww   = (const float*)d_in[3];
  const float* wwsc = (const float*)d_in[4];
  const float* alph = (const float*)d_in[5];
  const float* cw   = (const float*)d_in[6];
  const float* sf   = (const float*)d_in[7];
  const float* bf   = (const float*)d_in[8];
  const float* bt   = (const float*)d_in[9];
  const float* p1   = (const float*)d_in[10];
  const float* w1   = (const float*)d_in[11];
  const float* s1   = (const float*)d_in[12];
  const float* b1   = (const float*)d_in[13];
  const float* p2   = (const float*)d_in[14];
  const float* w2   = (const float*)d_in[15];
  const float* s2   = (const float*)d_in[16];
  const float* b2   = (const float*)d_in[17];
  const float* apj  = (const float*)d_in[18];
  const float* mwp  = (const float*)d_in[19];
  float* out = (float*)d_out;

  char* wsbase = (char*)d_ws;
  size_t off = 0;
  auto alloc = [&](size_t nbytes) -> char* {
    char* p = wsbase + off;
    off = (off + nbytes + 255) & ~(size_t)255;
    return p;
  };
  // ---- persistent region ----
  float*  zb  = (float*)alloc(8 * (size_t)PLANE * 4);
  float*  yb  = (float*)alloc(8 * (size_t)PLANE * 4);
  float*  red = (float*)alloc(64 * 4);
  float*  inv = (float*)alloc(32 * 4);
  float*  cwn = (float*)alloc(800 * 4);
  float*  wTt = (float*)alloc(800 * 4);
  unsigned short* w1f = (unsigned short*)alloc(5 * 36864 * (size_t)2);
  unsigned short* w2f = (unsigned short*)alloc(5 * 36864 * (size_t)2);
  // ---- union region ----
  size_t U0 = off;
  // DFT view
  float2* tw  = (float2*)alloc(2 * (size_t)PLANE * 4);
  float*  xp  = (float*)alloc(2 * (size_t)PLANE * 4);
  float*  rtm = (float*)alloc(2 * (size_t)PLANE * 4);
  float2* cb0 = (float2*)alloc(2 * 8 * (size_t)PLANE * 8);
  float2* cb1 = (float2*)alloc(2 * 8 * (size_t)PLANE * 8);
  float2* Yb  = (float2*)alloc(2 * 2 * (size_t)PLANE * 8);
  float2* Hf  = (float2*)alloc(2 * (size_t)PLANE * 4);
  float*  Sb  = (float*)alloc((size_t)PLANE * 4);
  float2* Tb  = (float2*)alloc(2 * 4 * (size_t)PLANE * 4);
  float*  ahw = (float*)alloc(540 * 4);
  float*  wwn = (float*)alloc(600 * 4);
  // conv view (aliases the DFT view). S = 8 if workspace allows, else 4.
  size_t conv8 = (size_t)8 * 4 * PPLANE * 32 + 256 + (size_t)8 * 8 * PPLANE * 16 + 256;
  int S = (ws_size >= U0 + conv8) ? 8 : 4;
  int nc = 8 / S;
  off = U0;
  uint4* act1 = (uint4*)alloc((size_t)S * 4 * PPLANE * 32);   // 32ch split acts; aliases sOb (S*25*PLANE f32)
  uint4* act2 = (uint4*)alloc((size_t)S * 8 * PPLANE * 16);   // 64ch single-bf16 acts
  float* sOb = (float*)act1;

  // setup
  k_twiddle<<<285, 256, 0, stream>>>(tw);
  k_sympad<<<(2 * PLANE + 255) / 256, 256, 0, stream>>>(x, xp);
  k_edget<<<1, 512, 0, stream>>>(bk, ahw);
  k_Hf<<<285, 256, 0, stream>>>(bk, Hf);
  k_wnorm<<<24, 256, 0, stream>>>(ww, wwsc, wwn, 25);
  k_wnorm<<<32, 256, 0, stream>>>(cw, sf, cwn, 25);
  k_wT<<<4, 256, 0, stream>>>(cwn, wTt);
  k_wfrag<32, 64><<<320, 256, 0, stream>>>(w1, s1, w1f);
  k_wfrag<64, 32><<<160, 256, 0, stream>>>(w2, s2, w2f);
  k_inv<<<1, 32, 0, stream>>>(p1, inv);
  k_S<<<285, 256, 0, stream>>>(wwn, Sb);
  k_T<<<(4 * PLANE + 255) / 256, 256, 0, stream>>>(Hf, Sb, alph, Tb);
  k_amp<<<4, 256, 0, stream>>>(Tb, red);
  k_eps<<<1, 64, 0, stream>>>(apj, stdn, red);

  dim3 g2(5, 45, 2), g8(5, 45, 8);

  // edgetaper
  k_rowT<6, true ><<<g2, 64, 0, stream>>>(xp, cb1, tw, -1.f);
  k_colT<6, false><<<g2, 64, 0, stream>>>(cb1, cb0, tw, -1.f, 1.f);
  k_mulHf<<<(2 * PLANE + 255) / 256, 256, 0, stream>>>(cb0, Hf, cb1);
  k_rowT<6, false><<<g2, 64, 0, stream>>>(cb1, cb0, tw, 1.f);
  k_colT<6, true ><<<g2, 64, 0, stream>>>(cb0, rtm, tw, 1.f, 1.f / (float)PLANE);
  k_taper<<<(2 * PLANE + 255) / 256, 256, 0, stream>>>(xp, rtm, ahw);

  // Y = fft2(xp)
  k_rowT<6, true ><<<g2, 64, 0, stream>>>(xp, cb1, tw, -1.f);
  k_colT<6, false><<<g2, 64, 0, stream>>>(cb1, Yb, tw, -1.f, 1.f);

  // z = ifft2(T*Y).real for all 8 (b,d)
  k_mulTY<<<(8 * PLANE + 255) / 256, 256, 0, stream>>>(Tb, Yb, cb0);
  k_rowT<6, false><<<g8, 64, 0, stream>>>(cb0, cb1, tw, 1.f);
  k_colT<6, true ><<<g8, 64, 0, stream>>>(cb1, zb, tw, 1.f, 1.f / (float)PLANE);

  // conv net, nc chunks of S samples
  for (int c = 0; c < nc; ++c) {
    const float* zc = zb + (size_t)c * S * PLANE;
    float* ybc = yb + (size_t)c * S * PLANE;
    k_conv5<<<dim3(285, S), 256, 0, stream>>>(zc, cwn, bf, p1, act1);
    for (int i = 0; i < 5; ++i) {
      // 32->64: split input, single-bf16 output
      k_mconv<32, 64, false, 1, false><<<dim3(289, S), 256, 0, stream>>>(
          act1, w1f + (size_t)i * 36864, b1 + i * 64, p2 + i * 64, (uint2*)act2, nullptr, nullptr, nullptr, nullptr);
      // 64->32: single-bf16 input
      if (i == 0)
        k_mconv<64, 32, true, 0, true><<<dim3(289, S), 256, 0, stream>>>(
            act2, w2f + (size_t)i * 36864, b2 + i * 32, p1 + (i + 1) * 32, (uint2*)act1, nullptr, (const uint2*)act1, inv, nullptr);
      else if (i < 4)
        k_mconv<64, 32, false, 0, true><<<dim3(289, S), 256, 0, stream>>>(
            act2, w2f + (size_t)i * 36864, b2 + i * 32, p1 + (i + 1) * 32, (uint2*)act1, nullptr, nullptr, nullptr, nullptr);
      else
        k_mconv<64, 32, false, 2, true><<<dim3(289, S), 256, 0, stream>>>(
            act2, w2f + (size_t)i * 36864, b2 + i * 32, nullptr, nullptr, sOb, nullptr, nullptr, wTt);
    }
    k_convT2<<<dim3(285, S), 256, 0, stream>>>(sOb, bt, ybc);
  }

  // projection + final mix
  k_nrm<<<8, 256, 0, stream>>>(yb, red);
  k_final<<<(131072 + 255) / 256, 256, 0, stream>>>(zb, yb, red, mwp, out);
}

// Round 14
// 1347.640 us; speedup vs baseline: 1.6753x; 1.1519x over previous
//
#include <hip/hip_runtime.h>
#include <math.h>

#define HP     270
#define PLANE  72900      // 270*270
#define PW     272
#define PPLANE 73984      // 272*272

typedef unsigned int uint32;
typedef unsigned short ushort;
typedef __attribute__((ext_vector_type(8))) short bf16x8;
typedef __attribute__((ext_vector_type(4))) float f32x4;

// ---------------- reduction helper ----------------
__device__ __forceinline__ float blockReduceSum(float val) {
  __shared__ float sh[16];
  int lane = threadIdx.x & 63, wid = threadIdx.x >> 6;
#pragma unroll
  for (int o = 32; o > 0; o >>= 1) val += __shfl_down(val, o, 64);
  __syncthreads();
  if (lane == 0) sh[wid] = val;
  __syncthreads();
  float tot = 0.f;
  int nw = (blockDim.x + 63) >> 6;
  for (int i = 0; i < nw; ++i) tot += sh[i];
  return tot;
}

// ---------------- twiddle matrix ----------------
__global__ __launch_bounds__(256) void k_twiddle(float2* __restrict__ tw) {
  int idx = blockIdx.x * 256 + threadIdx.x;
  if (idx >= PLANE) return;
  int j = idx / HP, k = idx % HP;
  int m = (j * k) % HP;
  double ang = (2.0 * M_PI * (double)m) / 270.0;
  tw[idx] = make_float2((float)cos(ang), (float)sin(ang));
}

// ---------------- symmetric pad x (2,256,256) -> xp (2,270,270), pad 7 ----------------
__global__ __launch_bounds__(256) void k_sympad(const float* __restrict__ x, float* __restrict__ xp) {
  int idx = blockIdx.x * 256 + threadIdx.x;
  if (idx >= 2 * PLANE) return;
  int b = idx / PLANE, p = idx % PLANE;
  int i = p / HP, j = p % HP;
  int si = i - 7; si = si < 0 ? -1 - si : (si > 255 ? 511 - si : si);
  int sj = j - 7; sj = sj < 0 ? -1 - sj : (sj > 255 ? 511 - sj : sj);
  xp[idx] = x[(b * 256 + si) * 256 + sj];
}

// ---------------- edgetaper 1D weights ----------------
__global__ __launch_bounds__(512) void k_edget(const float* __restrict__ bk, float* __restrict__ ahw) {
  __shared__ float pr[15], pc[15], acr[15], accl[15];
  int t = threadIdx.x;
  if (t < 15) {
    float sr = 0.f, scv = 0.f;
    for (int k = 0; k < 15; ++k) { sr += bk[t * 15 + k]; scv += bk[k * 15 + t]; }
    pr[t] = sr; pc[t] = scv;
  }
  __syncthreads();
  if (t < 30) {
    int l = t % 15; bool isr = (t < 15);
    const float* p = isr ? pr : pc;
    float s = 0.f;
    for (int j = 0; j + l < 15; ++j) s += p[j] * p[j + l];
    if (isr) acr[l] = s; else accl[l] = s;
  }
  __syncthreads();
  for (int i = t; i < 540; i += blockDim.x) {
    bool isr = (i < 270);
    int ii = isr ? i : i - 270;
    const float* ac = isr ? acr : accl;
    int m = (ii == 269) ? 0 : ii;
    float zv;
    if (m < 15) zv = ac[m];
    else if (m >= 255) zv = ac[269 - m];
    else zv = 0.f;
    ahw[i] = 1.f - zv / ac[0];
  }
}

// ---------------- Hf = psf2otf(blur 15x15) ----------------
__global__ __launch_bounds__(256) void k_Hf(const float* __restrict__ bk, float2* __restrict__ Hf) {
  int p = blockIdx.x * 256 + threadIdx.x;
  if (p >= PLANE) return;
  int u = p / HP, v = p % HP;
  float2 er[15], es[15];
#pragma unroll
  for (int r = 0; r < 15; ++r) {
    int m = ((u * (r - 7)) % HP + HP) % HP;
    float sn, cs;
    sincosf(2.f * (float)M_PI * (float)m / 270.f, &sn, &cs);
    er[r] = make_float2(cs, -sn);
    int m2 = ((v * (r - 7)) % HP + HP) % HP;
    sincosf(2.f * (float)M_PI * (float)m2 / 270.f, &sn, &cs);
    es[r] = make_float2(cs, -sn);
  }
  float ar = 0.f, ai = 0.f;
#pragma unroll 1
  for (int r = 0; r < 15; ++r) {
    float rr = 0.f, ri = 0.f;
#pragma unroll
    for (int s = 0; s < 15; ++s) {
      float wv = bk[r * 15 + s];
      rr += wv * es[s].x; ri += wv * es[s].y;
    }
    ar += er[r].x * rr - er[r].y * ri;
    ai += er[r].x * ri + er[r].y * rr;
  }
  Hf[p] = make_float2(ar, ai);
}

// ---------------- weight normalization, plain layout ----------------
__global__ __launch_bounds__(256) void k_wnorm(const float* __restrict__ w, const float* __restrict__ scale,
                                               float* __restrict__ out, int fsize) {
  int f = blockIdx.x;
  const float* wf = w + (size_t)f * fsize;
  float s = 0.f;
  for (int i = threadIdx.x; i < fsize; i += 256) s += wf[i];
  float mean = blockReduceSum(s) / (float)fsize;
  float s2 = 0.f;
  for (int i = threadIdx.x; i < fsize; i += 256) { float d = wf[i] - mean; s2 += d * d; }
  float nrm = sqrtf(blockReduceSum(s2));
  float sc = scale[f] / nrm;
  for (int i = threadIdx.x; i < fsize; i += 256) out[(size_t)f * fsize + i] = (wf[i] - mean) * sc;
}

// ---------------- transpose conv5 weights to tap-major (flipped) ----------------
__global__ void k_wT(const float* __restrict__ cwn, float* __restrict__ wT) {
  int idx = blockIdx.x * 256 + threadIdx.x;
  if (idx >= 800) return;
  int t = idx >> 5, f = idx & 31;
  int dri = t / 5, dci = t % 5;           // input offsets dr = dri-2, dc = dci-2
  wT[t * 32 + f] = cwn[f * 25 + (4 - dri) * 5 + (4 - dci)];
}

// ---------------- weight normalization -> split-bf16 MFMA fragment layout ----------------
template <int CIN, int COUT>
__global__ __launch_bounds__(256) void k_wfrag(const float* __restrict__ w, const float* __restrict__ scale,
                                               unsigned short* __restrict__ outb) {
  constexpr int KC = CIN / 32, MT = COUT / 16, FS = CIN * 9;
  int fg = blockIdx.x;
  int f = fg % COUT, iter = fg / COUT;
  const float* wf = w + (size_t)fg * FS;
  float s = 0.f;
  for (int i = threadIdx.x; i < FS; i += 256) s += wf[i];
  float mean = blockReduceSum(s) / (float)FS;
  float s2 = 0.f;
  for (int i = threadIdx.x; i < FS; i += 256) { float d = wf[i] - mean; s2 += d * d; }
  float nrm = sqrtf(blockReduceSum(s2));
  float scv = scale[fg] / nrm;
  unsigned short* dst0 = outb + (size_t)iter * (9 * KC * MT * 64 * 16);
  for (int i = threadIdx.x; i < FS; i += 256) {
    float val = (wf[i] - mean) * scv;
    int ci = i / 9, rs = i - ci * 9;
    int kc = ci >> 5, cil = ci & 31, q = cil >> 3, j = cil & 7;
    int mt = f >> 4, ocl = f & 15, lane = q * 16 + ocl;
    unsigned short* d2 = dst0 + ((((rs * KC + kc) * MT + mt) * 64 + lane) * 16);
    uint32 u = __float_as_uint(val);
    d2[j] = (unsigned short)(u >> 16);
    float lof = val - __uint_as_float(u & 0xFFFF0000u);
    d2[8 + j] = (unsigned short)(__float_as_uint(lof) >> 16);
  }
}

// ---------------- S = sum_f |FT(ww_f 5x5)|^2 ----------------
__global__ __launch_bounds__(256) void k_S(const float* __restrict__ wwn, float* __restrict__ S) {
  int p = blockIdx.x * 256 + threadIdx.x;
  if (p >= PLANE) return;
  int u = p / HP, v = p % HP;
  float2 er[5], es[5];
#pragma unroll
  for (int r = 0; r < 5; ++r) {
    float sn, cs;
    int m = (u * r) % HP;
    sincosf(2.f * (float)M_PI * (float)m / 270.f, &sn, &cs);
    er[r] = make_float2(cs, -sn);
    int m2 = (v * r) % HP;
    sincosf(2.f * (float)M_PI * (float)m2 / 270.f, &sn, &cs);
    es[r] = make_float2(cs, -sn);
  }
  float prr[25], pii[25];
#pragma unroll
  for (int r = 0; r < 5; ++r)
#pragma unroll
    for (int s = 0; s < 5; ++s) {
      prr[r * 5 + s] = er[r].x * es[s].x - er[r].y * es[s].y;
      pii[r * 5 + s] = er[r].x * es[s].y + er[r].y * es[s].x;
    }
  float acc = 0.f;
#pragma unroll 1
  for (int f = 0; f < 24; ++f) {
    float xr = 0.f, xi = 0.f;
#pragma unroll
    for (int t = 0; t < 25; ++t) {
      float wv = wwn[f * 25 + t];
      xr += wv * prr[t]; xi += wv * pii[t];
    }
    acc += xr * xr + xi * xi;
  }
  S[p] = acc;
}

// ---------------- T = conj(Hf)/(|Hf|^2 + a_d S) ----------------
__global__ __launch_bounds__(256) void k_T(const float2* __restrict__ Hf, const float* __restrict__ S,
                                           const float* __restrict__ alpha, float2* __restrict__ T) {
  int idx = blockIdx.x * 256 + threadIdx.x;
  if (idx >= 4 * PLANE) return;
  int d = idx / PLANE, p = idx % PLANE;
  float a = expf(alpha[d]);
  float2 h = Hf[p];
  float den = h.x * h.x + h.y * h.y + a * S[p];
  T[idx] = make_float2(h.x / den, -h.y / den);
}

__global__ __launch_bounds__(256) void k_amp(const float2* __restrict__ T, float* __restrict__ red) {
  int d = blockIdx.x;
  const float2* Td = T + (size_t)d * PLANE;
  float acc = 0.f;
  for (int i = threadIdx.x; i < PLANE; i += 256) { float2 t = Td[i]; acc += t.x * t.x + t.y * t.y; }
  float tot = blockReduceSum(acc);
  if (threadIdx.x == 0) red[d] = tot / (float)PLANE;
}

__global__ void k_eps(const float* __restrict__ apj, const float* __restrict__ stdn, float* __restrict__ red) {
  int s = threadIdx.x;
  if (s < 8) {
    int b = s >> 2, d = s & 3;
    red[8 + s] = expf(apj[0]) * stdn[b] * sqrtf(red[d]) * sqrtf(72899.f);
  }
}

__global__ void k_inv(const float* __restrict__ p, float* __restrict__ inv) {
  int t = threadIdx.x;
  if (t < 32) inv[t] = 1.f / p[t];
}

// ---------------- register-tiled DFT passes ----------------
template <int NR, bool REALIN>
__global__ __launch_bounds__(64) void k_rowT(const void* __restrict__ inv_, float2* __restrict__ out,
                                             const float2* __restrict__ tw, float sgn) {
  int v = blockIdx.x * 64 + threadIdx.x;
  int r0 = blockIdx.y * NR;
  int m = blockIdx.z;
  bool ok = v < HP;
  int vc = ok ? v : 0;
  float P[NR], R[NR], Q[NR], Sm[NR];
#pragma unroll
  for (int i = 0; i < NR; ++i) { P[i] = R[i] = 0.f; if (!REALIN) { Q[i] = Sm[i] = 0.f; } }
  const float*  inR = (const float*)inv_  + ((size_t)m * HP + r0) * HP;
  const float2* inC = (const float2*)inv_ + ((size_t)m * HP + r0) * HP;
#pragma unroll 3
  for (int w = 0; w < HP; ++w) {
    float2 t = tw[w * HP + vc];
#pragma unroll
    for (int i = 0; i < NR; ++i) {
      if (REALIN) {
        float a = inR[i * HP + w];
        P[i] += a * t.x; R[i] += a * t.y;
      } else {
        float2 g = inC[i * HP + w];
        P[i] += g.x * t.x; Q[i] += g.y * t.y;
        R[i] += g.x * t.y; Sm[i] += g.y * t.x;
      }
    }
  }
  if (ok) {
#pragma unroll
    for (int i = 0; i < NR; ++i) {
      float ar, ai;
      if (REALIN) { ar = P[i]; ai = sgn * R[i]; }
      else        { ar = P[i] - sgn * Q[i]; ai = sgn * R[i] + Sm[i]; }
      out[((size_t)m * HP + r0 + i) * HP + v] = make_float2(ar, ai);
    }
  }
}

template <int NU, bool REALOUT>
__global__ __launch_bounds__(64) void k_colT(const float2* __restrict__ in, void* __restrict__ outv,
                                             const float2* __restrict__ tw, float sgn, float scale) {
  int v = blockIdx.x * 64 + threadIdx.x;
  int u0 = blockIdx.y * NU;
  int m = blockIdx.z;
  bool ok = v < HP;
  int vc = ok ? v : 0;
  float P[NU], Q[NU], R[NU], Sm[NU];
#pragma unroll
  for (int j = 0; j < NU; ++j) { P[j] = Q[j] = 0.f; if (!REALOUT) { R[j] = Sm[j] = 0.f; } }
  const float2* cp = in + (size_t)m * PLANE + vc;
#pragma unroll 3
  for (int h = 0; h < HP; ++h) {
    float2 g = cp[(size_t)h * HP];
    const float2* tr = tw + h * HP + u0;
#pragma unroll
    for (int j = 0; j < NU; ++j) {
      float2 t = tr[j];
      P[j] += g.x * t.x; Q[j] += g.y * t.y;
      if (!REALOUT) { R[j] += g.x * t.y; Sm[j] += g.y * t.x; }
    }
  }
  if (ok) {
#pragma unroll
    for (int j = 0; j < NU; ++j) {
      float ar = (P[j] - sgn * Q[j]) * scale;
      if (REALOUT) ((float*)outv)[((size_t)m * HP + u0 + j) * HP + v] = ar;
      else {
        float ai = (sgn * R[j] + Sm[j]) * scale;
        ((float2*)outv)[((size_t)m * HP + u0 + j) * HP + v] = make_float2(ar, ai);
      }
    }
  }
}

// ---------------- pointwise ----------------
__global__ __launch_bounds__(256) void k_mulHf(const float2* __restrict__ in, const float2* __restrict__ Hf,
                                               float2* __restrict__ out) {
  int idx = blockIdx.x * 256 + threadIdx.x;
  if (idx >= 2 * PLANE) return;
  int p = idx % PLANE;
  float2 a = in[idx], b = Hf[p];
  out[idx] = make_float2(a.x * b.x - a.y * b.y, a.x * b.y + a.y * b.x);
}

__global__ __launch_bounds__(256) void k_taper(float* __restrict__ xp, const float* __restrict__ blr,
                                               const float* __restrict__ ahw) {
  int idx = blockIdx.x * 256 + threadIdx.x;
  if (idx >= 2 * PLANE) return;
  int p = idx % PLANE;
  int i = p / HP, j = p % HP;
  float al = ahw[i] * ahw[270 + j];
  xp[idx] = al * xp[idx] + (1.f - al) * blr[idx];
}

__global__ __launch_bounds__(256) void k_mulTY(const float2* __restrict__ T, const float2* __restrict__ Y,
                                               float2* __restrict__ out) {
  int idx = blockIdx.x * 256 + threadIdx.x;
  if (idx >= 8 * PLANE) return;
  int s = idx / PLANE, p = idx % PLANE;
  int b = s >> 2, d = s & 3;
  float2 a = T[(size_t)d * PLANE + p], y = Y[(size_t)b * PLANE + p];
  out[idx] = make_float2(a.x * y.x - a.y * y.y, a.x * y.y + a.y * y.x);
}

// ---------------- pack helpers ----------------
__device__ __forceinline__ uint32 rne_pack(float a, float b) {
  uint32 ua = __float_as_uint(a), ub = __float_as_uint(b);
  ua += 0x7FFFu + ((ua >> 16) & 1u);
  ub += 0x7FFFu + ((ub >> 16) & 1u);
  return (ua >> 16) | (ub & 0xFFFF0000u);
}

__device__ __forceinline__ ushort rne1(float a) {
  uint32 ua = __float_as_uint(a);
  ua += 0x7FFFu + ((ua >> 16) & 1u);
  return (ushort)(ua >> 16);
}

template <typename T, int STRIDE>
__device__ __forceinline__ void store_halo_s(T* __restrict__ op, int xx, int yy, int o, T val) {
  op[o] = val;
  bool xl = (xx == 0), xr = (xx == 269), yt = (yy == 0), yb = (yy == 269);
  if (xl) op[o - STRIDE] = val;
  if (xr) op[o + STRIDE] = val;
  if (yt) { op[o - PW * STRIDE] = val; if (xl) op[o - (PW + 1) * STRIDE] = val; if (xr) op[o - (PW - 1) * STRIDE] = val; }
  if (yb) { op[o + PW * STRIDE] = val; if (xl) op[o + (PW - 1) * STRIDE] = val; if (xr) op[o + (PW + 1) * STRIDE] = val; }
}

// ---------------- first conv 5x5 1->32 -> single-bf16 act records ----------------
__global__ __launch_bounds__(256) void k_conv5(const float* __restrict__ z, const float* __restrict__ cw,
                                               const float* __restrict__ bias, const float* __restrict__ pre,
                                               uint4* __restrict__ actout) {
  int p = blockIdx.x * 256 + threadIdx.x;
  if (p >= PLANE) return;
  int sc = blockIdx.y;
  int i = p / HP, j = p % HP;
  const float* zs = z + (size_t)sc * PLANE;
  float v[25];
#pragma unroll
  for (int r = 0; r < 5; ++r) {
    int ii = i + r - 2; ii = ii < 0 ? -1 - ii : (ii > 269 ? 539 - ii : ii);
#pragma unroll
    for (int s = 0; s < 5; ++s) {
      int jj = j + s - 2; jj = jj < 0 ? -1 - jj : (jj > 269 ? 539 - jj : jj);
      v[r * 5 + s] = zs[ii * HP + jj];
    }
  }
  int o = (i + 1) * PW + (j + 1);
#pragma unroll 1
  for (int g = 0; g < 4; ++g) {
    float tt[8];
#pragma unroll
    for (int r8 = 0; r8 < 8; ++r8) {
      int oc = 8 * g + r8;
      float a = bias[oc];
#pragma unroll
      for (int k = 0; k < 25; ++k) a += cw[oc * 25 + k] * v[k];
      float pa = pre[oc];
      tt[r8] = fmaxf(a, 0.f) + pa * fminf(a, 0.f);
    }
    uint4 sp = make_uint4(rne_pack(tt[0], tt[1]), rne_pack(tt[2], tt[3]),
                          rne_pack(tt[4], tt[5]), rne_pack(tt[6], tt[7]));
    uint4* opb = actout + (size_t)(sc * 4 + g) * PPLANE;
    store_halo_s<uint4, 1>(opb, j, i, o, sp);
  }
}

// ---------------- MFMA 3x3 conv with LDS tile staging (single-bf16 acts) ----------------
// Block = 16x16 pixel tile. Input: single-bf16 records (uint4 per 8-ch group),
// all CIN/8 groups staged once; 2 MFMAs (Wh,Wl x B) per fragment.
// OMODE: 1 = single-bf16 RNE store (+optional SC reconstruction), 2 = fused convT (bf16 tap planes).
#define TSTRIDE 144
template <int CIN, int COUT, bool SC, int OMODE>
__global__ __launch_bounds__(256, 3) void k_mconv(
    const uint4* __restrict__ act, const unsigned short* __restrict__ wf,
    const float* __restrict__ bias, const float* __restrict__ pre,
    uint2* __restrict__ actout, ushort* __restrict__ sout,
    const uint2* __restrict__ scact, const float* __restrict__ scinv,
    const float* __restrict__ wTt) {
  constexpr int KC = CIN / 32, MT = COUT / 16;
  __shared__ uint4 smem4[18 * 18 * TSTRIDE / 16];
  unsigned char* smem = (unsigned char*)smem4;

  const int lane = threadIdx.x & 63, wv = threadIdx.x >> 6;
  const int quad = lane >> 4, col = lane & 15;
  const int sc = blockIdx.y;
  int bx = blockIdx.x;
  int tile = (bx < 288) ? ((bx & 7) * 36 + (bx >> 3)) : 288;
  const int tx0 = (tile % 17) * 16, ty0 = (tile / 17) * 16;

  uint32 py[4], px[4], boff[4];
  bool vld[4];
#pragma unroll
  for (int nt = 0; nt < 4; ++nt) {
    int xr = tx0 + col, yr = ty0 + wv * 4 + nt;
    vld[nt] = (xr < 270) && (yr < 270);
    int xx = xr > 269 ? 269 : xr;
    int yy = yr > 269 ? 269 : yr;
    px[nt] = xx; py[nt] = yy;
    boff[nt] = (yy + 1) * PW + xx;
  }

  f32x4 acc[MT][4];
#pragma unroll
  for (int mt = 0; mt < MT; ++mt)
#pragma unroll
    for (int nt = 0; nt < 4; ++nt) { f32x4 z = {0.f, 0.f, 0.f, 0.f}; acc[mt][nt] = z; }

  // ---- stage all CIN/8 single records once ----
  {
    const uint4* srcb = act + (size_t)(sc * (CIN / 8)) * PPLANE;
    for (int i = threadIdx.x; i < 324 * (CIN / 8); i += 256) {
      int g = i / 324, pxl = i - g * 324;
      int pyy = pxl / 18, pxx = pxl - pyy * 18;
      int gy = ty0 + pyy; if (gy > 271) gy = 271;
      int gx = tx0 + pxx; if (gx > 271) gx = 271;
      uint4 v = srcb[(size_t)g * PPLANE + gy * PW + gx];
      *(uint4*)(smem + pxl * TSTRIDE + g * 16) = v;
    }
  }
  __syncthreads();
#pragma unroll 1
  for (int kc = 0; kc < KC; ++kc) {
#pragma unroll
    for (int o = 0; o < 9; ++o) {
      const int dy = o / 3, dx = o % 3;
      union { uint4 u; bf16x8 v; } Wh[MT], Wl[MT];
#pragma unroll
      for (int mt = 0; mt < MT; ++mt) {
        const uint4* wp = (const uint4*)wf + ((((o * KC + kc) * MT + mt) * 64 + lane) * 2);
        Wh[mt].u = wp[0]; Wl[mt].u = wp[1];
      }
      const int lx = col + dx;
#pragma unroll
      for (int nt = 0; nt < 4; ++nt) {
        const int ly = wv * 4 + nt + dy;
        union { uint4 u; bf16x8 v; } B;
        B.u = *(const uint4*)(smem + (ly * 18 + lx) * TSTRIDE + (kc * 4 + quad) * 16);
#pragma unroll
        for (int mt = 0; mt < MT; ++mt)
          acc[mt][nt] = __builtin_amdgcn_mfma_f32_16x16x32_bf16(Wh[mt].v, B.v, acc[mt][nt], 0, 0, 0);
#pragma unroll
        for (int mt = 0; mt < MT; ++mt)
          acc[mt][nt] = __builtin_amdgcn_mfma_f32_16x16x32_bf16(Wl[mt].v, B.v, acc[mt][nt], 0, 0, 0);
      }
    }
  }

  if (OMODE == 1) {
    // single-bf16 RNE store, with optional shortcut reconstruction
#pragma unroll
    for (int mt = 0; mt < MT; ++mt) {
      const int ocb = mt * 16 + quad * 4;
      const int g2 = 2 * mt + (quad >> 1), slot = quad & 1;
      f32x4 bias4 = *(const f32x4*)(bias + ocb);
      f32x4 pr4 = *(const f32x4*)(pre + ocb);
      f32x4 inv4;
      if (SC) inv4 = *(const f32x4*)(scinv + ocb);
#pragma unroll
      for (int nt = 0; nt < 4; ++nt) {
        if (!vld[nt]) continue;
        const uint32 ppix = boff[nt] + 1;
        float v0 = acc[mt][nt][0] + bias4[0], v1 = acc[mt][nt][1] + bias4[1];
        float v2 = acc[mt][nt][2] + bias4[2], v3 = acc[mt][nt][3] + bias4[3];
        if (SC) {
          uint2 h = scact[((size_t)(sc * (COUT / 8) + g2) * PPLANE + ppix) * 2 + slot];
          float s0 = __uint_as_float(h.x << 16), s1 = __uint_as_float(h.x & 0xFFFF0000u);
          float s2 = __uint_as_float(h.y << 16), s3 = __uint_as_float(h.y & 0xFFFF0000u);
          v0 += (s0 >= 0.f) ? s0 : s0 * inv4[0];
          v1 += (s1 >= 0.f) ? s1 : s1 * inv4[1];
          v2 += (s2 >= 0.f) ? s2 : s2 * inv4[2];
          v3 += (s3 >= 0.f) ? s3 : s3 * inv4[3];
        }
        float t0 = fmaxf(v0, 0.f) + pr4[0] * fminf(v0, 0.f);
        float t1 = fmaxf(v1, 0.f) + pr4[1] * fminf(v1, 0.f);
        float t2 = fmaxf(v2, 0.f) + pr4[2] * fminf(v2, 0.f);
        float t3 = fmaxf(v3, 0.f) + pr4[3] * fminf(v3, 0.f);
        uint2 sp = make_uint2(rne_pack(t0, t1), rne_pack(t2, t3));
        uint2* opb = actout + (size_t)(sc * (COUT / 8) + g2) * PPLANE * 2;
        store_halo_s<uint2, 2>(opb, (int)px[nt], (int)py[nt], (int)ppix * 2 + slot, sp);
      }
    }
  } else {
    // fused convT channel contraction: s_t = sum_ch wT[t][ch]*(acc+bias) -> bf16 tap planes
    float4 b4[MT];
#pragma unroll
    for (int mt = 0; mt < MT; ++mt) b4[mt] = *(const float4*)(bias + mt * 16 + quad * 4);
#pragma unroll
    for (int nt = 0; nt < 4; ++nt) {
      float vv[MT][4];
#pragma unroll
      for (int mt = 0; mt < MT; ++mt) {
        vv[mt][0] = acc[mt][nt][0] + b4[mt].x;
        vv[mt][1] = acc[mt][nt][1] + b4[mt].y;
        vv[mt][2] = acc[mt][nt][2] + b4[mt].z;
        vv[mt][3] = acc[mt][nt][3] + b4[mt].w;
      }
      ushort* sp = sout + (size_t)sc * 25 * PLANE + (int)(py[nt] * 270 + px[nt]);
#pragma unroll
      for (int t = 0; t < 25; ++t) {
        const float* wp = wTt + t * 32 + quad * 4;
        float c = 0.f;
#pragma unroll
        for (int mt = 0; mt < MT; ++mt) {
          float4 w4 = *(const float4*)(wp + mt * 16);
          c += w4.x * vv[mt][0] + w4.y * vv[mt][1] + w4.z * vv[mt][2] + w4.w * vv[mt][3];
        }
        c += __shfl_xor(c, 16, 64);
        c += __shfl_xor(c, 32, 64);
        if (quad == 0 && vld[nt]) sp[(size_t)t * PLANE] = rne1(c);
      }
    }
  }
}

// ---------------- convT pass 2: out = bt + sum_t s_t(shifted), bf16 tap planes ----------------
__global__ __launch_bounds__(256) void k_convT2(const ushort* __restrict__ s, const float* __restrict__ bt,
                                                float* __restrict__ yo) {
  int p = blockIdx.x * 256 + threadIdx.x;
  if (p >= PLANE) return;
  int sc = blockIdx.y;
  int y = p / 270, x = p - y * 270;
  float acc = bt[0];
  const ushort* sb = s + (size_t)sc * 25 * PLANE;
#pragma unroll
  for (int a = 0; a < 5; ++a) {
    int yy = y + a - 2;
    if ((unsigned)yy >= 270u) continue;
    const ushort* row = sb + (size_t)(a * 5) * PLANE + yy * 270;
#pragma unroll
    for (int b = 0; b < 5; ++b) {
      int xx = x + b - 2;
      if ((unsigned)xx < 270u) acc += __uint_as_float(((uint32)row[(size_t)b * PLANE + xx]) << 16);
    }
  }
  yo[(size_t)sc * PLANE + p] = acc;
}

// ---------------- norm projection scale ----------------
__global__ __launch_bounds__(256) void k_nrm(const float* __restrict__ yb, float* __restrict__ red) {
  int s = blockIdx.x;
  const float* ys = yb + (size_t)s * PLANE;
  float acc = 0.f;
  for (int i = threadIdx.x; i < PLANE; i += 256) { float v = ys[i]; acc += v * v; }
  float tot = blockReduceSum(acc);
  if (threadIdx.x == 0) {
    float nrm = sqrtf(tot);
    float eps = red[8 + s];
    red[16 + s] = (nrm > eps) ? eps / fmaxf(nrm, 1e-12f) : 1.0f;
  }
}

// ---------------- final: clip(z - scl*y), crop, mix ----------------
__global__ __launch_bounds__(256) void k_final(const float* __restrict__ z, const float* __restrict__ yb,
                                               const float* __restrict__ red, const float* __restrict__ mw,
                                               float* __restrict__ out) {
  int idx = blockIdx.x * 256 + threadIdx.x;
  if (idx >= 131072) return;
  int b = idx >> 16;
  int rem = idx & 65535;
  int h = rem >> 8, w = rem & 255;
  int p = (h + 7) * HP + (w + 7);
  float acc = 0.f;
#pragma unroll
  for (int d = 0; d < 4; ++d) {
    int s = b * 4 + d;
    float v = z[(size_t)s * PLANE + p] - red[16 + s] * yb[(size_t)s * PLANE + p];
    v = fminf(fmaxf(v, 0.f), 255.f);
    acc += mw[d] * v;
  }
  out[idx] = acc;
}

// =====================================================================
extern "C" void kernel_launch(void* const* d_in, const int* in_sizes, int n_in,
                              void* d_out, int out_size, void* d_ws, size_t ws_size,
                              hipStream_t stream) {
  (void)in_sizes; (void)n_in; (void)out_size;
  const float* x    = (const float*)d_in[0];
  const float* bk   = (const float*)d_in[1];
  const float* stdn = (const float*)d_in[2];
  const float* ww   = (const float*)d_in[3];
  const float* wwsc = (const float*)d_in[4];
  const float* alph = (const float*)d_in[5];
  const float* cw   = (const float*)d_in[6];
  const float* sf   = (const float*)d_in[7];
  const float* bf   = (const float*)d_in[8];
  const float* bt   = (const float*)d_in[9];
  const float* p1   = (const float*)d_in[10];
  const float* w1   = (const float*)d_in[11];
  const float* s1   = (const float*)d_in[12];
  const float* b1   = (const float*)d_in[13];
  const float* p2   = (const float*)d_in[14];
  const float* w2   = (const float*)d_in[15];
  const float* s2   = (const float*)d_in[16];
  const float* b2   = (const float*)d_in[17];
  const float* apj  = (const float*)d_in[18];
  const float* mwp  = (const float*)d_in[19];
  float* out = (float*)d_out;

  char* wsbase = (char*)d_ws;
  size_t off = 0;
  auto alloc = [&](size_t nbytes) -> char* {
    char* p = wsbase + off;
    off = (off + nbytes + 255) & ~(size_t)255;
    return p;
  };
  // ---- persistent region ----
  float*  zb  = (float*)alloc(8 * (size_t)PLANE * 4);
  float*  yb  = (float*)alloc(8 * (size_t)PLANE * 4);
  float*  red = (float*)alloc(64 * 4);
  float*  inv = (float*)alloc(32 * 4);
  float*  cwn = (float*)alloc(800 * 4);
  float*  wTt = (float*)alloc(800 * 4);
  unsigned short* w1f = (unsigned short*)alloc(5 * 36864 * (size_t)2);
  unsigned short* w2f = (unsigned short*)alloc(5 * 36864 * (size_t)2);
  // ---- union region ----
  size_t U0 = off;
  // DFT view
  float2* tw  = (float2*)alloc(2 * (size_t)PLANE * 4);
  float*  xp  = (float*)alloc(2 * (size_t)PLANE * 4);
  float*  rtm = (float*)alloc(2 * (size_t)PLANE * 4);
  float2* cb0 = (float2*)alloc(2 * 8 * (size_t)PLANE * 8);
  float2* cb1 = (float2*)alloc(2 * 8 * (size_t)PLANE * 8);
  float2* Yb  = (float2*)alloc(2 * 2 * (size_t)PLANE * 8);
  float2* Hf  = (float2*)alloc(2 * (size_t)PLANE * 4);
  float*  Sb  = (float*)alloc((size_t)PLANE * 4);
  float2* Tb  = (float2*)alloc(2 * 4 * (size_t)PLANE * 4);
  float*  ahw = (float*)alloc(540 * 4);
  float*  wwn = (float*)alloc(600 * 4);
  // conv view (aliases the DFT view). S = 8 if workspace allows, else 4.
  size_t conv8 = (size_t)8 * 4 * PPLANE * 16 + 256 + (size_t)8 * 8 * PPLANE * 16 + 256;
  int S = (ws_size >= U0 + conv8) ? 8 : 4;
  int nc = 8 / S;
  off = U0;
  uint4* act1 = (uint4*)alloc((size_t)S * 4 * PPLANE * 16);   // 32ch single-bf16 acts; aliases sOb (S*25*PLANE bf16)
  uint4* act2 = (uint4*)alloc((size_t)S * 8 * PPLANE * 16);   // 64ch single-bf16 acts
  ushort* sOb = (ushort*)act1;

  // setup
  k_twiddle<<<285, 256, 0, stream>>>(tw);
  k_sympad<<<(2 * PLANE + 255) / 256, 256, 0, stream>>>(x, xp);
  k_edget<<<1, 512, 0, stream>>>(bk, ahw);
  k_Hf<<<285, 256, 0, stream>>>(bk, Hf);
  k_wnorm<<<24, 256, 0, stream>>>(ww, wwsc, wwn, 25);
  k_wnorm<<<32, 256, 0, stream>>>(cw, sf, cwn, 25);
  k_wT<<<4, 256, 0, stream>>>(cwn, wTt);
  k_wfrag<32, 64><<<320, 256, 0, stream>>>(w1, s1, w1f);
  k_wfrag<64, 32><<<160, 256, 0, stream>>>(w2, s2, w2f);
  k_inv<<<1, 32, 0, stream>>>(p1, inv);
  k_S<<<285, 256, 0, stream>>>(wwn, Sb);
  k_T<<<(4 * PLANE + 255) / 256, 256, 0, stream>>>(Hf, Sb, alph, Tb);
  k_amp<<<4, 256, 0, stream>>>(Tb, red);
  k_eps<<<1, 64, 0, stream>>>(apj, stdn, red);

  dim3 g2(5, 45, 2), g8(5, 45, 8);

  // edgetaper
  k_rowT<6, true ><<<g2, 64, 0, stream>>>(xp, cb1, tw, -1.f);
  k_colT<6, false><<<g2, 64, 0, stream>>>(cb1, cb0, tw, -1.f, 1.f);
  k_mulHf<<<(2 * PLANE + 255) / 256, 256, 0, stream>>>(cb0, Hf, cb1);
  k_rowT<6, false><<<g2, 64, 0, stream>>>(cb1, cb0, tw, 1.f);
  k_colT<6, true ><<<g2, 64, 0, stream>>>(cb0, rtm, tw, 1.f, 1.f / (float)PLANE);
  k_taper<<<(2 * PLANE + 255) / 256, 256, 0, stream>>>(xp, rtm, ahw);

  // Y = fft2(xp)
  k_rowT<6, true ><<<g2, 64, 0, stream>>>(xp, cb1, tw, -1.f);
  k_colT<6, false><<<g2, 64, 0, stream>>>(cb1, Yb, tw, -1.f, 1.f);

  // z = ifft2(T*Y).real for all 8 (b,d)
  k_mulTY<<<(8 * PLANE + 255) / 256, 256, 0, stream>>>(Tb, Yb, cb0);
  k_rowT<6, false><<<g8, 64, 0, stream>>>(cb0, cb1, tw, 1.f);
  k_colT<6, true ><<<g8, 64, 0, stream>>>(cb1, zb, tw, 1.f, 1.f / (float)PLANE);

  // conv net, nc chunks of S samples
  for (int c = 0; c < nc; ++c) {
    const float* zc = zb + (size_t)c * S * PLANE;
    float* ybc = yb + (size_t)c * S * PLANE;
    k_conv5<<<dim3(285, S), 256, 0, stream>>>(zc, cwn, bf, p1, act1);
    for (int i = 0; i < 5; ++i) {
      // 32->64: single-bf16 in/out
      k_mconv<32, 64, false, 1><<<dim3(289, S), 256, 0, stream>>>(
          act1, w1f + (size_t)i * 36864, b1 + i * 64, p2 + i * 64, (uint2*)act2, nullptr, nullptr, nullptr, nullptr);
      // 64->32: single-bf16 in/out
      if (i == 0)
        k_mconv<64, 32, true, 1><<<dim3(289, S), 256, 0, stream>>>(
            act2, w2f + (size_t)i * 36864, b2 + i * 32, p1 + (i + 1) * 32, (uint2*)act1, nullptr, (const uint2*)act1, inv, nullptr);
      else if (i < 4)
        k_mconv<64, 32, false, 1><<<dim3(289, S), 256, 0, stream>>>(
            act2, w2f + (size_t)i * 36864, b2 + i * 32, p1 + (i + 1) * 32, (uint2*)act1, nullptr, nullptr, nullptr, nullptr);
      else
        k_mconv<64, 32, false, 2><<<dim3(289, S), 256, 0, stream>>>(
            act2, w2f + (size_t)i * 36864, b2 + i * 32, nullptr, nullptr, sOb, nullptr, nullptr, wTt);
    }
    k_convT2<<<dim3(285, S), 256, 0, stream>>>(sOb, bt, ybc);
  }

  // projection + final mix
  k_nrm<<<8, 256, 0, stream>>>(yb, red);
  k_final<<<(131072 + 255) / 256, 256, 0, stream>>>(zb, yb, red, mwp, out);
}

// Round 15
// 1198.510 us; speedup vs baseline: 1.8837x; 1.1244x over previous
//
#include <hip/hip_runtime.h>
#include <math.h>

#define HP     270
#define PLANE  72900      // 270*270
#define PW     272
#define PPLANE 73984      // 272*272

typedef unsigned int uint32;
typedef unsigned short ushort;
typedef __attribute__((ext_vector_type(8))) short bf16x8;
typedef __attribute__((ext_vector_type(4))) float f32x4;

// ---------------- reduction helper ----------------
__device__ __forceinline__ float blockReduceSum(float val) {
  __shared__ float sh[16];
  int lane = threadIdx.x & 63, wid = threadIdx.x >> 6;
#pragma unroll
  for (int o = 32; o > 0; o >>= 1) val += __shfl_down(val, o, 64);
  __syncthreads();
  if (lane == 0) sh[wid] = val;
  __syncthreads();
  float tot = 0.f;
  int nw = (blockDim.x + 63) >> 6;
  for (int i = 0; i < nw; ++i) tot += sh[i];
  return tot;
}

// ---------------- twiddle matrix ----------------
__global__ __launch_bounds__(256) void k_twiddle(float2* __restrict__ tw) {
  int idx = blockIdx.x * 256 + threadIdx.x;
  if (idx >= PLANE) return;
  int j = idx / HP, k = idx % HP;
  int m = (j * k) % HP;
  double ang = (2.0 * M_PI * (double)m) / 270.0;
  tw[idx] = make_float2((float)cos(ang), (float)sin(ang));
}

// ---------------- symmetric pad x (2,256,256) -> xp (2,270,270), pad 7 ----------------
__global__ __launch_bounds__(256) void k_sympad(const float* __restrict__ x, float* __restrict__ xp) {
  int idx = blockIdx.x * 256 + threadIdx.x;
  if (idx >= 2 * PLANE) return;
  int b = idx / PLANE, p = idx % PLANE;
  int i = p / HP, j = p % HP;
  int si = i - 7; si = si < 0 ? -1 - si : (si > 255 ? 511 - si : si);
  int sj = j - 7; sj = sj < 0 ? -1 - sj : (sj > 255 ? 511 - sj : sj);
  xp[idx] = x[(b * 256 + si) * 256 + sj];
}

// ---------------- edgetaper 1D weights ----------------
__global__ __launch_bounds__(512) void k_edget(const float* __restrict__ bk, float* __restrict__ ahw) {
  __shared__ float pr[15], pc[15], acr[15], accl[15];
  int t = threadIdx.x;
  if (t < 15) {
    float sr = 0.f, scv = 0.f;
    for (int k = 0; k < 15; ++k) { sr += bk[t * 15 + k]; scv += bk[k * 15 + t]; }
    pr[t] = sr; pc[t] = scv;
  }
  __syncthreads();
  if (t < 30) {
    int l = t % 15; bool isr = (t < 15);
    const float* p = isr ? pr : pc;
    float s = 0.f;
    for (int j = 0; j + l < 15; ++j) s += p[j] * p[j + l];
    if (isr) acr[l] = s; else accl[l] = s;
  }
  __syncthreads();
  for (int i = t; i < 540; i += blockDim.x) {
    bool isr = (i < 270);
    int ii = isr ? i : i - 270;
    const float* ac = isr ? acr : accl;
    int m = (ii == 269) ? 0 : ii;
    float zv;
    if (m < 15) zv = ac[m];
    else if (m >= 255) zv = ac[269 - m];
    else zv = 0.f;
    ahw[i] = 1.f - zv / ac[0];
  }
}

// ---------------- Hf = psf2otf(blur 15x15) ----------------
__global__ __launch_bounds__(256) void k_Hf(const float* __restrict__ bk, float2* __restrict__ Hf) {
  int p = blockIdx.x * 256 + threadIdx.x;
  if (p >= PLANE) return;
  int u = p / HP, v = p % HP;
  float2 er[15], es[15];
#pragma unroll
  for (int r = 0; r < 15; ++r) {
    int m = ((u * (r - 7)) % HP + HP) % HP;
    float sn, cs;
    sincosf(2.f * (float)M_PI * (float)m / 270.f, &sn, &cs);
    er[r] = make_float2(cs, -sn);
    int m2 = ((v * (r - 7)) % HP + HP) % HP;
    sincosf(2.f * (float)M_PI * (float)m2 / 270.f, &sn, &cs);
    es[r] = make_float2(cs, -sn);
  }
  float ar = 0.f, ai = 0.f;
#pragma unroll 1
  for (int r = 0; r < 15; ++r) {
    float rr = 0.f, ri = 0.f;
#pragma unroll
    for (int s = 0; s < 15; ++s) {
      float wv = bk[r * 15 + s];
      rr += wv * es[s].x; ri += wv * es[s].y;
    }
    ar += er[r].x * rr - er[r].y * ri;
    ai += er[r].x * ri + er[r].y * rr;
  }
  Hf[p] = make_float2(ar, ai);
}

// ---------------- weight normalization, plain layout ----------------
__global__ __launch_bounds__(256) void k_wnorm(const float* __restrict__ w, const float* __restrict__ scale,
                                               float* __restrict__ out, int fsize) {
  int f = blockIdx.x;
  const float* wf = w + (size_t)f * fsize;
  float s = 0.f;
  for (int i = threadIdx.x; i < fsize; i += 256) s += wf[i];
  float mean = blockReduceSum(s) / (float)fsize;
  float s2 = 0.f;
  for (int i = threadIdx.x; i < fsize; i += 256) { float d = wf[i] - mean; s2 += d * d; }
  float nrm = sqrtf(blockReduceSum(s2));
  float sc = scale[f] / nrm;
  for (int i = threadIdx.x; i < fsize; i += 256) out[(size_t)f * fsize + i] = (wf[i] - mean) * sc;
}

// ---------------- transpose conv5 weights to tap-major (flipped) ----------------
__global__ void k_wT(const float* __restrict__ cwn, float* __restrict__ wT) {
  int idx = blockIdx.x * 256 + threadIdx.x;
  if (idx >= 800) return;
  int t = idx >> 5, f = idx & 31;
  int dri = t / 5, dci = t % 5;           // input offsets dr = dri-2, dc = dci-2
  wT[t * 32 + f] = cwn[f * 25 + (4 - dri) * 5 + (4 - dci)];
}

// ---------------- weight normalization -> split-bf16 MFMA fragment layout ----------------
template <int CIN, int COUT>
__global__ __launch_bounds__(256) void k_wfrag(const float* __restrict__ w, const float* __restrict__ scale,
                                               unsigned short* __restrict__ outb) {
  constexpr int KC = CIN / 32, MT = COUT / 16, FS = CIN * 9;
  int fg = blockIdx.x;
  int f = fg % COUT, iter = fg / COUT;
  const float* wf = w + (size_t)fg * FS;
  float s = 0.f;
  for (int i = threadIdx.x; i < FS; i += 256) s += wf[i];
  float mean = blockReduceSum(s) / (float)FS;
  float s2 = 0.f;
  for (int i = threadIdx.x; i < FS; i += 256) { float d = wf[i] - mean; s2 += d * d; }
  float nrm = sqrtf(blockReduceSum(s2));
  float scv = scale[fg] / nrm;
  unsigned short* dst0 = outb + (size_t)iter * (9 * KC * MT * 64 * 16);
  for (int i = threadIdx.x; i < FS; i += 256) {
    float val = (wf[i] - mean) * scv;
    int ci = i / 9, rs = i - ci * 9;
    int kc = ci >> 5, cil = ci & 31, q = cil >> 3, j = cil & 7;
    int mt = f >> 4, ocl = f & 15, lane = q * 16 + ocl;
    unsigned short* d2 = dst0 + ((((rs * KC + kc) * MT + mt) * 64 + lane) * 16);
    uint32 u = __float_as_uint(val);
    d2[j] = (unsigned short)(u >> 16);
    float lof = val - __uint_as_float(u & 0xFFFF0000u);
    d2[8 + j] = (unsigned short)(__float_as_uint(lof) >> 16);
  }
}

// ---------------- S = sum_f |FT(ww_f 5x5)|^2 ----------------
__global__ __launch_bounds__(256) void k_S(const float* __restrict__ wwn, float* __restrict__ S) {
  int p = blockIdx.x * 256 + threadIdx.x;
  if (p >= PLANE) return;
  int u = p / HP, v = p % HP;
  float2 er[5], es[5];
#pragma unroll
  for (int r = 0; r < 5; ++r) {
    float sn, cs;
    int m = (u * r) % HP;
    sincosf(2.f * (float)M_PI * (float)m / 270.f, &sn, &cs);
    er[r] = make_float2(cs, -sn);
    int m2 = (v * r) % HP;
    sincosf(2.f * (float)M_PI * (float)m2 / 270.f, &sn, &cs);
    es[r] = make_float2(cs, -sn);
  }
  float prr[25], pii[25];
#pragma unroll
  for (int r = 0; r < 5; ++r)
#pragma unroll
    for (int s = 0; s < 5; ++s) {
      prr[r * 5 + s] = er[r].x * es[s].x - er[r].y * es[s].y;
      pii[r * 5 + s] = er[r].x * es[s].y + er[r].y * es[s].x;
    }
  float acc = 0.f;
#pragma unroll 1
  for (int f = 0; f < 24; ++f) {
    float xr = 0.f, xi = 0.f;
#pragma unroll
    for (int t = 0; t < 25; ++t) {
      float wv = wwn[f * 25 + t];
      xr += wv * prr[t]; xi += wv * pii[t];
    }
    acc += xr * xr + xi * xi;
  }
  S[p] = acc;
}

// ---------------- T = conj(Hf)/(|Hf|^2 + a_d S) ----------------
__global__ __launch_bounds__(256) void k_T(const float2* __restrict__ Hf, const float* __restrict__ S,
                                           const float* __restrict__ alpha, float2* __restrict__ T) {
  int idx = blockIdx.x * 256 + threadIdx.x;
  if (idx >= 4 * PLANE) return;
  int d = idx / PLANE, p = idx % PLANE;
  float a = expf(alpha[d]);
  float2 h = Hf[p];
  float den = h.x * h.x + h.y * h.y + a * S[p];
  T[idx] = make_float2(h.x / den, -h.y / den);
}

__global__ __launch_bounds__(256) void k_amp(const float2* __restrict__ T, float* __restrict__ red) {
  int d = blockIdx.x;
  const float2* Td = T + (size_t)d * PLANE;
  float acc = 0.f;
  for (int i = threadIdx.x; i < PLANE; i += 256) { float2 t = Td[i]; acc += t.x * t.x + t.y * t.y; }
  float tot = blockReduceSum(acc);
  if (threadIdx.x == 0) red[d] = tot / (float)PLANE;
}

__global__ void k_eps(const float* __restrict__ apj, const float* __restrict__ stdn, float* __restrict__ red) {
  int s = threadIdx.x;
  if (s < 8) {
    int b = s >> 2, d = s & 3;
    red[8 + s] = expf(apj[0]) * stdn[b] * sqrtf(red[d]) * sqrtf(72899.f);
  }
}

__global__ void k_inv(const float* __restrict__ p, float* __restrict__ inv) {
  int t = threadIdx.x;
  if (t < 32) inv[t] = 1.f / p[t];
}

// ---------------- register-tiled DFT passes ----------------
template <int NR, bool REALIN>
__global__ __launch_bounds__(64) void k_rowT(const void* __restrict__ inv_, float2* __restrict__ out,
                                             const float2* __restrict__ tw, float sgn) {
  int v = blockIdx.x * 64 + threadIdx.x;
  int r0 = blockIdx.y * NR;
  int m = blockIdx.z;
  bool ok = v < HP;
  int vc = ok ? v : 0;
  float P[NR], R[NR], Q[NR], Sm[NR];
#pragma unroll
  for (int i = 0; i < NR; ++i) { P[i] = R[i] = 0.f; if (!REALIN) { Q[i] = Sm[i] = 0.f; } }
  const float*  inR = (const float*)inv_  + ((size_t)m * HP + r0) * HP;
  const float2* inC = (const float2*)inv_ + ((size_t)m * HP + r0) * HP;
#pragma unroll 3
  for (int w = 0; w < HP; ++w) {
    float2 t = tw[w * HP + vc];
#pragma unroll
    for (int i = 0; i < NR; ++i) {
      if (REALIN) {
        float a = inR[i * HP + w];
        P[i] += a * t.x; R[i] += a * t.y;
      } else {
        float2 g = inC[i * HP + w];
        P[i] += g.x * t.x; Q[i] += g.y * t.y;
        R[i] += g.x * t.y; Sm[i] += g.y * t.x;
      }
    }
  }
  if (ok) {
#pragma unroll
    for (int i = 0; i < NR; ++i) {
      float ar, ai;
      if (REALIN) { ar = P[i]; ai = sgn * R[i]; }
      else        { ar = P[i] - sgn * Q[i]; ai = sgn * R[i] + Sm[i]; }
      out[((size_t)m * HP + r0 + i) * HP + v] = make_float2(ar, ai);
    }
  }
}

template <int NU, bool REALOUT>
__global__ __launch_bounds__(64) void k_colT(const float2* __restrict__ in, void* __restrict__ outv,
                                             const float2* __restrict__ tw, float sgn, float scale) {
  int v = blockIdx.x * 64 + threadIdx.x;
  int u0 = blockIdx.y * NU;
  int m = blockIdx.z;
  bool ok = v < HP;
  int vc = ok ? v : 0;
  float P[NU], Q[NU], R[NU], Sm[NU];
#pragma unroll
  for (int j = 0; j < NU; ++j) { P[j] = Q[j] = 0.f; if (!REALOUT) { R[j] = Sm[j] = 0.f; } }
  const float2* cp = in + (size_t)m * PLANE + vc;
#pragma unroll 3
  for (int h = 0; h < HP; ++h) {
    float2 g = cp[(size_t)h * HP];
    const float2* tr = tw + h * HP + u0;
#pragma unroll
    for (int j = 0; j < NU; ++j) {
      float2 t = tr[j];
      P[j] += g.x * t.x; Q[j] += g.y * t.y;
      if (!REALOUT) { R[j] += g.x * t.y; Sm[j] += g.y * t.x; }
    }
  }
  if (ok) {
#pragma unroll
    for (int j = 0; j < NU; ++j) {
      float ar = (P[j] - sgn * Q[j]) * scale;
      if (REALOUT) ((float*)outv)[((size_t)m * HP + u0 + j) * HP + v] = ar;
      else {
        float ai = (sgn * R[j] + Sm[j]) * scale;
        ((float2*)outv)[((size_t)m * HP + u0 + j) * HP + v] = make_float2(ar, ai);
      }
    }
  }
}

// ---------------- pointwise ----------------
__global__ __launch_bounds__(256) void k_mulHf(const float2* __restrict__ in, const float2* __restrict__ Hf,
                                               float2* __restrict__ out) {
  int idx = blockIdx.x * 256 + threadIdx.x;
  if (idx >= 2 * PLANE) return;
  int p = idx % PLANE;
  float2 a = in[idx], b = Hf[p];
  out[idx] = make_float2(a.x * b.x - a.y * b.y, a.x * b.y + a.y * b.x);
}

__global__ __launch_bounds__(256) void k_taper(float* __restrict__ xp, const float* __restrict__ blr,
                                               const float* __restrict__ ahw) {
  int idx = blockIdx.x * 256 + threadIdx.x;
  if (idx >= 2 * PLANE) return;
  int p = idx % PLANE;
  int i = p / HP, j = p % HP;
  float al = ahw[i] * ahw[270 + j];
  xp[idx] = al * xp[idx] + (1.f - al) * blr[idx];
}

__global__ __launch_bounds__(256) void k_mulTY(const float2* __restrict__ T, const float2* __restrict__ Y,
                                               float2* __restrict__ out) {
  int idx = blockIdx.x * 256 + threadIdx.x;
  if (idx >= 8 * PLANE) return;
  int s = idx / PLANE, p = idx % PLANE;
  int b = s >> 2, d = s & 3;
  float2 a = T[(size_t)d * PLANE + p], y = Y[(size_t)b * PLANE + p];
  out[idx] = make_float2(a.x * y.x - a.y * y.y, a.x * y.y + a.y * y.x);
}

// ---------------- pack helpers ----------------
__device__ __forceinline__ uint32 rne_pack(float a, float b) {
  uint32 ua = __float_as_uint(a), ub = __float_as_uint(b);
  ua += 0x7FFFu + ((ua >> 16) & 1u);
  ub += 0x7FFFu + ((ub >> 16) & 1u);
  return (ua >> 16) | (ub & 0xFFFF0000u);
}

__device__ __forceinline__ ushort rne1(float a) {
  uint32 ua = __float_as_uint(a);
  ua += 0x7FFFu + ((ua >> 16) & 1u);
  return (ushort)(ua >> 16);
}

template <typename T, int STRIDE>
__device__ __forceinline__ void store_halo_s(T* __restrict__ op, int xx, int yy, int o, T val) {
  op[o] = val;
  bool xl = (xx == 0), xr = (xx == 269), yt = (yy == 0), yb = (yy == 269);
  if (xl) op[o - STRIDE] = val;
  if (xr) op[o + STRIDE] = val;
  if (yt) { op[o - PW * STRIDE] = val; if (xl) op[o - (PW + 1) * STRIDE] = val; if (xr) op[o - (PW - 1) * STRIDE] = val; }
  if (yb) { op[o + PW * STRIDE] = val; if (xl) op[o + (PW - 1) * STRIDE] = val; if (xr) op[o + (PW + 1) * STRIDE] = val; }
}

// ---------------- first conv 5x5 1->32 -> single-bf16 act records ----------------
__global__ __launch_bounds__(256) void k_conv5(const float* __restrict__ z, const float* __restrict__ cw,
                                               const float* __restrict__ bias, const float* __restrict__ pre,
                                               uint4* __restrict__ actout) {
  int p = blockIdx.x * 256 + threadIdx.x;
  if (p >= PLANE) return;
  int sc = blockIdx.y;
  int i = p / HP, j = p % HP;
  const float* zs = z + (size_t)sc * PLANE;
  float v[25];
#pragma unroll
  for (int r = 0; r < 5; ++r) {
    int ii = i + r - 2; ii = ii < 0 ? -1 - ii : (ii > 269 ? 539 - ii : ii);
#pragma unroll
    for (int s = 0; s < 5; ++s) {
      int jj = j + s - 2; jj = jj < 0 ? -1 - jj : (jj > 269 ? 539 - jj : jj);
      v[r * 5 + s] = zs[ii * HP + jj];
    }
  }
  int o = (i + 1) * PW + (j + 1);
#pragma unroll 1
  for (int g = 0; g < 4; ++g) {
    float tt[8];
#pragma unroll
    for (int r8 = 0; r8 < 8; ++r8) {
      int oc = 8 * g + r8;
      float a = bias[oc];
#pragma unroll
      for (int k = 0; k < 25; ++k) a += cw[oc * 25 + k] * v[k];
      float pa = pre[oc];
      tt[r8] = fmaxf(a, 0.f) + pa * fminf(a, 0.f);
    }
    uint4 sp = make_uint4(rne_pack(tt[0], tt[1]), rne_pack(tt[2], tt[3]),
                          rne_pack(tt[4], tt[5]), rne_pack(tt[6], tt[7]));
    uint4* opb = actout + (size_t)(sc * 4 + g) * PPLANE;
    store_halo_s<uint4, 1>(opb, j, i, o, sp);
  }
}

// ---------------- FUSED RPA block: 32->64 (LDS intermediate) -> 64->32 ----------------
// Block = 16x16 output tile. stage0: 20x20 input (4 groups x 16B, stride 80).
// stage1: 18x18 x 64ch bf16 intermediate (8 groups x 16B, stride 144), RNE - numerically
// identical to the old global act2 (deterministic recompute of overlapping halos).
// OMODE: 1 = bf16 act store (+optional SC), 2 = fused convT tap-plane store.
template <bool SC, int OMODE>
__global__ __launch_bounds__(256, 2) void k_fused(
    const uint4* __restrict__ actin, const unsigned short* __restrict__ w1fb,
    const unsigned short* __restrict__ w2fb,
    const float* __restrict__ b1v, const float* __restrict__ p2v,
    const float* __restrict__ b2v, const float* __restrict__ p1v,
    uint2* __restrict__ actout, ushort* __restrict__ sout,
    const uint2* __restrict__ scact, const float* __restrict__ scinv,
    const float* __restrict__ wTt) {
  __shared__ uint4 smemAll[(32000 + 46656) / 16];
  unsigned char* st0 = (unsigned char*)smemAll;           // 400 px * 80 B
  unsigned char* st1 = (unsigned char*)smemAll + 32000;   // 324 px * 144 B

  const int lane = threadIdx.x & 63, wv = threadIdx.x >> 6;
  const int quad = lane >> 4, col = lane & 15;
  const int sc = blockIdx.y;
  int bx = blockIdx.x;
  int tile = (bx < 288) ? ((bx & 7) * 36 + (bx >> 3)) : 288;
  const int tx0 = (tile % 17) * 16, ty0 = (tile / 17) * 16;

  // ---- stage0: 20x20 region of actin ----
  {
    const uint4* srcb = actin + (size_t)(sc * 4) * PPLANE;
    for (int i = threadIdx.x; i < 1600; i += 256) {
      int g = i / 400, pxl = i - g * 400;
      int ry = pxl / 20, rx = pxl - ry * 20;
      int pr = ty0 - 1 + ry; pr = pr < 0 ? 0 : (pr > 271 ? 271 : pr);
      int pc = tx0 - 1 + rx; pc = pc < 0 ? 0 : (pc > 271 ? 271 : pc);
      uint4 v = srcb[(size_t)g * PPLANE + pr * PW + pc];
      *(uint4*)(st0 + pxl * 80 + g * 16) = v;
    }
  }
  __syncthreads();

  // ---- layer1: 32 -> 64 over 18x18 intermediate (6 sets of 16 px per wave) ----
  {
    int rb[6], pcl6[6];
#pragma unroll
    for (int s = 0; s < 6; ++s) {
      int p = (wv * 6 + s) * 16 + col; if (p > 323) p = 323;
      pcl6[s] = p;
      int iy = p / 18, ix = p - iy * 18;
      int gy = ty0 - 1 + iy; gy = gy < 0 ? 0 : (gy > 269 ? 269 : gy);
      int gx = tx0 - 1 + ix; gx = gx < 0 ? 0 : (gx > 269 ? 269 : gx);
      rb[s] = (((gy - ty0 + 1) * 20) + (gx - tx0 + 1)) * 80 + quad * 16;
    }
    f32x4 a1[4][6];
#pragma unroll
    for (int mt = 0; mt < 4; ++mt)
#pragma unroll
      for (int s = 0; s < 6; ++s) { f32x4 z = {0.f, 0.f, 0.f, 0.f}; a1[mt][s] = z; }
#pragma unroll
    for (int o = 0; o < 9; ++o) {
      const int dy = o / 3, dx = o % 3;
      const int doff = (dy * 20 + dx) * 80;
      union { uint4 u; bf16x8 v; } Wh[4], Wl[4];
#pragma unroll
      for (int mt = 0; mt < 4; ++mt) {
        const uint4* wp = (const uint4*)w1fb + (((o * 4 + mt) * 64 + lane) * 2);
        Wh[mt].u = wp[0]; Wl[mt].u = wp[1];
      }
#pragma unroll
      for (int s = 0; s < 6; ++s) {
        union { uint4 u; bf16x8 v; } B;
        B.u = *(const uint4*)(st0 + rb[s] + doff);
#pragma unroll
        for (int mt = 0; mt < 4; ++mt)
          a1[mt][s] = __builtin_amdgcn_mfma_f32_16x16x32_bf16(Wh[mt].v, B.v, a1[mt][s], 0, 0, 0);
#pragma unroll
        for (int mt = 0; mt < 4; ++mt)
          a1[mt][s] = __builtin_amdgcn_mfma_f32_16x16x32_bf16(Wl[mt].v, B.v, a1[mt][s], 0, 0, 0);
      }
    }
    // write intermediate (bias + prelu + RNE bf16) into st1
#pragma unroll
    for (int mt = 0; mt < 4; ++mt) {
      const int ocb = mt * 16 + quad * 4;
      const int g2 = 2 * mt + (quad >> 1), slot = quad & 1;
      f32x4 b4 = *(const f32x4*)(b1v + ocb);
      f32x4 pr4 = *(const f32x4*)(p2v + ocb);
#pragma unroll
      for (int s = 0; s < 6; ++s) {
        float v0 = a1[mt][s][0] + b4[0], v1 = a1[mt][s][1] + b4[1];
        float v2 = a1[mt][s][2] + b4[2], v3 = a1[mt][s][3] + b4[3];
        float t0 = fmaxf(v0, 0.f) + pr4[0] * fminf(v0, 0.f);
        float t1 = fmaxf(v1, 0.f) + pr4[1] * fminf(v1, 0.f);
        float t2 = fmaxf(v2, 0.f) + pr4[2] * fminf(v2, 0.f);
        float t3 = fmaxf(v3, 0.f) + pr4[3] * fminf(v3, 0.f);
        uint2 sp = make_uint2(rne_pack(t0, t1), rne_pack(t2, t3));
        *(uint2*)(st1 + pcl6[s] * 144 + g2 * 16 + slot * 8) = sp;
      }
    }
  }
  __syncthreads();

  // ---- layer2: 64 -> 32 over the 16x16 output tile ----
  uint32 py[4], px[4], boff[4];
  bool vld[4];
#pragma unroll
  for (int nt = 0; nt < 4; ++nt) {
    int xr = tx0 + col, yr = ty0 + wv * 4 + nt;
    vld[nt] = (xr < 270) && (yr < 270);
    int xx = xr > 269 ? 269 : xr;
    int yy = yr > 269 ? 269 : yr;
    px[nt] = xx; py[nt] = yy;
    boff[nt] = (yy + 1) * PW + xx;
  }
  f32x4 acc[2][4];
#pragma unroll
  for (int mt = 0; mt < 2; ++mt)
#pragma unroll
    for (int nt = 0; nt < 4; ++nt) { f32x4 z = {0.f, 0.f, 0.f, 0.f}; acc[mt][nt] = z; }
#pragma unroll 1
  for (int kc = 0; kc < 2; ++kc) {
#pragma unroll
    for (int o = 0; o < 9; ++o) {
      const int dy = o / 3, dx = o % 3;
      union { uint4 u; bf16x8 v; } Wh[2], Wl[2];
#pragma unroll
      for (int mt = 0; mt < 2; ++mt) {
        const uint4* wp = (const uint4*)w2fb + ((((o * 2 + kc) * 2 + mt) * 64 + lane) * 2);
        Wh[mt].u = wp[0]; Wl[mt].u = wp[1];
      }
      const int lx = col + dx;
#pragma unroll
      for (int nt = 0; nt < 4; ++nt) {
        const int ly = wv * 4 + nt + dy;
        union { uint4 u; bf16x8 v; } B;
        B.u = *(const uint4*)(st1 + (ly * 18 + lx) * 144 + (kc * 4 + quad) * 16);
#pragma unroll
        for (int mt = 0; mt < 2; ++mt)
          acc[mt][nt] = __builtin_amdgcn_mfma_f32_16x16x32_bf16(Wh[mt].v, B.v, acc[mt][nt], 0, 0, 0);
#pragma unroll
        for (int mt = 0; mt < 2; ++mt)
          acc[mt][nt] = __builtin_amdgcn_mfma_f32_16x16x32_bf16(Wl[mt].v, B.v, acc[mt][nt], 0, 0, 0);
      }
    }
  }

  if (OMODE == 1) {
#pragma unroll
    for (int mt = 0; mt < 2; ++mt) {
      const int ocb = mt * 16 + quad * 4;
      const int g2 = 2 * mt + (quad >> 1), slot = quad & 1;
      f32x4 bias4 = *(const f32x4*)(b2v + ocb);
      f32x4 pr4 = *(const f32x4*)(p1v + ocb);
      f32x4 inv4;
      if (SC) inv4 = *(const f32x4*)(scinv + ocb);
#pragma unroll
      for (int nt = 0; nt < 4; ++nt) {
        if (!vld[nt]) continue;
        const uint32 ppix = boff[nt] + 1;
        float v0 = acc[mt][nt][0] + bias4[0], v1 = acc[mt][nt][1] + bias4[1];
        float v2 = acc[mt][nt][2] + bias4[2], v3 = acc[mt][nt][3] + bias4[3];
        if (SC) {
          uint2 h = scact[((size_t)(sc * 4 + g2) * PPLANE + ppix) * 2 + slot];
          float s0 = __uint_as_float(h.x << 16), s1 = __uint_as_float(h.x & 0xFFFF0000u);
          float s2 = __uint_as_float(h.y << 16), s3 = __uint_as_float(h.y & 0xFFFF0000u);
          v0 += (s0 >= 0.f) ? s0 : s0 * inv4[0];
          v1 += (s1 >= 0.f) ? s1 : s1 * inv4[1];
          v2 += (s2 >= 0.f) ? s2 : s2 * inv4[2];
          v3 += (s3 >= 0.f) ? s3 : s3 * inv4[3];
        }
        float t0 = fmaxf(v0, 0.f) + pr4[0] * fminf(v0, 0.f);
        float t1 = fmaxf(v1, 0.f) + pr4[1] * fminf(v1, 0.f);
        float t2 = fmaxf(v2, 0.f) + pr4[2] * fminf(v2, 0.f);
        float t3 = fmaxf(v3, 0.f) + pr4[3] * fminf(v3, 0.f);
        uint2 sp = make_uint2(rne_pack(t0, t1), rne_pack(t2, t3));
        uint2* opb = actout + (size_t)(sc * 4 + g2) * PPLANE * 2;
        store_halo_s<uint2, 2>(opb, (int)px[nt], (int)py[nt], (int)ppix * 2 + slot, sp);
      }
    }
  } else {
    // fused convT channel contraction -> bf16 tap planes
    float4 b4[2];
#pragma unroll
    for (int mt = 0; mt < 2; ++mt) b4[mt] = *(const float4*)(b2v + mt * 16 + quad * 4);
#pragma unroll
    for (int nt = 0; nt < 4; ++nt) {
      float vv[2][4];
#pragma unroll
      for (int mt = 0; mt < 2; ++mt) {
        vv[mt][0] = acc[mt][nt][0] + b4[mt].x;
        vv[mt][1] = acc[mt][nt][1] + b4[mt].y;
        vv[mt][2] = acc[mt][nt][2] + b4[mt].z;
        vv[mt][3] = acc[mt][nt][3] + b4[mt].w;
      }
      ushort* sp = sout + (size_t)sc * 25 * PLANE + (int)(py[nt] * 270 + px[nt]);
#pragma unroll
      for (int t = 0; t < 25; ++t) {
        const float* wp = wTt + t * 32 + quad * 4;
        float c = 0.f;
#pragma unroll
        for (int mt = 0; mt < 2; ++mt) {
          float4 w4 = *(const float4*)(wp + mt * 16);
          c += w4.x * vv[mt][0] + w4.y * vv[mt][1] + w4.z * vv[mt][2] + w4.w * vv[mt][3];
        }
        c += __shfl_xor(c, 16, 64);
        c += __shfl_xor(c, 32, 64);
        if (quad == 0 && vld[nt]) sp[(size_t)t * PLANE] = rne1(c);
      }
    }
  }
}

// ---------------- convT pass 2: out = bt + sum_t s_t(shifted), bf16 tap planes ----------------
__global__ __launch_bounds__(256) void k_convT2(const ushort* __restrict__ s, const float* __restrict__ bt,
                                                float* __restrict__ yo) {
  int p = blockIdx.x * 256 + threadIdx.x;
  if (p >= PLANE) return;
  int sc = blockIdx.y;
  int y = p / 270, x = p - y * 270;
  float acc = bt[0];
  const ushort* sb = s + (size_t)sc * 25 * PLANE;
#pragma unroll
  for (int a = 0; a < 5; ++a) {
    int yy = y + a - 2;
    if ((unsigned)yy >= 270u) continue;
    const ushort* row = sb + (size_t)(a * 5) * PLANE + yy * 270;
#pragma unroll
    for (int b = 0; b < 5; ++b) {
      int xx = x + b - 2;
      if ((unsigned)xx < 270u) acc += __uint_as_float(((uint32)row[(size_t)b * PLANE + xx]) << 16);
    }
  }
  yo[(size_t)sc * PLANE + p] = acc;
}

// ---------------- norm projection scale ----------------
__global__ __launch_bounds__(256) void k_nrm(const float* __restrict__ yb, float* __restrict__ red) {
  int s = blockIdx.x;
  const float* ys = yb + (size_t)s * PLANE;
  float acc = 0.f;
  for (int i = threadIdx.x; i < PLANE; i += 256) { float v = ys[i]; acc += v * v; }
  float tot = blockReduceSum(acc);
  if (threadIdx.x == 0) {
    float nrm = sqrtf(tot);
    float eps = red[8 + s];
    red[16 + s] = (nrm > eps) ? eps / fmaxf(nrm, 1e-12f) : 1.0f;
  }
}

// ---------------- final: clip(z - scl*y), crop, mix ----------------
__global__ __launch_bounds__(256) void k_final(const float* __restrict__ z, const float* __restrict__ yb,
                                               const float* __restrict__ red, const float* __restrict__ mw,
                                               float* __restrict__ out) {
  int idx = blockIdx.x * 256 + threadIdx.x;
  if (idx >= 131072) return;
  int b = idx >> 16;
  int rem = idx & 65535;
  int h = rem >> 8, w = rem & 255;
  int p = (h + 7) * HP + (w + 7);
  float acc = 0.f;
#pragma unroll
  for (int d = 0; d < 4; ++d) {
    int s = b * 4 + d;
    float v = z[(size_t)s * PLANE + p] - red[16 + s] * yb[(size_t)s * PLANE + p];
    v = fminf(fmaxf(v, 0.f), 255.f);
    acc += mw[d] * v;
  }
  out[idx] = acc;
}

// =====================================================================
extern "C" void kernel_launch(void* const* d_in, const int* in_sizes, int n_in,
                              void* d_out, int out_size, void* d_ws, size_t ws_size,
                              hipStream_t stream) {
  (void)in_sizes; (void)n_in; (void)out_size;
  const float* x    = (const float*)d_in[0];
  const float* bk   = (const float*)d_in[1];
  const float* stdn = (const float*)d_in[2];
  const float* ww   = (const float*)d_in[3];
  const float* wwsc = (const float*)d_in[4];
  const float* alph = (const float*)d_in[5];
  const float* cw   = (const float*)d_in[6];
  const float* sf   = (const float*)d_in[7];
  const float* bf   = (const float*)d_in[8];
  const float* bt   = (const float*)d_in[9];
  const float* p1   = (const float*)d_in[10];
  const float* w1   = (const float*)d_in[11];
  const float* s1   = (const float*)d_in[12];
  const float* b1   = (const float*)d_in[13];
  const float* p2   = (const float*)d_in[14];
  const float* w2   = (const float*)d_in[15];
  const float* s2   = (const float*)d_in[16];
  const float* b2   = (const float*)d_in[17];
  const float* apj  = (const float*)d_in[18];
  const float* mwp  = (const float*)d_in[19];
  float* out = (float*)d_out;

  char* wsbase = (char*)d_ws;
  size_t off = 0;
  auto alloc = [&](size_t nbytes) -> char* {
    char* p = wsbase + off;
    off = (off + nbytes + 255) & ~(size_t)255;
    return p;
  };
  // ---- persistent region ----
  float*  zb  = (float*)alloc(8 * (size_t)PLANE * 4);
  float*  yb  = (float*)alloc(8 * (size_t)PLANE * 4);
  float*  red = (float*)alloc(64 * 4);
  float*  inv = (float*)alloc(32 * 4);
  float*  cwn = (float*)alloc(800 * 4);
  float*  wTt = (float*)alloc(800 * 4);
  unsigned short* w1f = (unsigned short*)alloc(5 * 36864 * (size_t)2);
  unsigned short* w2f = (unsigned short*)alloc(5 * 36864 * (size_t)2);
  // ---- union region ----
  size_t U0 = off;
  // DFT view
  float2* tw  = (float2*)alloc(2 * (size_t)PLANE * 4);
  float*  xp  = (float*)alloc(2 * (size_t)PLANE * 4);
  float*  rtm = (float*)alloc(2 * (size_t)PLANE * 4);
  float2* cb0 = (float2*)alloc(2 * 8 * (size_t)PLANE * 8);
  float2* cb1 = (float2*)alloc(2 * 8 * (size_t)PLANE * 8);
  float2* Yb  = (float2*)alloc(2 * 2 * (size_t)PLANE * 8);
  float2* Hf  = (float2*)alloc(2 * (size_t)PLANE * 4);
  float*  Sb  = (float*)alloc((size_t)PLANE * 4);
  float2* Tb  = (float2*)alloc(2 * 4 * (size_t)PLANE * 4);
  float*  ahw = (float*)alloc(540 * 4);
  float*  wwn = (float*)alloc(600 * 4);
  // conv view (aliases the DFT view). S = 8 if workspace allows, else 4.
  size_t conv8 = 2 * ((size_t)8 * 4 * PPLANE * 16 + 256);
  int S = (ws_size >= U0 + conv8) ? 8 : 4;
  int nc = 8 / S;
  off = U0;
  uint4* actA = (uint4*)alloc((size_t)S * 4 * PPLANE * 16);   // 32ch bf16 acts, buffer A
  uint4* actB = (uint4*)alloc((size_t)S * 4 * PPLANE * 16);   // buffer B; aliases sOb (S*25*PLANE bf16)
  ushort* sOb = (ushort*)actB;

  // setup
  k_twiddle<<<285, 256, 0, stream>>>(tw);
  k_sympad<<<(2 * PLANE + 255) / 256, 256, 0, stream>>>(x, xp);
  k_edget<<<1, 512, 0, stream>>>(bk, ahw);
  k_Hf<<<285, 256, 0, stream>>>(bk, Hf);
  k_wnorm<<<24, 256, 0, stream>>>(ww, wwsc, wwn, 25);
  k_wnorm<<<32, 256, 0, stream>>>(cw, sf, cwn, 25);
  k_wT<<<4, 256, 0, stream>>>(cwn, wTt);
  k_wfrag<32, 64><<<320, 256, 0, stream>>>(w1, s1, w1f);
  k_wfrag<64, 32><<<160, 256, 0, stream>>>(w2, s2, w2f);
  k_inv<<<1, 32, 0, stream>>>(p1, inv);
  k_S<<<285, 256, 0, stream>>>(wwn, Sb);
  k_T<<<(4 * PLANE + 255) / 256, 256, 0, stream>>>(Hf, Sb, alph, Tb);
  k_amp<<<4, 256, 0, stream>>>(Tb, red);
  k_eps<<<1, 64, 0, stream>>>(apj, stdn, red);

  dim3 g2(5, 45, 2), g8(5, 45, 8);

  // edgetaper
  k_rowT<6, true ><<<g2, 64, 0, stream>>>(xp, cb1, tw, -1.f);
  k_colT<6, false><<<g2, 64, 0, stream>>>(cb1, cb0, tw, -1.f, 1.f);
  k_mulHf<<<(2 * PLANE + 255) / 256, 256, 0, stream>>>(cb0, Hf, cb1);
  k_rowT<6, false><<<g2, 64, 0, stream>>>(cb1, cb0, tw, 1.f);
  k_colT<6, true ><<<g2, 64, 0, stream>>>(cb0, rtm, tw, 1.f, 1.f / (float)PLANE);
  k_taper<<<(2 * PLANE + 255) / 256, 256, 0, stream>>>(xp, rtm, ahw);

  // Y = fft2(xp)
  k_rowT<6, true ><<<g2, 64, 0, stream>>>(xp, cb1, tw, -1.f);
  k_colT<6, false><<<g2, 64, 0, stream>>>(cb1, Yb, tw, -1.f, 1.f);

  // z = ifft2(T*Y).real for all 8 (b,d)
  k_mulTY<<<(8 * PLANE + 255) / 256, 256, 0, stream>>>(Tb, Yb, cb0);
  k_rowT<6, false><<<g8, 64, 0, stream>>>(cb0, cb1, tw, 1.f);
  k_colT<6, true ><<<g8, 64, 0, stream>>>(cb1, zb, tw, 1.f, 1.f / (float)PLANE);

  // conv net, nc chunks of S samples; fused RPA pairs, A<->B ping-pong
  for (int c = 0; c < nc; ++c) {
    const float* zc = zb + (size_t)c * S * PLANE;
    float* ybc = yb + (size_t)c * S * PLANE;
    k_conv5<<<dim3(285, S), 256, 0, stream>>>(zc, cwn, bf, p1, actA);
    // i=0: A -> B, shortcut from A
    k_fused<true, 1><<<dim3(289, S), 256, 0, stream>>>(
        actA, w1f, w2f, b1, p2, b2, p1 + 32, (uint2*)actB, nullptr, (const uint2*)actA, inv, nullptr);
    // i=1: B -> A
    k_fused<false, 1><<<dim3(289, S), 256, 0, stream>>>(
        actB, w1f + 36864, w2f + 36864, b1 + 64, p2 + 64, b2 + 32, p1 + 64, (uint2*)actA, nullptr, nullptr, nullptr, nullptr);
    // i=2: A -> B
    k_fused<false, 1><<<dim3(289, S), 256, 0, stream>>>(
        actA, w1f + 2 * 36864, w2f + 2 * 36864, b1 + 128, p2 + 128, b2 + 64, p1 + 96, (uint2*)actB, nullptr, nullptr, nullptr, nullptr);
    // i=3: B -> A
    k_fused<false, 1><<<dim3(289, S), 256, 0, stream>>>(
        actB, w1f + 3 * 36864, w2f + 3 * 36864, b1 + 192, p2 + 192, b2 + 96, p1 + 128, (uint2*)actA, nullptr, nullptr, nullptr, nullptr);
    // i=4: A -> tap planes (sOb aliases B, dead)
    k_fused<false, 2><<<dim3(289, S), 256, 0, stream>>>(
        actA, w1f + 4 * 36864, w2f + 4 * 36864, b1 + 256, p2 + 256, b2 + 128, nullptr, nullptr, sOb, nullptr, nullptr, wTt);
    k_convT2<<<dim3(285, S), 256, 0, stream>>>(sOb, bt, ybc);
  }

  // projection + final mix
  k_nrm<<<8, 256, 0, stream>>>(yb, red);
  k_final<<<(131072 + 255) / 256, 256, 0, stream>>>(zb, yb, red, mwp, out);
}